// Round 1
// baseline (3931.315 us; speedup 1.0000x reference)
//
#include <hip/hip_runtime.h>
#include <hip/hip_bf16.h>

// ---------------------------------------------------------------------------
// Qwen2.5-VL decoder layer, MI355X (gfx950)
// B=1, N=1024, D=3584, H=28, KVH=4, HD=128, I=18944
// Strategy: bf16 MFMA GEMMs (16x16x32), fp32 accumulation, weights
// transposed+converted to bf16 [N][K] each call, flash-style attention with
// exact prune-masked softmax semantics.
// ---------------------------------------------------------------------------

#define SEQ   1024
#define DIM   3584
#define NH    28
#define NKVH  4
#define HDIM  128
#define IDIM  18944
#define QKVN  4608    // 3584 q + 512 k + 512 v
#define GUN   37888   // 2*18944

typedef __attribute__((ext_vector_type(8))) __bf16 bf16x8;
typedef __attribute__((ext_vector_type(4))) __bf16 bf16x4;
typedef __attribute__((ext_vector_type(4))) float  f32x4;

// ---------------- workspace layout (bytes) ----------------
static constexpr size_t OFF_WQKVT = 0;                                   // [4608][3584] bf16
static constexpr size_t OFF_WOT   = OFF_WQKVT + (size_t)QKVN*DIM*2;      // [3584][3584] bf16
static constexpr size_t OFF_WGUT  = OFF_WOT   + (size_t)DIM*DIM*2;       // [37888][3584] bf16
static constexpr size_t OFF_WDT   = OFF_WGUT  + (size_t)GUN*DIM*2;       // [3584][18944] bf16
static constexpr size_t OFF_XB    = OFF_WDT   + (size_t)DIM*IDIM*2;      // [1024][3584] bf16
static constexpr size_t OFF_QKV   = OFF_XB    + (size_t)SEQ*DIM*2;       // [1024][4608] bf16
static constexpr size_t OFF_VT    = OFF_QKV   + (size_t)SEQ*QKVN*2;      // [4][128][1024] bf16
static constexpr size_t OFF_VSUMP = OFF_VT    + (size_t)NKVH*HDIM*SEQ*2; // [4][8][128] f32
static constexpr size_t OFF_VSUM  = OFF_VSUMP + 4*8*128*4;               // [4][128] f32
static constexpr size_t OFF_BQKV  = OFF_VSUM  + 4*128*4;                 // [4608] f32
static constexpr size_t OFF_OB    = OFF_BQKV  + (size_t)QKVN*4;          // [1024][3584] bf16
static constexpr size_t OFF_HB    = OFF_OB    + (size_t)SEQ*DIM*2;       // [1024][3584] f32
static constexpr size_t OFF_YB    = OFF_HB    + (size_t)SEQ*DIM*4;       // [1024][3584] bf16
static constexpr size_t OFF_GU    = OFF_YB    + (size_t)SEQ*DIM*2;       // [1024][37888] bf16
static constexpr size_t OFF_PB    = OFF_GU    + (size_t)SEQ*GUN*2;       // [1024][18944] bf16

// ---------------- weight transpose + fp32->bf16 ----------------
// W [K][N] f32  ->  WT [N][K] bf16.  64x64 tiles.
__global__ __launch_bounds__(256) void transconv_kernel(
    const float* __restrict__ W, __bf16* __restrict__ WT, int K, int N)
{
  __shared__ __bf16 t[64][72];
  const int tid = threadIdx.x;
  const int k0 = blockIdx.y * 64, n0 = blockIdx.x * 64;
#pragma unroll
  for (int it = 0; it < 4; ++it) {
    int idx = it * 256 + tid;          // 1024 float4 chunks
    int r = idx >> 4, c4 = idx & 15;
    float4 v = *(const float4*)(W + (size_t)(k0 + r) * N + n0 + c4 * 4);
    t[r][c4 * 4 + 0] = (__bf16)v.x;
    t[r][c4 * 4 + 1] = (__bf16)v.y;
    t[r][c4 * 4 + 2] = (__bf16)v.z;
    t[r][c4 * 4 + 3] = (__bf16)v.w;
  }
  __syncthreads();
#pragma unroll
  for (int it = 0; it < 2; ++it) {
    int idx = it * 256 + tid;          // 512 chunks of 8
    int r = idx >> 3, c8 = idx & 7;
    bf16x8 o;
#pragma unroll
    for (int i = 0; i < 8; ++i) o[i] = t[c8 * 8 + i][r];
    *(bf16x8*)(WT + (size_t)(n0 + r) * K + k0 + c8 * 8) = o;
  }
}

// ---------------- bias concat ----------------
__global__ __launch_bounds__(256) void pack_bias_kernel(
    const float* __restrict__ bq, const float* __restrict__ bk,
    const float* __restrict__ bv, float* __restrict__ out)
{
  int i = blockIdx.x * 256 + threadIdx.x;
  if (i < DIM) out[i] = bq[i];
  else if (i < DIM + 512) out[i] = bk[i - DIM];
  else if (i < QKVN) out[i] = bv[i - DIM - 512];
}

// ---------------- RMSNorm (fp32 in, bf16 out) ----------------
__global__ __launch_bounds__(256) void rmsnorm_kernel(
    const float* __restrict__ in, const float* __restrict__ w,
    __bf16* __restrict__ out)
{
  const int row = blockIdx.x;
  const int t = threadIdx.x;
  const float* x = in + (size_t)row * DIM;
  float4 v[4];
  float ss = 0.f;
#pragma unroll
  for (int i = 0; i < 4; ++i) {
    int idx = t + i * 256;             // 896 float4s per row
    if (idx < 896) {
      v[i] = ((const float4*)x)[idx];
      ss += v[i].x * v[i].x + v[i].y * v[i].y + v[i].z * v[i].z + v[i].w * v[i].w;
    }
  }
#pragma unroll
  for (int m = 1; m < 64; m <<= 1) ss += __shfl_xor(ss, m);
  __shared__ float red[4];
  if ((t & 63) == 0) red[t >> 6] = ss;
  __syncthreads();
  float tot = red[0] + red[1] + red[2] + red[3];
  float rs = rsqrtf(tot / (float)DIM + 1e-6f);
#pragma unroll
  for (int i = 0; i < 4; ++i) {
    int idx = t + i * 256;
    if (idx < 896) {
      float4 wv = ((const float4*)w)[idx];
      bf16x4 o;
      o[0] = (__bf16)(v[i].x * rs * wv.x);
      o[1] = (__bf16)(v[i].y * rs * wv.y);
      o[2] = (__bf16)(v[i].z * rs * wv.z);
      o[3] = (__bf16)(v[i].w * rs * wv.w);
      *(bf16x4*)(out + (size_t)row * DIM + idx * 4) = o;
    }
  }
}

// ---------------- GEMM: C[M][N] = A[M][K] @ BT[N][K]^T (+epilogue) ----------
// 128x128 tile, BK=64, 256 threads (4 waves, 2x2 of 64x64), XOR-swizzled LDS.
template<bool F32OUT>
__global__ __launch_bounds__(256, 2) void gemm_bt_kernel(
    const __bf16* __restrict__ A, const __bf16* __restrict__ BT,
    const float* __restrict__ bias, const float* __restrict__ resid,
    void* __restrict__ C, int M, int N, int K)
{
  __shared__ int4 lds4[2048];          // 16KB A tile + 16KB B tile
  const short* ldsS = (const short*)lds4;
  const int tid = threadIdx.x;
  const int l = tid & 63, w = tid >> 6;
  const int row0 = blockIdx.y * 128;
  const int col0 = blockIdx.x * 128;
  const int m0 = (w >> 1) * 64;
  const int n0 = (w & 1) * 64;
  const int lg = l >> 4, lc = l & 15;

  f32x4 acc[4][4] = {};

  int aoff[4], boff[4], ldst[4];
#pragma unroll
  for (int i = 0; i < 4; ++i) {
    int c = i * 256 + tid;             // 16B chunk index within tile
    int r = c >> 3, p = c & 7;
    int b = p ^ (r & 7);               // logical k-block for phys slot p
    aoff[i] = (row0 + r) * K + b * 8;
    boff[i] = (col0 + r) * K + b * 8;
    ldst[i] = c;
  }

  const int ktc = K >> 6;
  for (int kt = 0; kt < ktc; ++kt) {
    const int k0 = kt << 6;
    int4 av[4], bv[4];
#pragma unroll
    for (int i = 0; i < 4; ++i) {
      av[i] = *(const int4*)(A + aoff[i] + k0);
      bv[i] = *(const int4*)(BT + boff[i] + k0);
    }
    __syncthreads();
#pragma unroll
    for (int i = 0; i < 4; ++i) {
      lds4[ldst[i]] = av[i];
      lds4[1024 + ldst[i]] = bv[i];
    }
    __syncthreads();
#pragma unroll
    for (int s = 0; s < 2; ++s) {
      bf16x8 af[4], bfv[4];
      const int c4 = s * 4 + lg;
#pragma unroll
      for (int a = 0; a < 4; ++a) {
        int r = m0 + a * 16 + lc;
        af[a] = *(const bf16x8*)(ldsS + r * 64 + ((c4 ^ (r & 7)) * 8));
      }
#pragma unroll
      for (int b = 0; b < 4; ++b) {
        int r = n0 + b * 16 + lc;
        bfv[b] = *(const bf16x8*)(ldsS + 8192 + r * 64 + ((c4 ^ (r & 7)) * 8));
      }
#pragma unroll
      for (int a = 0; a < 4; ++a)
#pragma unroll
        for (int b = 0; b < 4; ++b)
          acc[a][b] = __builtin_amdgcn_mfma_f32_16x16x32_bf16(af[a], bfv[b], acc[a][b], 0, 0, 0);
    }
  }

  const int lr = lg * 4;
#pragma unroll
  for (int b = 0; b < 4; ++b) {
    const int col = col0 + n0 + b * 16 + lc;
    float bias_v = 0.f;
    if (!F32OUT && bias != nullptr) bias_v = bias[col];
#pragma unroll
    for (int a = 0; a < 4; ++a) {
#pragma unroll
      for (int j = 0; j < 4; ++j) {
        const int row = row0 + m0 + a * 16 + lr + j;
        float vv = acc[a][b][j];
        if (F32OUT) {
          ((float*)C)[(size_t)row * N + col] = vv + resid[(size_t)row * N + col];
        } else {
          ((__bf16*)C)[(size_t)row * N + col] = (__bf16)(vv + bias_v);
        }
      }
    }
  }
}

// ---------------- mRoPE (in-place on q,k columns of qkv) ----------------
__global__ __launch_bounds__(256) void rope_kernel(
    __bf16* __restrict__ qkv, const float* __restrict__ cosb,
    const float* __restrict__ sinb)
{
  const int n = blockIdx.x;
  for (int p = threadIdx.x; p < 32 * 64; p += 256) {
    const int head = p >> 6;
    const int d = p & 63;
    const int src = (d < 16) ? 0 : (d < 40) ? 1 : 2;
    const float* cb = cosb + (size_t)src * SEQ * HDIM + (size_t)n * HDIM;
    const float* sb = sinb + (size_t)src * SEQ * HDIM + (size_t)n * HDIM;
    const float c0 = cb[d], c1 = cb[d + 64];
    const float s0 = sb[d], s1 = sb[d + 64];
    const int col = (head < NH) ? head * HDIM : DIM + (head - NH) * HDIM;
    __bf16* q = qkv + (size_t)n * QKVN + col;
    const float a = (float)q[d];
    const float b = (float)q[d + 64];
    q[d]      = (__bf16)(a * c0 - b * s0);
    q[d + 64] = (__bf16)(b * c1 + a * s1);
  }
}

// ---------------- V transpose [n][d] -> [d][n], plus column sums -----------
__global__ __launch_bounds__(256) void vtrans_kernel(
    const __bf16* __restrict__ qkv, __bf16* __restrict__ vT,
    float* __restrict__ vsump)
{
  __shared__ __bf16 t[128][132];
  const int nt = blockIdx.x, kvh = blockIdx.y;
  const int n0 = nt * 128;
  const int tid = threadIdx.x;
#pragma unroll
  for (int it = 0; it < 8; ++it) {
    int idx = it * 256 + tid;          // 2048 chunks of 8
    int nl = idx >> 4, c8 = idx & 15;
    bf16x8 v = *(const bf16x8*)(qkv + (size_t)(n0 + nl) * QKVN + 4096 + kvh * HDIM + c8 * 8);
#pragma unroll
    for (int i = 0; i < 8; ++i) t[nl][c8 * 8 + i] = v[i];
  }
  __syncthreads();
#pragma unroll
  for (int it = 0; it < 8; ++it) {
    int idx = it * 256 + tid;
    int d = idx >> 4, c8 = idx & 15;
    bf16x8 o;
#pragma unroll
    for (int i = 0; i < 8; ++i) o[i] = t[c8 * 8 + i][d];
    *(bf16x8*)(vT + (size_t)(kvh * HDIM + d) * SEQ + n0 + c8 * 8) = o;
  }
  if (tid < 128) {
    float s = 0.f;
    for (int nl = 0; nl < 128; ++nl) s += (float)t[nl][tid];
    vsump[(size_t)(kvh * 8 + nt) * 128 + tid] = s;
  }
}

__global__ __launch_bounds__(512) void vsum_reduce_kernel(
    const float* __restrict__ vsump, float* __restrict__ vsum)
{
  const int idx = threadIdx.x;         // kvh*128 + d
  const int kvh = idx >> 7, d = idx & 127;
  float s = 0.f;
#pragma unroll
  for (int nt = 0; nt < 8; ++nt) s += vsump[(size_t)(kvh * 8 + nt) * 128 + d];
  vsum[idx] = s;
}

// ---------------- attention -------------------------------------------------
// grid (16 q-tiles, 28 heads), 256 thr; wave w owns 16 q rows.
// Online softmax, max over causal scores (pre-prune), prune mask on e only,
// exact (e + EPS/N) / (sum e + EPS) via vsum term.
__global__ __launch_bounds__(256) void attn_kernel(
    const __bf16* __restrict__ qkv, const __bf16* __restrict__ vT,
    const float* __restrict__ vsum, const int* __restrict__ prune,
    __bf16* __restrict__ o)
{
  __shared__ __bf16 plds[4 * 16 * 40];
  const int tid = threadIdx.x;
  const int l = tid & 63, w = tid >> 6;
  const int h = blockIdx.y;
  const int kvh = h / 7;
  const int qt = blockIdx.x;
  const int qbase = qt * 64 + w * 16;
  const int lg = l >> 4, lc = l & 15;
  __bf16* pw = plds + w * (16 * 40);

  bf16x8 qf[4];
#pragma unroll
  for (int s = 0; s < 4; ++s)
    qf[s] = *(const bf16x8*)(qkv + (size_t)(qbase + lc) * QKVN + h * HDIM + s * 32 + lg * 8);

  f32x4 oacc[8] = {};
  float mrun[4] = {-3e38f, -3e38f, -3e38f, -3e38f};
  float lrun[4] = {0.f, 0.f, 0.f, 0.f};

  const int kbEnd = ((qbase + 15) >> 5) + 1;
  for (int kb = 0; kb < kbEnd; ++kb) {
    f32x4 sacc[2] = {};
#pragma unroll
    for (int s = 0; s < 4; ++s) {
#pragma unroll
      for (int c = 0; c < 2; ++c) {
        bf16x8 kf = *(const bf16x8*)(qkv + (size_t)(kb * 32 + c * 16 + lc) * QKVN
                                     + DIM + kvh * HDIM + s * 32 + lg * 8);
        sacc[c] = __builtin_amdgcn_mfma_f32_16x16x32_bf16(qf[s], kf, sacc[c], 0, 0, 0);
      }
    }
    float p[2][4];
    int am[2];
#pragma unroll
    for (int c = 0; c < 2; ++c) {
      const int col = kb * 32 + c * 16 + lc;
      am[c] = (prune[col] != 0) ? 1 : 0;
#pragma unroll
      for (int j = 0; j < 4; ++j) {
        const int row = qbase + lg * 4 + j;
        float sv = sacc[c][j] * 0.08838834764831845f;   // 1/sqrt(128)
        p[c][j] = (col <= row) ? sv : -3e38f;
      }
    }
#pragma unroll
    for (int j = 0; j < 4; ++j) {
      float mx = fmaxf(p[0][j], p[1][j]);
      mx = fmaxf(mx, __shfl_xor(mx, 1));
      mx = fmaxf(mx, __shfl_xor(mx, 2));
      mx = fmaxf(mx, __shfl_xor(mx, 4));
      mx = fmaxf(mx, __shfl_xor(mx, 8));
      const float mnew = fmaxf(mrun[j], mx);
      const float scale = __expf(mrun[j] - mnew);
      mrun[j] = mnew;
      const int row = qbase + lg * 4 + j;
      float rs = 0.f;
#pragma unroll
      for (int c = 0; c < 2; ++c) {
        const int col = kb * 32 + c * 16 + lc;
        float e = __expf(p[c][j] - mnew);
        const int keep = (col == row) ? 1 : am[c];
        e = keep ? e : 0.f;
        p[c][j] = e;
        rs += e;
      }
      rs += __shfl_xor(rs, 1);
      rs += __shfl_xor(rs, 2);
      rs += __shfl_xor(rs, 4);
      rs += __shfl_xor(rs, 8);
      lrun[j] = lrun[j] * scale + rs;
#pragma unroll
      for (int df = 0; df < 8; ++df) oacc[df][j] *= scale;
    }
#pragma unroll
    for (int c = 0; c < 2; ++c)
#pragma unroll
      for (int j = 0; j < 4; ++j)
        pw[(lg * 4 + j) * 40 + c * 16 + lc] = (__bf16)p[c][j];
    // same-wave LDS exchange: DS ops execute in order within a wave
    bf16x8 pa = *(const bf16x8*)(pw + lc * 40 + lg * 8);
#pragma unroll
    for (int df = 0; df < 8; ++df) {
      bf16x8 vf = *(const bf16x8*)(vT + (size_t)(kvh * HDIM + df * 16 + lc) * SEQ + kb * 32 + lg * 8);
      oacc[df] = __builtin_amdgcn_mfma_f32_16x16x32_bf16(pa, vf, oacc[df], 0, 0, 0);
    }
  }
#pragma unroll
  for (int df = 0; df < 8; ++df) {
    const float vs = vsum[kvh * HDIM + df * 16 + lc];
#pragma unroll
    for (int j = 0; j < 4; ++j) {
      const int row = qbase + lg * 4 + j;
      const float denom = lrun[j] + 1e-6f;
      const float val = (oacc[df][j] + 9.765625e-10f * vs) / denom;   // EPS/N = 1e-6/1024
      o[(size_t)row * DIM + h * HDIM + df * 16 + lc] = (__bf16)val;
    }
  }
}

// ---------------- SiLU(g) * u ----------------
__global__ __launch_bounds__(256) void silu_mul_kernel(
    const __bf16* __restrict__ gu, __bf16* __restrict__ p)
{
  const int n = blockIdx.y;
  const int i8 = blockIdx.x * 256 + threadIdx.x;
  if (i8 >= IDIM / 8) return;
  bf16x8 g = *(const bf16x8*)(gu + (size_t)n * GUN + i8 * 8);
  bf16x8 u = *(const bf16x8*)(gu + (size_t)n * GUN + IDIM + i8 * 8);
  bf16x8 o;
#pragma unroll
  for (int i = 0; i < 8; ++i) {
    const float gf = (float)g[i];
    const float uf = (float)u[i];
    const float s = gf / (1.f + __expf(-gf));
    o[i] = (__bf16)(s * uf);
  }
  *(bf16x8*)(p + (size_t)n * IDIM + i8 * 8) = o;
}

// ---------------------------------------------------------------------------
extern "C" void kernel_launch(void* const* d_in, const int* in_sizes, int n_in,
                              void* d_out, int out_size, void* d_ws, size_t ws_size,
                              hipStream_t stream) {
  const float* hidden = (const float*)d_in[0];
  const float* cosb   = (const float*)d_in[1];
  const float* sinb   = (const float*)d_in[2];
  const int*   prune  = (const int*)d_in[3];
  const float* Wq     = (const float*)d_in[4];
  const float* bq     = (const float*)d_in[5];
  const float* Wk     = (const float*)d_in[6];
  const float* bk     = (const float*)d_in[7];
  const float* Wv     = (const float*)d_in[8];
  const float* bv     = (const float*)d_in[9];
  const float* Wo     = (const float*)d_in[10];
  const float* ln1    = (const float*)d_in[11];
  const float* ln2    = (const float*)d_in[12];
  const float* Wg     = (const float*)d_in[13];
  const float* Wu     = (const float*)d_in[14];
  const float* Wd     = (const float*)d_in[15];
  float* out = (float*)d_out;
  char* ws = (char*)d_ws;

  __bf16* WQKVT = (__bf16*)(ws + OFF_WQKVT);
  __bf16* WOT   = (__bf16*)(ws + OFF_WOT);
  __bf16* WGUT  = (__bf16*)(ws + OFF_WGUT);
  __bf16* WDT   = (__bf16*)(ws + OFF_WDT);
  __bf16* XB    = (__bf16*)(ws + OFF_XB);
  __bf16* QKV   = (__bf16*)(ws + OFF_QKV);
  __bf16* VT    = (__bf16*)(ws + OFF_VT);
  float*  VSUMP = (float*)(ws + OFF_VSUMP);
  float*  VSUM  = (float*)(ws + OFF_VSUM);
  float*  BQKV  = (float*)(ws + OFF_BQKV);
  __bf16* OB    = (__bf16*)(ws + OFF_OB);
  float*  HB    = (float*)(ws + OFF_HB);
  __bf16* YB    = (__bf16*)(ws + OFF_YB);
  __bf16* GU    = (__bf16*)(ws + OFF_GU);
  __bf16* PB    = (__bf16*)(ws + OFF_PB);

  // weight transpose + convert
  transconv_kernel<<<dim3(DIM / 64, DIM / 64), 256, 0, stream>>>(Wq, WQKVT, DIM, DIM);
  transconv_kernel<<<dim3(512 / 64, DIM / 64), 256, 0, stream>>>(Wk, WQKVT + (size_t)DIM * DIM, DIM, 512);
  transconv_kernel<<<dim3(512 / 64, DIM / 64), 256, 0, stream>>>(Wv, WQKVT + (size_t)4096 * DIM, DIM, 512);
  transconv_kernel<<<dim3(DIM / 64, DIM / 64), 256, 0, stream>>>(Wo, WOT, DIM, DIM);
  transconv_kernel<<<dim3(IDIM / 64, DIM / 64), 256, 0, stream>>>(Wg, WGUT, DIM, IDIM);
  transconv_kernel<<<dim3(IDIM / 64, DIM / 64), 256, 0, stream>>>(Wu, WGUT + (size_t)IDIM * DIM, DIM, IDIM);
  transconv_kernel<<<dim3(DIM / 64, IDIM / 64), 256, 0, stream>>>(Wd, WDT, IDIM, DIM);

  pack_bias_kernel<<<QKVN / 256, 256, 0, stream>>>(bq, bk, bv, BQKV);

  // x = rmsnorm(hidden, ln1) (bf16)
  rmsnorm_kernel<<<SEQ, 256, 0, stream>>>(hidden, ln1, XB);

  // qkv = x @ Wqkv + b
  gemm_bt_kernel<false><<<dim3(QKVN / 128, SEQ / 128), 256, 0, stream>>>(
      XB, WQKVT, BQKV, nullptr, QKV, SEQ, QKVN, DIM);

  // mRoPE in-place on q,k
  rope_kernel<<<SEQ, 256, 0, stream>>>(QKV, cosb, sinb);

  // v transpose + column sums
  vtrans_kernel<<<dim3(8, NKVH), 256, 0, stream>>>(QKV, VT, VSUMP);
  vsum_reduce_kernel<<<1, 512, 0, stream>>>(VSUMP, VSUM);

  // attention -> OB (bf16 [1024][3584], head-concat layout)
  attn_kernel<<<dim3(SEQ / 64, NH), 256, 0, stream>>>(QKV, VT, VSUM, prune, OB);

  // h = hidden + OB @ Wo  (f32)
  gemm_bt_kernel<true><<<dim3(DIM / 128, SEQ / 128), 256, 0, stream>>>(
      OB, WOT, nullptr, hidden, HB, SEQ, DIM, DIM);

  // y = rmsnorm(h, ln2) (bf16)
  rmsnorm_kernel<<<SEQ, 256, 0, stream>>>(HB, ln2, YB);

  // [g|u] = y @ [Wg|Wu]
  gemm_bt_kernel<false><<<dim3(GUN / 128, SEQ / 128), 256, 0, stream>>>(
      YB, WGUT, nullptr, nullptr, GU, SEQ, GUN, DIM);

  // p = silu(g) * u
  silu_mul_kernel<<<dim3(10, SEQ), 256, 0, stream>>>(GU, PB);

  // out = h + p @ Wd  (f32)
  gemm_bt_kernel<true><<<dim3(DIM / 128, SEQ / 128), 256, 0, stream>>>(
      PB, WDT, nullptr, HB, out, SEQ, DIM, IDIM);
}

// Round 2
// 1456.676 us; speedup vs baseline: 2.6988x; 2.6988x over previous
//
#include <hip/hip_runtime.h>
#include <hip/hip_bf16.h>

// ---------------------------------------------------------------------------
// Qwen2.5-VL decoder layer, MI355X (gfx950)
// B=1, N=1024, D=3584, H=28, KVH=4, HD=128, I=18944
// Round 2: gemm_bt rewritten to m97 structure — global_load_lds width=16
// direct HBM->LDS staging (no staging registers -> no spills), 128x128 tile,
// BK=64, 2-barrier loop, bijective XCD swizzle for B-panel L2 reuse.
// ---------------------------------------------------------------------------

#define SEQ   1024
#define DIM   3584
#define NH    28
#define NKVH  4
#define HDIM  128
#define IDIM  18944
#define QKVN  4608    // 3584 q + 512 k + 512 v
#define GUN   37888   // 2*18944

typedef __attribute__((ext_vector_type(8))) __bf16 bf16x8;
typedef __attribute__((ext_vector_type(4))) __bf16 bf16x4;
typedef __attribute__((ext_vector_type(4))) float  f32x4;

// ---------------- workspace layout (bytes) ----------------
static constexpr size_t OFF_WQKVT = 0;                                   // [4608][3584] bf16
static constexpr size_t OFF_WOT   = OFF_WQKVT + (size_t)QKVN*DIM*2;      // [3584][3584] bf16
static constexpr size_t OFF_WGUT  = OFF_WOT   + (size_t)DIM*DIM*2;       // [37888][3584] bf16
static constexpr size_t OFF_WDT   = OFF_WGUT  + (size_t)GUN*DIM*2;       // [3584][18944] bf16
static constexpr size_t OFF_XB    = OFF_WDT   + (size_t)DIM*IDIM*2;      // [1024][3584] bf16
static constexpr size_t OFF_QKV   = OFF_XB    + (size_t)SEQ*DIM*2;       // [1024][4608] bf16
static constexpr size_t OFF_VT    = OFF_QKV   + (size_t)SEQ*QKVN*2;      // [4][128][1024] bf16
static constexpr size_t OFF_VSUMP = OFF_VT    + (size_t)NKVH*HDIM*SEQ*2; // [4][8][128] f32
static constexpr size_t OFF_VSUM  = OFF_VSUMP + 4*8*128*4;               // [4][128] f32
static constexpr size_t OFF_BQKV  = OFF_VSUM  + 4*128*4;                 // [4608] f32
static constexpr size_t OFF_OB    = OFF_BQKV  + (size_t)QKVN*4;          // [1024][3584] bf16
static constexpr size_t OFF_HB    = OFF_OB    + (size_t)SEQ*DIM*2;       // [1024][3584] f32
static constexpr size_t OFF_YB    = OFF_HB    + (size_t)SEQ*DIM*4;       // [1024][3584] bf16
static constexpr size_t OFF_GU    = OFF_YB    + (size_t)SEQ*DIM*2;       // [1024][37888] bf16
static constexpr size_t OFF_PB    = OFF_GU    + (size_t)SEQ*GUN*2;       // [1024][18944] bf16

// async global->LDS, 16B per lane. lds ptr must be wave-uniform; HW writes
// lane l's 16B to ldsbase + l*16. global ptr is per-lane.
#define GLL16(gp, lp)                                                        \
  __builtin_amdgcn_global_load_lds(                                         \
      (const __attribute__((address_space(1))) void*)(gp),                  \
      (__attribute__((address_space(3))) void*)(lp), 16, 0, 0)

// ---------------- weight transpose + fp32->bf16 ----------------
// W [K][N] f32  ->  WT [N][K] bf16.  64x64 tiles.
__global__ __launch_bounds__(256) void transconv_kernel(
    const float* __restrict__ W, __bf16* __restrict__ WT, int K, int N)
{
  __shared__ __bf16 t[64][72];
  const int tid = threadIdx.x;
  const int k0 = blockIdx.y * 64, n0 = blockIdx.x * 64;
#pragma unroll
  for (int it = 0; it < 4; ++it) {
    int idx = it * 256 + tid;          // 1024 float4 chunks
    int r = idx >> 4, c4 = idx & 15;
    float4 v = *(const float4*)(W + (size_t)(k0 + r) * N + n0 + c4 * 4);
    t[r][c4 * 4 + 0] = (__bf16)v.x;
    t[r][c4 * 4 + 1] = (__bf16)v.y;
    t[r][c4 * 4 + 2] = (__bf16)v.z;
    t[r][c4 * 4 + 3] = (__bf16)v.w;
  }
  __syncthreads();
#pragma unroll
  for (int it = 0; it < 2; ++it) {
    int idx = it * 256 + tid;          // 512 chunks of 8
    int r = idx >> 3, c8 = idx & 7;
    bf16x8 o;
#pragma unroll
    for (int i = 0; i < 8; ++i) o[i] = t[c8 * 8 + i][r];
    *(bf16x8*)(WT + (size_t)(n0 + r) * K + k0 + c8 * 8) = o;
  }
}

// ---------------- bias concat ----------------
__global__ __launch_bounds__(256) void pack_bias_kernel(
    const float* __restrict__ bq, const float* __restrict__ bk,
    const float* __restrict__ bv, float* __restrict__ out)
{
  int i = blockIdx.x * 256 + threadIdx.x;
  if (i < DIM) out[i] = bq[i];
  else if (i < DIM + 512) out[i] = bk[i - DIM];
  else if (i < QKVN) out[i] = bv[i - DIM - 512];
}

// ---------------- RMSNorm (fp32 in, bf16 out) ----------------
__global__ __launch_bounds__(256) void rmsnorm_kernel(
    const float* __restrict__ in, const float* __restrict__ w,
    __bf16* __restrict__ out)
{
  const int row = blockIdx.x;
  const int t = threadIdx.x;
  const float* x = in + (size_t)row * DIM;
  float4 v[4];
  float ss = 0.f;
#pragma unroll
  for (int i = 0; i < 4; ++i) {
    int idx = t + i * 256;             // 896 float4s per row
    if (idx < 896) {
      v[i] = ((const float4*)x)[idx];
      ss += v[i].x * v[i].x + v[i].y * v[i].y + v[i].z * v[i].z + v[i].w * v[i].w;
    }
  }
#pragma unroll
  for (int m = 1; m < 64; m <<= 1) ss += __shfl_xor(ss, m);
  __shared__ float red[4];
  if ((t & 63) == 0) red[t >> 6] = ss;
  __syncthreads();
  float tot = red[0] + red[1] + red[2] + red[3];
  float rs = rsqrtf(tot / (float)DIM + 1e-6f);
#pragma unroll
  for (int i = 0; i < 4; ++i) {
    int idx = t + i * 256;
    if (idx < 896) {
      float4 wv = ((const float4*)w)[idx];
      bf16x4 o;
      o[0] = (__bf16)(v[i].x * rs * wv.x);
      o[1] = (__bf16)(v[i].y * rs * wv.y);
      o[2] = (__bf16)(v[i].z * rs * wv.z);
      o[3] = (__bf16)(v[i].w * rs * wv.w);
      *(bf16x4*)(out + (size_t)row * DIM + idx * 4) = o;
    }
  }
}

// ---------------- GEMM: C[M][N] = A[M][K] @ BT[N][K]^T (+epilogue) ----------
// m97 structure: 128x128 tile, BK=64, 256 threads (4 waves, 2x2 of 64x64),
// global_load_lds width=16 direct staging, linear LDS, 2 barriers per K-step.
// 1-D grid with bijective XCD swizzle; decode puts blocks sharing a B-panel
// (same tn) on consecutive wg so each weight panel is fetched ~once per XCD.
template<bool F32OUT>
__global__ __launch_bounds__(256, 2) void gemm_bt_kernel(
    const __bf16* __restrict__ A, const __bf16* __restrict__ BT,
    const float* __restrict__ bias, const float* __restrict__ resid,
    void* __restrict__ C, int M, int N, int K, int gridY)
{
  __shared__ __bf16 As[128 * 64];      // 16 KB
  __shared__ __bf16 Bs[128 * 64];      // 16 KB
  const int tid = threadIdx.x;
  const int l = tid & 63, w = tid >> 6;

  // bijective XCD swizzle (m204)
  const int nwg = gridDim.x;
  const int bq8 = nwg >> 3, br8 = nwg & 7;
  const int xcd = blockIdx.x & 7, bidx = blockIdx.x >> 3;
  const int wg = (xcd < br8 ? xcd * (bq8 + 1) : br8 * (bq8 + 1) + (xcd - br8) * bq8) + bidx;
  const int tm = wg % gridY;           // M-tile (consecutive wg share tn -> B-panel reuse)
  const int tn = wg / gridY;           // N-tile
  const int row0 = tm * 128;
  const int col0 = tn * 128;

  const int m0 = (w >> 1) * 64;
  const int n0 = (w & 1) * 64;
  const int lg = l >> 4, lc = l & 15;

  f32x4 acc[4][4] = {};

  // staging geometry: tile = 128 rows x 64 bf16 = 1024 chunks of 16B.
  // wave w, iter it covers chunks [(it*4+w)*64, +64); lane l -> chunk cbase+l.
  size_t aoff[4], boff[4];
  int lbyte[4];
#pragma unroll
  for (int it = 0; it < 4; ++it) {
    const int cbase = (it * 4 + w) * 64;
    const int c = cbase + l;
    const int r = c >> 3, p = c & 7;   // row in tile, 16B chunk within row
    aoff[it] = (size_t)(row0 + r) * K + p * 8;
    boff[it] = (size_t)(col0 + r) * K + p * 8;
    lbyte[it] = cbase * 16;            // wave-uniform LDS byte base
  }

  const int ktc = K >> 6;
  for (int kt = 0; kt < ktc; ++kt) {
    const int k0 = kt << 6;
#pragma unroll
    for (int it = 0; it < 4; ++it) {
      GLL16(A + aoff[it] + k0, (char*)As + lbyte[it]);
      GLL16(BT + boff[it] + k0, (char*)Bs + lbyte[it]);
    }
    __syncthreads();                   // waits vmcnt(0): staging complete
#pragma unroll
    for (int s = 0; s < 2; ++s) {
      bf16x8 af[4], bfv[4];
      const int koff = s * 32 + lg * 8;
#pragma unroll
      for (int a = 0; a < 4; ++a)
        af[a] = *(const bf16x8*)(As + (m0 + a * 16 + lc) * 64 + koff);
#pragma unroll
      for (int b = 0; b < 4; ++b)
        bfv[b] = *(const bf16x8*)(Bs + (n0 + b * 16 + lc) * 64 + koff);
#pragma unroll
      for (int a = 0; a < 4; ++a)
#pragma unroll
        for (int b = 0; b < 4; ++b)
          acc[a][b] = __builtin_amdgcn_mfma_f32_16x16x32_bf16(af[a], bfv[b], acc[a][b], 0, 0, 0);
    }
    __syncthreads();                   // compute done before next overwrite
  }

  const int lr = lg * 4;
#pragma unroll
  for (int b = 0; b < 4; ++b) {
    const int col = col0 + n0 + b * 16 + lc;
    float bias_v = 0.f;
    if (!F32OUT && bias != nullptr) bias_v = bias[col];
#pragma unroll
    for (int a = 0; a < 4; ++a) {
#pragma unroll
      for (int j = 0; j < 4; ++j) {
        const int row = row0 + m0 + a * 16 + lr + j;
        float vv = acc[a][b][j];
        if (F32OUT) {
          ((float*)C)[(size_t)row * N + col] = vv + resid[(size_t)row * N + col];
        } else {
          ((__bf16*)C)[(size_t)row * N + col] = (__bf16)(vv + bias_v);
        }
      }
    }
  }
}

// ---------------- mRoPE (in-place on q,k columns of qkv) ----------------
__global__ __launch_bounds__(256) void rope_kernel(
    __bf16* __restrict__ qkv, const float* __restrict__ cosb,
    const float* __restrict__ sinb)
{
  const int n = blockIdx.x;
  for (int p = threadIdx.x; p < 32 * 64; p += 256) {
    const int head = p >> 6;
    const int d = p & 63;
    const int src = (d < 16) ? 0 : (d < 40) ? 1 : 2;
    const float* cb = cosb + (size_t)src * SEQ * HDIM + (size_t)n * HDIM;
    const float* sb = sinb + (size_t)src * SEQ * HDIM + (size_t)n * HDIM;
    const float c0 = cb[d], c1 = cb[d + 64];
    const float s0 = sb[d], s1 = sb[d + 64];
    const int col = (head < NH) ? head * HDIM : DIM + (head - NH) * HDIM;
    __bf16* q = qkv + (size_t)n * QKVN + col;
    const float a = (float)q[d];
    const float b = (float)q[d + 64];
    q[d]      = (__bf16)(a * c0 - b * s0);
    q[d + 64] = (__bf16)(b * c1 + a * s1);
  }
}

// ---------------- V transpose [n][d] -> [d][n], plus column sums -----------
__global__ __launch_bounds__(256) void vtrans_kernel(
    const __bf16* __restrict__ qkv, __bf16* __restrict__ vT,
    float* __restrict__ vsump)
{
  __shared__ __bf16 t[128][132];
  const int nt = blockIdx.x, kvh = blockIdx.y;
  const int n0 = nt * 128;
  const int tid = threadIdx.x;
#pragma unroll
  for (int it = 0; it < 8; ++it) {
    int idx = it * 256 + tid;          // 2048 chunks of 8
    int nl = idx >> 4, c8 = idx & 15;
    bf16x8 v = *(const bf16x8*)(qkv + (size_t)(n0 + nl) * QKVN + 4096 + kvh * HDIM + c8 * 8);
#pragma unroll
    for (int i = 0; i < 8; ++i) t[nl][c8 * 8 + i] = v[i];
  }
  __syncthreads();
#pragma unroll
  for (int it = 0; it < 8; ++it) {
    int idx = it * 256 + tid;
    int d = idx >> 4, c8 = idx & 15;
    bf16x8 o;
#pragma unroll
    for (int i = 0; i < 8; ++i) o[i] = t[c8 * 8 + i][d];
    *(bf16x8*)(vT + (size_t)(kvh * HDIM + d) * SEQ + n0 + c8 * 8) = o;
  }
  if (tid < 128) {
    float s = 0.f;
    for (int nl = 0; nl < 128; ++nl) s += (float)t[nl][tid];
    vsump[(size_t)(kvh * 8 + nt) * 128 + tid] = s;
  }
}

__global__ __launch_bounds__(512) void vsum_reduce_kernel(
    const float* __restrict__ vsump, float* __restrict__ vsum)
{
  const int idx = threadIdx.x;         // kvh*128 + d
  const int kvh = idx >> 7, d = idx & 127;
  float s = 0.f;
#pragma unroll
  for (int nt = 0; nt < 8; ++nt) s += vsump[(size_t)(kvh * 8 + nt) * 128 + d];
  vsum[idx] = s;
}

// ---------------- attention -------------------------------------------------
__global__ __launch_bounds__(256) void attn_kernel(
    const __bf16* __restrict__ qkv, const __bf16* __restrict__ vT,
    const float* __restrict__ vsum, const int* __restrict__ prune,
    __bf16* __restrict__ o)
{
  __shared__ __bf16 plds[4 * 16 * 40];
  const int tid = threadIdx.x;
  const int l = tid & 63, w = tid >> 6;
  const int h = blockIdx.y;
  const int kvh = h / 7;
  const int qt = blockIdx.x;
  const int qbase = qt * 64 + w * 16;
  const int lg = l >> 4, lc = l & 15;
  __bf16* pw = plds + w * (16 * 40);

  bf16x8 qf[4];
#pragma unroll
  for (int s = 0; s < 4; ++s)
    qf[s] = *(const bf16x8*)(qkv + (size_t)(qbase + lc) * QKVN + h * HDIM + s * 32 + lg * 8);

  f32x4 oacc[8] = {};
  float mrun[4] = {-3e38f, -3e38f, -3e38f, -3e38f};
  float lrun[4] = {0.f, 0.f, 0.f, 0.f};

  const int kbEnd = ((qbase + 15) >> 5) + 1;
  for (int kb = 0; kb < kbEnd; ++kb) {
    f32x4 sacc[2] = {};
#pragma unroll
    for (int s = 0; s < 4; ++s) {
#pragma unroll
      for (int c = 0; c < 2; ++c) {
        bf16x8 kf = *(const bf16x8*)(qkv + (size_t)(kb * 32 + c * 16 + lc) * QKVN
                                     + DIM + kvh * HDIM + s * 32 + lg * 8);
        sacc[c] = __builtin_amdgcn_mfma_f32_16x16x32_bf16(qf[s], kf, sacc[c], 0, 0, 0);
      }
    }
    float p[2][4];
    int am[2];
#pragma unroll
    for (int c = 0; c < 2; ++c) {
      const int col = kb * 32 + c * 16 + lc;
      am[c] = (prune[col] != 0) ? 1 : 0;
#pragma unroll
      for (int j = 0; j < 4; ++j) {
        const int row = qbase + lg * 4 + j;
        float sv = sacc[c][j] * 0.08838834764831845f;   // 1/sqrt(128)
        p[c][j] = (col <= row) ? sv : -3e38f;
      }
    }
#pragma unroll
    for (int j = 0; j < 4; ++j) {
      float mx = fmaxf(p[0][j], p[1][j]);
      mx = fmaxf(mx, __shfl_xor(mx, 1));
      mx = fmaxf(mx, __shfl_xor(mx, 2));
      mx = fmaxf(mx, __shfl_xor(mx, 4));
      mx = fmaxf(mx, __shfl_xor(mx, 8));
      const float mnew = fmaxf(mrun[j], mx);
      const float scale = __expf(mrun[j] - mnew);
      mrun[j] = mnew;
      const int row = qbase + lg * 4 + j;
      float rs = 0.f;
#pragma unroll
      for (int c = 0; c < 2; ++c) {
        const int col = kb * 32 + c * 16 + lc;
        float e = __expf(p[c][j] - mnew);
        const int keep = (col == row) ? 1 : am[c];
        e = keep ? e : 0.f;
        p[c][j] = e;
        rs += e;
      }
      rs += __shfl_xor(rs, 1);
      rs += __shfl_xor(rs, 2);
      rs += __shfl_xor(rs, 4);
      rs += __shfl_xor(rs, 8);
      lrun[j] = lrun[j] * scale + rs;
#pragma unroll
      for (int df = 0; df < 8; ++df) oacc[df][j] *= scale;
    }
#pragma unroll
    for (int c = 0; c < 2; ++c)
#pragma unroll
      for (int j = 0; j < 4; ++j)
        pw[(lg * 4 + j) * 40 + c * 16 + lc] = (__bf16)p[c][j];
    // same-wave LDS exchange: DS ops complete in order within a wave
    bf16x8 pa = *(const bf16x8*)(pw + lc * 40 + lg * 8);
#pragma unroll
    for (int df = 0; df < 8; ++df) {
      bf16x8 vf = *(const bf16x8*)(vT + (size_t)(kvh * HDIM + df * 16 + lc) * SEQ + kb * 32 + lg * 8);
      oacc[df] = __builtin_amdgcn_mfma_f32_16x16x32_bf16(pa, vf, oacc[df], 0, 0, 0);
    }
  }
#pragma unroll
  for (int df = 0; df < 8; ++df) {
    const float vs = vsum[kvh * HDIM + df * 16 + lc];
#pragma unroll
    for (int j = 0; j < 4; ++j) {
      const int row = qbase + lg * 4 + j;
      const float denom = lrun[j] + 1e-6f;
      const float val = (oacc[df][j] + 9.765625e-10f * vs) / denom;   // EPS/N = 1e-6/1024
      o[(size_t)row * DIM + h * HDIM + df * 16 + lc] = (__bf16)val;
    }
  }
}

// ---------------- SiLU(g) * u ----------------
__global__ __launch_bounds__(256) void silu_mul_kernel(
    const __bf16* __restrict__ gu, __bf16* __restrict__ p)
{
  const int n = blockIdx.y;
  const int i8 = blockIdx.x * 256 + threadIdx.x;
  if (i8 >= IDIM / 8) return;
  bf16x8 g = *(const bf16x8*)(gu + (size_t)n * GUN + i8 * 8);
  bf16x8 u = *(const bf16x8*)(gu + (size_t)n * GUN + IDIM + i8 * 8);
  bf16x8 o;
#pragma unroll
  for (int i = 0; i < 8; ++i) {
    const float gf = (float)g[i];
    const float uf = (float)u[i];
    const float s = gf / (1.f + __expf(-gf));
    o[i] = (__bf16)(s * uf);
  }
  *(bf16x8*)(p + (size_t)n * IDIM + i8 * 8) = o;
}

// ---------------------------------------------------------------------------
extern "C" void kernel_launch(void* const* d_in, const int* in_sizes, int n_in,
                              void* d_out, int out_size, void* d_ws, size_t ws_size,
                              hipStream_t stream) {
  const float* hidden = (const float*)d_in[0];
  const float* cosb   = (const float*)d_in[1];
  const float* sinb   = (const float*)d_in[2];
  const int*   prune  = (const int*)d_in[3];
  const float* Wq     = (const float*)d_in[4];
  const float* bq     = (const float*)d_in[5];
  const float* Wk     = (const float*)d_in[6];
  const float* bk     = (const float*)d_in[7];
  const float* Wv     = (const float*)d_in[8];
  const float* bv     = (const float*)d_in[9];
  const float* Wo     = (const float*)d_in[10];
  const float* ln1    = (const float*)d_in[11];
  const float* ln2    = (const float*)d_in[12];
  const float* Wg     = (const float*)d_in[13];
  const float* Wu     = (const float*)d_in[14];
  const float* Wd     = (const float*)d_in[15];
  float* out = (float*)d_out;
  char* ws = (char*)d_ws;

  __bf16* WQKVT = (__bf16*)(ws + OFF_WQKVT);
  __bf16* WOT   = (__bf16*)(ws + OFF_WOT);
  __bf16* WGUT  = (__bf16*)(ws + OFF_WGUT);
  __bf16* WDT   = (__bf16*)(ws + OFF_WDT);
  __bf16* XB    = (__bf16*)(ws + OFF_XB);
  __bf16* QKV   = (__bf16*)(ws + OFF_QKV);
  __bf16* VT    = (__bf16*)(ws + OFF_VT);
  float*  VSUMP = (float*)(ws + OFF_VSUMP);
  float*  VSUM  = (float*)(ws + OFF_VSUM);
  float*  BQKV  = (float*)(ws + OFF_BQKV);
  __bf16* OB    = (__bf16*)(ws + OFF_OB);
  float*  HB    = (float*)(ws + OFF_HB);
  __bf16* YB    = (__bf16*)(ws + OFF_YB);
  __bf16* GU    = (__bf16*)(ws + OFF_GU);
  __bf16* PB    = (__bf16*)(ws + OFF_PB);

  // weight transpose + convert
  transconv_kernel<<<dim3(DIM / 64, DIM / 64), 256, 0, stream>>>(Wq, WQKVT, DIM, DIM);
  transconv_kernel<<<dim3(512 / 64, DIM / 64), 256, 0, stream>>>(Wk, WQKVT + (size_t)DIM * DIM, DIM, 512);
  transconv_kernel<<<dim3(512 / 64, DIM / 64), 256, 0, stream>>>(Wv, WQKVT + (size_t)4096 * DIM, DIM, 512);
  transconv_kernel<<<dim3(DIM / 64, DIM / 64), 256, 0, stream>>>(Wo, WOT, DIM, DIM);
  transconv_kernel<<<dim3(IDIM / 64, DIM / 64), 256, 0, stream>>>(Wg, WGUT, DIM, IDIM);
  transconv_kernel<<<dim3(IDIM / 64, DIM / 64), 256, 0, stream>>>(Wu, WGUT + (size_t)IDIM * DIM, DIM, IDIM);
  transconv_kernel<<<dim3(DIM / 64, IDIM / 64), 256, 0, stream>>>(Wd, WDT, IDIM, DIM);

  pack_bias_kernel<<<QKVN / 256, 256, 0, stream>>>(bq, bk, bv, BQKV);

  // x = rmsnorm(hidden, ln1) (bf16)
  rmsnorm_kernel<<<SEQ, 256, 0, stream>>>(hidden, ln1, XB);

  // qkv = x @ Wqkv + b
  gemm_bt_kernel<false><<<(QKVN / 128) * (SEQ / 128), 256, 0, stream>>>(
      XB, WQKVT, BQKV, nullptr, QKV, SEQ, QKVN, DIM, SEQ / 128);

  // mRoPE in-place on q,k
  rope_kernel<<<SEQ, 256, 0, stream>>>(QKV, cosb, sinb);

  // v transpose + column sums
  vtrans_kernel<<<dim3(8, NKVH), 256, 0, stream>>>(QKV, VT, VSUMP);
  vsum_reduce_kernel<<<1, 512, 0, stream>>>(VSUMP, VSUM);

  // attention -> OB (bf16 [1024][3584], head-concat layout)
  attn_kernel<<<dim3(SEQ / 64, NH), 256, 0, stream>>>(QKV, VT, VSUM, prune, OB);

  // h = hidden + OB @ Wo  (f32)
  gemm_bt_kernel<true><<<(DIM / 128) * (SEQ / 128), 256, 0, stream>>>(
      OB, WOT, nullptr, hidden, HB, SEQ, DIM, DIM, SEQ / 128);

  // y = rmsnorm(h, ln2) (bf16)
  rmsnorm_kernel<<<SEQ, 256, 0, stream>>>(HB, ln2, YB);

  // [g|u] = y @ [Wg|Wu]
  gemm_bt_kernel<false><<<(GUN / 128) * (SEQ / 128), 256, 0, stream>>>(
      YB, WGUT, nullptr, nullptr, GU, SEQ, GUN, DIM, SEQ / 128);

  // p = silu(g) * u
  silu_mul_kernel<<<dim3(10, SEQ), 256, 0, stream>>>(GU, PB);

  // out = h + p @ Wd  (f32)
  gemm_bt_kernel<true><<<(DIM / 128) * (SEQ / 128), 256, 0, stream>>>(
      PB, WDT, nullptr, HB, out, SEQ, DIM, IDIM, SEQ / 128);
}

// Round 3
// 1270.749 us; speedup vs baseline: 3.0937x; 1.1463x over previous
//
#include <hip/hip_runtime.h>
#include <hip/hip_bf16.h>

// ---------------------------------------------------------------------------
// Qwen2.5-VL decoder layer, MI355X (gfx950)
// B=1, N=1024, D=3584, H=28, KVH=4, HD=128, I=18944
// Round 3: gate/up GEMM -> 256x256 8-phase schedule (T2 swizzle + T3/T4
// counted vmcnt + T5 setprio). 128x128 GEMMs get the LDS XOR swizzle.
// ---------------------------------------------------------------------------

#define SEQ   1024
#define DIM   3584
#define NH    28
#define NKVH  4
#define HDIM  128
#define IDIM  18944
#define QKVN  4608    // 3584 q + 512 k + 512 v
#define GUN   37888   // 2*18944

typedef __attribute__((ext_vector_type(8))) __bf16 bf16x8;
typedef __attribute__((ext_vector_type(4))) __bf16 bf16x4;
typedef __attribute__((ext_vector_type(4))) float  f32x4;

// ---------------- workspace layout (bytes) ----------------
static constexpr size_t OFF_WQKVT = 0;                                   // [4608][3584] bf16
static constexpr size_t OFF_WOT   = OFF_WQKVT + (size_t)QKVN*DIM*2;      // [3584][3584] bf16
static constexpr size_t OFF_WGUT  = OFF_WOT   + (size_t)DIM*DIM*2;       // [37888][3584] bf16
static constexpr size_t OFF_WDT   = OFF_WGUT  + (size_t)GUN*DIM*2;       // [3584][18944] bf16
static constexpr size_t OFF_XB    = OFF_WDT   + (size_t)DIM*IDIM*2;      // [1024][3584] bf16
static constexpr size_t OFF_QKV   = OFF_XB    + (size_t)SEQ*DIM*2;       // [1024][4608] bf16
static constexpr size_t OFF_VT    = OFF_QKV   + (size_t)SEQ*QKVN*2;      // [4][128][1024] bf16
static constexpr size_t OFF_VSUMP = OFF_VT    + (size_t)NKVH*HDIM*SEQ*2; // [4][8][128] f32
static constexpr size_t OFF_VSUM  = OFF_VSUMP + 4*8*128*4;               // [4][128] f32
static constexpr size_t OFF_BQKV  = OFF_VSUM  + 4*128*4;                 // [4608] f32
static constexpr size_t OFF_OB    = OFF_BQKV  + (size_t)QKVN*4;          // [1024][3584] bf16
static constexpr size_t OFF_HB    = OFF_OB    + (size_t)SEQ*DIM*2;       // [1024][3584] f32
static constexpr size_t OFF_YB    = OFF_HB    + (size_t)SEQ*DIM*4;       // [1024][3584] bf16
static constexpr size_t OFF_GU    = OFF_YB    + (size_t)SEQ*DIM*2;       // [1024][37888] bf16
static constexpr size_t OFF_PB    = OFF_GU    + (size_t)SEQ*GUN*2;       // [1024][18944] bf16

// async global->LDS, 16B per lane. lds ptr must be wave-uniform; HW writes
// lane l's 16B to ldsbase + l*16. global ptr is per-lane.
#define GLL16(gp, lp)                                                        \
  __builtin_amdgcn_global_load_lds(                                         \
      (const __attribute__((address_space(1))) void*)(gp),                  \
      (__attribute__((address_space(3))) void*)(lp), 16, 0, 0)

#define BAR    asm volatile("s_barrier" ::: "memory")
#define SCHEDB __builtin_amdgcn_sched_barrier(0)

// ---------------- weight transpose + fp32->bf16 ----------------
__global__ __launch_bounds__(256) void transconv_kernel(
    const float* __restrict__ W, __bf16* __restrict__ WT, int K, int N)
{
  __shared__ __bf16 t[64][72];
  const int tid = threadIdx.x;
  const int k0 = blockIdx.y * 64, n0 = blockIdx.x * 64;
#pragma unroll
  for (int it = 0; it < 4; ++it) {
    int idx = it * 256 + tid;
    int r = idx >> 4, c4 = idx & 15;
    float4 v = *(const float4*)(W + (size_t)(k0 + r) * N + n0 + c4 * 4);
    t[r][c4 * 4 + 0] = (__bf16)v.x;
    t[r][c4 * 4 + 1] = (__bf16)v.y;
    t[r][c4 * 4 + 2] = (__bf16)v.z;
    t[r][c4 * 4 + 3] = (__bf16)v.w;
  }
  __syncthreads();
#pragma unroll
  for (int it = 0; it < 2; ++it) {
    int idx = it * 256 + tid;
    int r = idx >> 3, c8 = idx & 7;
    bf16x8 o;
#pragma unroll
    for (int i = 0; i < 8; ++i) o[i] = t[c8 * 8 + i][r];
    *(bf16x8*)(WT + (size_t)(n0 + r) * K + k0 + c8 * 8) = o;
  }
}

// ---------------- bias concat ----------------
__global__ __launch_bounds__(256) void pack_bias_kernel(
    const float* __restrict__ bq, const float* __restrict__ bk,
    const float* __restrict__ bv, float* __restrict__ out)
{
  int i = blockIdx.x * 256 + threadIdx.x;
  if (i < DIM) out[i] = bq[i];
  else if (i < DIM + 512) out[i] = bk[i - DIM];
  else if (i < QKVN) out[i] = bv[i - DIM - 512];
}

// ---------------- RMSNorm (fp32 in, bf16 out) ----------------
__global__ __launch_bounds__(256) void rmsnorm_kernel(
    const float* __restrict__ in, const float* __restrict__ w,
    __bf16* __restrict__ out)
{
  const int row = blockIdx.x;
  const int t = threadIdx.x;
  const float* x = in + (size_t)row * DIM;
  float4 v[4];
  float ss = 0.f;
#pragma unroll
  for (int i = 0; i < 4; ++i) {
    int idx = t + i * 256;
    if (idx < 896) {
      v[i] = ((const float4*)x)[idx];
      ss += v[i].x * v[i].x + v[i].y * v[i].y + v[i].z * v[i].z + v[i].w * v[i].w;
    }
  }
#pragma unroll
  for (int m = 1; m < 64; m <<= 1) ss += __shfl_xor(ss, m);
  __shared__ float red[4];
  if ((t & 63) == 0) red[t >> 6] = ss;
  __syncthreads();
  float tot = red[0] + red[1] + red[2] + red[3];
  float rs = rsqrtf(tot / (float)DIM + 1e-6f);
#pragma unroll
  for (int i = 0; i < 4; ++i) {
    int idx = t + i * 256;
    if (idx < 896) {
      float4 wv = ((const float4*)w)[idx];
      bf16x4 o;
      o[0] = (__bf16)(v[i].x * rs * wv.x);
      o[1] = (__bf16)(v[i].y * rs * wv.y);
      o[2] = (__bf16)(v[i].z * rs * wv.z);
      o[3] = (__bf16)(v[i].w * rs * wv.w);
      *(bf16x4*)(out + (size_t)row * DIM + idx * 4) = o;
    }
  }
}

// ---------------- 128x128 GEMM (m97 structure + LDS XOR swizzle) ----------
template<bool F32OUT>
__global__ __launch_bounds__(256, 2) void gemm_bt_kernel(
    const __bf16* __restrict__ A, const __bf16* __restrict__ BT,
    const float* __restrict__ bias, const float* __restrict__ resid,
    void* __restrict__ C, int M, int N, int K, int gridY)
{
  __shared__ __bf16 As[128 * 64];
  __shared__ __bf16 Bs[128 * 64];
  const int tid = threadIdx.x;
  const int l = tid & 63, w = tid >> 6;

  const int nwg = gridDim.x;
  const int bq8 = nwg >> 3, br8 = nwg & 7;
  const int xcd = blockIdx.x & 7, bidx = blockIdx.x >> 3;
  const int wg = (xcd < br8 ? xcd * (bq8 + 1) : br8 * (bq8 + 1) + (xcd - br8) * bq8) + bidx;
  const int tm = wg % gridY;
  const int tn = wg / gridY;
  const int row0 = tm * 128;
  const int col0 = tn * 128;

  const int m0 = (w >> 1) * 64;
  const int n0 = (w & 1) * 64;
  const int lg = l >> 4, lc = l & 15;

  f32x4 acc[4][4] = {};

  size_t aoff[4], boff[4];
  int lbyte[4];
#pragma unroll
  for (int it = 0; it < 4; ++it) {
    const int cbase = (it * 4 + w) * 64;
    const int c = cbase + l;
    const int r = c >> 3, p = c & 7;
    const int b = p ^ (r & 7);           // swizzled source slot
    aoff[it] = (size_t)(row0 + r) * K + b * 8;
    boff[it] = (size_t)(col0 + r) * K + b * 8;
    lbyte[it] = cbase * 16;
  }
  const int sw = lc & 7;

  const int ktc = K >> 6;
  for (int kt = 0; kt < ktc; ++kt) {
    const int k0 = kt << 6;
#pragma unroll
    for (int it = 0; it < 4; ++it) {
      GLL16(A + aoff[it] + k0, (char*)As + lbyte[it]);
      GLL16(BT + boff[it] + k0, (char*)Bs + lbyte[it]);
    }
    __syncthreads();
#pragma unroll
    for (int s = 0; s < 2; ++s) {
      bf16x8 af[4], bfv[4];
#pragma unroll
      for (int a = 0; a < 4; ++a)
        af[a] = *(const bf16x8*)(As + (m0 + a * 16 + lc) * 64 + ((s * 4 + lg) ^ sw) * 8);
#pragma unroll
      for (int b = 0; b < 4; ++b)
        bfv[b] = *(const bf16x8*)(Bs + (n0 + b * 16 + lc) * 64 + ((s * 4 + lg) ^ sw) * 8);
#pragma unroll
      for (int a = 0; a < 4; ++a)
#pragma unroll
        for (int b = 0; b < 4; ++b)
          acc[a][b] = __builtin_amdgcn_mfma_f32_16x16x32_bf16(af[a], bfv[b], acc[a][b], 0, 0, 0);
    }
    __syncthreads();
  }

  const int lr = lg * 4;
#pragma unroll
  for (int b = 0; b < 4; ++b) {
    const int col = col0 + n0 + b * 16 + lc;
    float bias_v = 0.f;
    if (!F32OUT && bias != nullptr) bias_v = bias[col];
#pragma unroll
    for (int a = 0; a < 4; ++a) {
#pragma unroll
      for (int j = 0; j < 4; ++j) {
        const int row = row0 + m0 + a * 16 + lr + j;
        float vv = acc[a][b][j];
        if (F32OUT) {
          ((float*)C)[(size_t)row * N + col] = vv + resid[(size_t)row * N + col];
        } else {
          ((__bf16*)C)[(size_t)row * N + col] = (__bf16)(vv + bias_v);
        }
      }
    }
  }
}

// ---------------- 256x256 8-phase GEMM (T2+T3+T4+T5), bf16 out ------------
// 8 waves (2M x 4N), BK=64, 128KB LDS double-buffer. Per iteration: 2 K-tiles.
// Staging: ph4: A(t0+2)->buf0; ph5: B(t0+2)->buf0; ph8: A+B(t1+2)->buf1.
// Gates: vmcnt(4) at ph4 (protects buf1 tile t1), vmcnt(8) at ph8 (protects
// buf0 tile t0+2). Buffer writes only open after the occupant's last read
// phase (buf0 reads end ph3, buf1 reads end ph7).
__global__ __launch_bounds__(512, 1) void gemm256_kernel(
    const __bf16* __restrict__ A, const __bf16* __restrict__ BT,
    __bf16* __restrict__ C, int M, int N, int K, int gridY)
{
  __shared__ int4 lds4[8192];            // 128 KB
  char* ldsc = (char*)lds4;
  const int tid = threadIdx.x;
  const int l = tid & 63, w = tid >> 6;
  const int wr = w >> 2, wc = w & 3;
  const int lg = l >> 4, lc = l & 15;

  const int nwg = gridDim.x;
  const int bq8 = nwg >> 3, br8 = nwg & 7;
  const int xcd = blockIdx.x & 7, bidx = blockIdx.x >> 3;
  const int wg = (xcd < br8 ? xcd * (bq8 + 1) : br8 * (bq8 + 1) + (xcd - br8) * bq8) + bidx;
  const int row0 = (wg % gridY) * 256;
  const int col0 = (wg / gridY) * 256;

  // staging precompute: unit = 128 rows x 64 k = 16KB; each wave issues 2
  // GLL16 per unit (j=0,1), lane l covers chunk (j*8+w)*64+l.
  size_t aoffj[2], boffj[2];
  int dstj[2];
#pragma unroll
  for (int j = 0; j < 2; ++j) {
    const int c = (j * 8 + w) * 64 + l;
    const int r = c >> 3, p = c & 7;
    const int b = p ^ (r & 7);           // inverse-swizzled source slot
    aoffj[j] = (size_t)(row0 + r) * K + b * 8;
    boffj[j] = (size_t)(col0 + r) * K + b * 8;
    dstj[j] = (j * 8 + w) * 1024;        // wave-uniform LDS byte offset
  }

#define STG_A(U, KT, BUFB) do {                                              \
    GLL16(A + aoffj[0] + (size_t)(U) * 128 * K + (size_t)(KT) * 64,          \
          ldsc + (BUFB) + (U) * 16384 + dstj[0]);                            \
    GLL16(A + aoffj[1] + (size_t)(U) * 128 * K + (size_t)(KT) * 64,          \
          ldsc + (BUFB) + (U) * 16384 + dstj[1]); } while (0)
#define STG_B(U, KT, BUFB) do {                                              \
    GLL16(BT + boffj[0] + (size_t)(U) * 128 * K + (size_t)(KT) * 64,         \
          ldsc + (BUFB) + 32768 + (U) * 16384 + dstj[0]);                    \
    GLL16(BT + boffj[1] + (size_t)(U) * 128 * K + (size_t)(KT) * 64,         \
          ldsc + (BUFB) + 32768 + (U) * 16384 + dstj[1]); } while (0)

  // read address precompute (swizzled slot; row&7 == lc&7)
  const int sw = lc & 7;
  const int rdA = (wr * 128 + lc) * 128;
  const int rdB = 32768 + (wc * 64 + lc) * 128;
  const int sk0 = (lg ^ sw) * 16;
  const int sk1 = ((4 | lg) ^ sw) * 16;

  f32x4 acc[8][4] = {};
  bf16x8 af[4][2], bfr[4][2];

#define RD_A4(MH, BUFB) do { _Pragma("unroll")                               \
    for (int mm = 0; mm < 4; ++mm) {                                         \
      af[mm][0] = *(const bf16x8*)(ldsc + (BUFB) + rdA + ((MH) * 4 + mm) * 2048 + sk0); \
      af[mm][1] = *(const bf16x8*)(ldsc + (BUFB) + rdA + ((MH) * 4 + mm) * 2048 + sk1); } } while (0)
#define RD_B2(NL, BUFB) do { _Pragma("unroll")                               \
    for (int nn = 0; nn < 2; ++nn) {                                         \
      bfr[(NL) + nn][0] = *(const bf16x8*)(ldsc + (BUFB) + rdB + ((NL) + nn) * 2048 + sk0); \
      bfr[(NL) + nn][1] = *(const bf16x8*)(ldsc + (BUFB) + rdB + ((NL) + nn) * 2048 + sk1); } } while (0)

#define MFMA16(MH, NL) do { _Pragma("unroll")                                \
    for (int mm = 0; mm < 4; ++mm) { _Pragma("unroll")                       \
      for (int nn = 0; nn < 2; ++nn) {                                       \
        acc[(MH)*4+mm][(NL)+nn] = __builtin_amdgcn_mfma_f32_16x16x32_bf16(   \
            af[mm][0], bfr[(NL)+nn][0], acc[(MH)*4+mm][(NL)+nn], 0, 0, 0);   \
        acc[(MH)*4+mm][(NL)+nn] = __builtin_amdgcn_mfma_f32_16x16x32_bf16(   \
            af[mm][1], bfr[(NL)+nn][1], acc[(MH)*4+mm][(NL)+nn], 0, 0, 0); } } } while (0)

#define PH_MFMA(MH, NL)                                                      \
    BAR; SCHEDB; __builtin_amdgcn_s_setprio(1);                              \
    MFMA16(MH, NL);                                                          \
    __builtin_amdgcn_s_setprio(0); SCHEDB; BAR

  // prologue: tile0 full -> buf0, tile1 full -> buf1 (16 loads); wait tile0.
  STG_A(0, 0, 0); STG_A(1, 0, 0); STG_B(0, 0, 0); STG_B(1, 0, 0);
  STG_A(0, 1, 65536); STG_A(1, 1, 65536); STG_B(0, 1, 65536); STG_B(1, 1, 65536);
  asm volatile("s_waitcnt vmcnt(8)" ::: "memory");
  BAR;

  const int T = K >> 6;                  // even
#pragma unroll 1
  for (int i = 0; i < (T >> 1); ++i) {
    const int t0 = 2 * i;
    const int se = (t0 + 2 < T) ? t0 + 2 : 0;   // next buf0 tile (dummy at end)
    const int so = (t0 + 3 < T) ? t0 + 3 : 0;   // next buf1 tile (dummy at end)
    // ph1
    RD_A4(0, 0); RD_B2(0, 0);
    PH_MFMA(0, 0);
    // ph2
    RD_B2(2, 0);
    PH_MFMA(0, 2);
    // ph3
    RD_A4(1, 0);
    PH_MFMA(1, 2);
    // ph4 (gate: tile t1 in buf1 must be complete before ph5 reads)
    STG_A(0, se, 0); STG_A(1, se, 0);
    asm volatile("s_waitcnt vmcnt(4)" ::: "memory");
    PH_MFMA(1, 0);
    // ph5
    RD_A4(0, 65536); RD_B2(0, 65536);
    STG_B(0, se, 0); STG_B(1, se, 0);
    PH_MFMA(0, 0);
    // ph6
    RD_B2(2, 65536);
    PH_MFMA(0, 2);
    // ph7
    RD_A4(1, 65536);
    PH_MFMA(1, 2);
    // ph8 (gate: tile se in buf0 must be complete before next ph1 reads)
    STG_A(0, so, 65536); STG_A(1, so, 65536);
    STG_B(0, so, 65536); STG_B(1, so, 65536);
    asm volatile("s_waitcnt vmcnt(8)" ::: "memory");
    PH_MFMA(1, 0);
  }
  asm volatile("s_waitcnt vmcnt(0)" ::: "memory");

#pragma unroll
  for (int m = 0; m < 8; ++m)
#pragma unroll
    for (int n = 0; n < 4; ++n)
#pragma unroll
      for (int j = 0; j < 4; ++j)
        C[(size_t)(row0 + wr * 128 + m * 16 + lg * 4 + j) * N
          + (col0 + wc * 64 + n * 16 + lc)] = (__bf16)acc[m][n][j];
#undef STG_A
#undef STG_B
#undef RD_A4
#undef RD_B2
#undef MFMA16
#undef PH_MFMA
}

// ---------------- mRoPE (in-place on q,k columns of qkv) ----------------
__global__ __launch_bounds__(256) void rope_kernel(
    __bf16* __restrict__ qkv, const float* __restrict__ cosb,
    const float* __restrict__ sinb)
{
  const int n = blockIdx.x;
  for (int p = threadIdx.x; p < 32 * 64; p += 256) {
    const int head = p >> 6;
    const int d = p & 63;
    const int src = (d < 16) ? 0 : (d < 40) ? 1 : 2;
    const float* cb = cosb + (size_t)src * SEQ * HDIM + (size_t)n * HDIM;
    const float* sb = sinb + (size_t)src * SEQ * HDIM + (size_t)n * HDIM;
    const float c0 = cb[d], c1 = cb[d + 64];
    const float s0 = sb[d], s1 = sb[d + 64];
    const int col = (head < NH) ? head * HDIM : DIM + (head - NH) * HDIM;
    __bf16* q = qkv + (size_t)n * QKVN + col;
    const float a = (float)q[d];
    const float b = (float)q[d + 64];
    q[d]      = (__bf16)(a * c0 - b * s0);
    q[d + 64] = (__bf16)(b * c1 + a * s1);
  }
}

// ---------------- V transpose [n][d] -> [d][n], plus column sums -----------
__global__ __launch_bounds__(256) void vtrans_kernel(
    const __bf16* __restrict__ qkv, __bf16* __restrict__ vT,
    float* __restrict__ vsump)
{
  __shared__ __bf16 t[128][132];
  const int nt = blockIdx.x, kvh = blockIdx.y;
  const int n0 = nt * 128;
  const int tid = threadIdx.x;
#pragma unroll
  for (int it = 0; it < 8; ++it) {
    int idx = it * 256 + tid;
    int nl = idx >> 4, c8 = idx & 15;
    bf16x8 v = *(const bf16x8*)(qkv + (size_t)(n0 + nl) * QKVN + 4096 + kvh * HDIM + c8 * 8);
#pragma unroll
    for (int i = 0; i < 8; ++i) t[nl][c8 * 8 + i] = v[i];
  }
  __syncthreads();
#pragma unroll
  for (int it = 0; it < 8; ++it) {
    int idx = it * 256 + tid;
    int d = idx >> 4, c8 = idx & 15;
    bf16x8 o;
#pragma unroll
    for (int i = 0; i < 8; ++i) o[i] = t[c8 * 8 + i][d];
    *(bf16x8*)(vT + (size_t)(kvh * HDIM + d) * SEQ + n0 + c8 * 8) = o;
  }
  if (tid < 128) {
    float s = 0.f;
    for (int nl = 0; nl < 128; ++nl) s += (float)t[nl][tid];
    vsump[(size_t)(kvh * 8 + nt) * 128 + tid] = s;
  }
}

__global__ __launch_bounds__(512) void vsum_reduce_kernel(
    const float* __restrict__ vsump, float* __restrict__ vsum)
{
  const int idx = threadIdx.x;
  const int kvh = idx >> 7, d = idx & 127;
  float s = 0.f;
#pragma unroll
  for (int nt = 0; nt < 8; ++nt) s += vsump[(size_t)(kvh * 8 + nt) * 128 + d];
  vsum[idx] = s;
}

// ---------------- attention -------------------------------------------------
__global__ __launch_bounds__(256) void attn_kernel(
    const __bf16* __restrict__ qkv, const __bf16* __restrict__ vT,
    const float* __restrict__ vsum, const int* __restrict__ prune,
    __bf16* __restrict__ o)
{
  __shared__ __bf16 plds[4 * 16 * 40];
  const int tid = threadIdx.x;
  const int l = tid & 63, w = tid >> 6;
  const int h = blockIdx.y;
  const int kvh = h / 7;
  const int qt = blockIdx.x;
  const int qbase = qt * 64 + w * 16;
  const int lg = l >> 4, lc = l & 15;
  __bf16* pw = plds + w * (16 * 40);

  bf16x8 qf[4];
#pragma unroll
  for (int s = 0; s < 4; ++s)
    qf[s] = *(const bf16x8*)(qkv + (size_t)(qbase + lc) * QKVN + h * HDIM + s * 32 + lg * 8);

  f32x4 oacc[8] = {};
  float mrun[4] = {-3e38f, -3e38f, -3e38f, -3e38f};
  float lrun[4] = {0.f, 0.f, 0.f, 0.f};

  const int kbEnd = ((qbase + 15) >> 5) + 1;
  for (int kb = 0; kb < kbEnd; ++kb) {
    f32x4 sacc[2] = {};
#pragma unroll
    for (int s = 0; s < 4; ++s) {
#pragma unroll
      for (int c = 0; c < 2; ++c) {
        bf16x8 kf = *(const bf16x8*)(qkv + (size_t)(kb * 32 + c * 16 + lc) * QKVN
                                     + DIM + kvh * HDIM + s * 32 + lg * 8);
        sacc[c] = __builtin_amdgcn_mfma_f32_16x16x32_bf16(qf[s], kf, sacc[c], 0, 0, 0);
      }
    }
    float p[2][4];
    int am[2];
#pragma unroll
    for (int c = 0; c < 2; ++c) {
      const int col = kb * 32 + c * 16 + lc;
      am[c] = (prune[col] != 0) ? 1 : 0;
#pragma unroll
      for (int j = 0; j < 4; ++j) {
        const int row = qbase + lg * 4 + j;
        float sv = sacc[c][j] * 0.08838834764831845f;
        p[c][j] = (col <= row) ? sv : -3e38f;
      }
    }
#pragma unroll
    for (int j = 0; j < 4; ++j) {
      float mx = fmaxf(p[0][j], p[1][j]);
      mx = fmaxf(mx, __shfl_xor(mx, 1));
      mx = fmaxf(mx, __shfl_xor(mx, 2));
      mx = fmaxf(mx, __shfl_xor(mx, 4));
      mx = fmaxf(mx, __shfl_xor(mx, 8));
      const float mnew = fmaxf(mrun[j], mx);
      const float scale = __expf(mrun[j] - mnew);
      mrun[j] = mnew;
      const int row = qbase + lg * 4 + j;
      float rs = 0.f;
#pragma unroll
      for (int c = 0; c < 2; ++c) {
        const int col = kb * 32 + c * 16 + lc;
        float e = __expf(p[c][j] - mnew);
        const int keep = (col == row) ? 1 : am[c];
        e = keep ? e : 0.f;
        p[c][j] = e;
        rs += e;
      }
      rs += __shfl_xor(rs, 1);
      rs += __shfl_xor(rs, 2);
      rs += __shfl_xor(rs, 4);
      rs += __shfl_xor(rs, 8);
      lrun[j] = lrun[j] * scale + rs;
#pragma unroll
      for (int df = 0; df < 8; ++df) oacc[df][j] *= scale;
    }
#pragma unroll
    for (int c = 0; c < 2; ++c)
#pragma unroll
      for (int j = 0; j < 4; ++j)
        pw[(lg * 4 + j) * 40 + c * 16 + lc] = (__bf16)p[c][j];
    bf16x8 pa = *(const bf16x8*)(pw + lc * 40 + lg * 8);
#pragma unroll
    for (int df = 0; df < 8; ++df) {
      bf16x8 vf = *(const bf16x8*)(vT + (size_t)(kvh * HDIM + df * 16 + lc) * SEQ + kb * 32 + lg * 8);
      oacc[df] = __builtin_amdgcn_mfma_f32_16x16x32_bf16(pa, vf, oacc[df], 0, 0, 0);
    }
  }
#pragma unroll
  for (int df = 0; df < 8; ++df) {
    const float vs = vsum[kvh * HDIM + df * 16 + lc];
#pragma unroll
    for (int j = 0; j < 4; ++j) {
      const int row = qbase + lg * 4 + j;
      const float denom = lrun[j] + 1e-6f;
      const float val = (oacc[df][j] + 9.765625e-10f * vs) / denom;
      o[(size_t)row * DIM + h * HDIM + df * 16 + lc] = (__bf16)val;
    }
  }
}

// ---------------- SiLU(g) * u ----------------
__global__ __launch_bounds__(256) void silu_mul_kernel(
    const __bf16* __restrict__ gu, __bf16* __restrict__ p)
{
  const int n = blockIdx.y;
  const int i8 = blockIdx.x * 256 + threadIdx.x;
  if (i8 >= IDIM / 8) return;
  bf16x8 g = *(const bf16x8*)(gu + (size_t)n * GUN + i8 * 8);
  bf16x8 u = *(const bf16x8*)(gu + (size_t)n * GUN + IDIM + i8 * 8);
  bf16x8 o;
#pragma unroll
  for (int i = 0; i < 8; ++i) {
    const float gf = (float)g[i];
    const float uf = (float)u[i];
    const float s = gf / (1.f + __expf(-gf));
    o[i] = (__bf16)(s * uf);
  }
  *(bf16x8*)(p + (size_t)n * IDIM + i8 * 8) = o;
}

// ---------------------------------------------------------------------------
extern "C" void kernel_launch(void* const* d_in, const int* in_sizes, int n_in,
                              void* d_out, int out_size, void* d_ws, size_t ws_size,
                              hipStream_t stream) {
  const float* hidden = (const float*)d_in[0];
  const float* cosb   = (const float*)d_in[1];
  const float* sinb   = (const float*)d_in[2];
  const int*   prune  = (const int*)d_in[3];
  const float* Wq     = (const float*)d_in[4];
  const float* bq     = (const float*)d_in[5];
  const float* Wk     = (const float*)d_in[6];
  const float* bk     = (const float*)d_in[7];
  const float* Wv     = (const float*)d_in[8];
  const float* bv     = (const float*)d_in[9];
  const float* Wo     = (const float*)d_in[10];
  const float* ln1    = (const float*)d_in[11];
  const float* ln2    = (const float*)d_in[12];
  const float* Wg     = (const float*)d_in[13];
  const float* Wu     = (const float*)d_in[14];
  const float* Wd     = (const float*)d_in[15];
  float* out = (float*)d_out;
  char* ws = (char*)d_ws;

  __bf16* WQKVT = (__bf16*)(ws + OFF_WQKVT);
  __bf16* WOT   = (__bf16*)(ws + OFF_WOT);
  __bf16* WGUT  = (__bf16*)(ws + OFF_WGUT);
  __bf16* WDT   = (__bf16*)(ws + OFF_WDT);
  __bf16* XB    = (__bf16*)(ws + OFF_XB);
  __bf16* QKV   = (__bf16*)(ws + OFF_QKV);
  __bf16* VT    = (__bf16*)(ws + OFF_VT);
  float*  VSUMP = (float*)(ws + OFF_VSUMP);
  float*  VSUM  = (float*)(ws + OFF_VSUM);
  float*  BQKV  = (float*)(ws + OFF_BQKV);
  __bf16* OB    = (__bf16*)(ws + OFF_OB);
  float*  HB    = (float*)(ws + OFF_HB);
  __bf16* YB    = (__bf16*)(ws + OFF_YB);
  __bf16* GU    = (__bf16*)(ws + OFF_GU);
  __bf16* PB    = (__bf16*)(ws + OFF_PB);

  // weight transpose + convert
  transconv_kernel<<<dim3(DIM / 64, DIM / 64), 256, 0, stream>>>(Wq, WQKVT, DIM, DIM);
  transconv_kernel<<<dim3(512 / 64, DIM / 64), 256, 0, stream>>>(Wk, WQKVT + (size_t)DIM * DIM, DIM, 512);
  transconv_kernel<<<dim3(512 / 64, DIM / 64), 256, 0, stream>>>(Wv, WQKVT + (size_t)4096 * DIM, DIM, 512);
  transconv_kernel<<<dim3(DIM / 64, DIM / 64), 256, 0, stream>>>(Wo, WOT, DIM, DIM);
  transconv_kernel<<<dim3(IDIM / 64, DIM / 64), 256, 0, stream>>>(Wg, WGUT, DIM, IDIM);
  transconv_kernel<<<dim3(IDIM / 64, DIM / 64), 256, 0, stream>>>(Wu, WGUT + (size_t)IDIM * DIM, DIM, IDIM);
  transconv_kernel<<<dim3(DIM / 64, IDIM / 64), 256, 0, stream>>>(Wd, WDT, IDIM, DIM);

  pack_bias_kernel<<<QKVN / 256, 256, 0, stream>>>(bq, bk, bv, BQKV);

  // x = rmsnorm(hidden, ln1)
  rmsnorm_kernel<<<SEQ, 256, 0, stream>>>(hidden, ln1, XB);

  // qkv = x @ Wqkv + b
  gemm_bt_kernel<false><<<(QKVN / 128) * (SEQ / 128), 256, 0, stream>>>(
      XB, WQKVT, BQKV, nullptr, QKV, SEQ, QKVN, DIM, SEQ / 128);

  // mRoPE in-place on q,k
  rope_kernel<<<SEQ, 256, 0, stream>>>(QKV, cosb, sinb);

  // v transpose + column sums
  vtrans_kernel<<<dim3(8, NKVH), 256, 0, stream>>>(QKV, VT, VSUMP);
  vsum_reduce_kernel<<<1, 512, 0, stream>>>(VSUMP, VSUM);

  // attention -> OB
  attn_kernel<<<dim3(SEQ / 64, NH), 256, 0, stream>>>(QKV, VT, VSUM, prune, OB);

  // h = hidden + OB @ Wo  (f32)
  gemm_bt_kernel<true><<<(DIM / 128) * (SEQ / 128), 256, 0, stream>>>(
      OB, WOT, nullptr, hidden, HB, SEQ, DIM, DIM, SEQ / 128);

  // y = rmsnorm(h, ln2)
  rmsnorm_kernel<<<SEQ, 256, 0, stream>>>(HB, ln2, YB);

  // [g|u] = y @ [Wg|Wu]  -- 256x256 8-phase kernel
  gemm256_kernel<<<(GUN / 256) * (SEQ / 256), 512, 0, stream>>>(
      YB, WGUT, GU, SEQ, GUN, DIM, SEQ / 256);

  // p = silu(g) * u
  silu_mul_kernel<<<dim3(10, SEQ), 256, 0, stream>>>(GU, PB);

  // out = h + p @ Wd  (f32)
  gemm_bt_kernel<true><<<(DIM / 128) * (SEQ / 128), 256, 0, stream>>>(
      PB, WDT, nullptr, HB, out, SEQ, DIM, IDIM, SEQ / 128);
}

// Round 4
// 1049.238 us; speedup vs baseline: 3.7468x; 1.2111x over previous
//
#include <hip/hip_runtime.h>
#include <hip/hip_bf16.h>

// ---------------------------------------------------------------------------
// Qwen2.5-VL decoder layer, MI355X (gfx950)
// B=1, N=1024, D=3584, H=28, KVH=4, HD=128, I=18944
// Round 4: thin GEMMs (QKV / Wo / down) -> split-K with f32 partials +
// fused reduce epilogues. Partial buffer aliases the (dead at use) GU region.
// ---------------------------------------------------------------------------

#define SEQ   1024
#define DIM   3584
#define NH    28
#define NKVH  4
#define HDIM  128
#define IDIM  18944
#define QKVN  4608    // 3584 q + 512 k + 512 v
#define GUN   37888   // 2*18944

typedef __attribute__((ext_vector_type(8))) __bf16 bf16x8;
typedef __attribute__((ext_vector_type(4))) __bf16 bf16x4;
typedef __attribute__((ext_vector_type(4))) float  f32x4;

// ---------------- workspace layout (bytes) ----------------
static constexpr size_t OFF_WQKVT = 0;                                   // [4608][3584] bf16
static constexpr size_t OFF_WOT   = OFF_WQKVT + (size_t)QKVN*DIM*2;      // [3584][3584] bf16
static constexpr size_t OFF_WGUT  = OFF_WOT   + (size_t)DIM*DIM*2;       // [37888][3584] bf16
static constexpr size_t OFF_WDT   = OFF_WGUT  + (size_t)GUN*DIM*2;       // [3584][18944] bf16
static constexpr size_t OFF_XB    = OFF_WDT   + (size_t)DIM*IDIM*2;      // [1024][3584] bf16
static constexpr size_t OFF_QKV   = OFF_XB    + (size_t)SEQ*DIM*2;       // [1024][4608] bf16
static constexpr size_t OFF_VT    = OFF_QKV   + (size_t)SEQ*QKVN*2;      // [4][128][1024] bf16
static constexpr size_t OFF_VSUMP = OFF_VT    + (size_t)NKVH*HDIM*SEQ*2; // [4][8][128] f32
static constexpr size_t OFF_VSUM  = OFF_VSUMP + 4*8*128*4;               // [4][128] f32
static constexpr size_t OFF_BQKV  = OFF_VSUM  + 4*128*4;                 // [4608] f32
static constexpr size_t OFF_OB    = OFF_BQKV  + (size_t)QKVN*4;          // [1024][3584] bf16
static constexpr size_t OFF_HB    = OFF_OB    + (size_t)SEQ*DIM*2;       // [1024][3584] f32
static constexpr size_t OFF_YB    = OFF_HB    + (size_t)SEQ*DIM*4;       // [1024][3584] bf16
static constexpr size_t OFF_GU    = OFF_YB    + (size_t)SEQ*DIM*2;       // [1024][37888] bf16
static constexpr size_t OFF_PB    = OFF_GU    + (size_t)SEQ*GUN*2;       // [1024][18944] bf16
// split-K f32 partials alias GU (dead at all split-K use sites); max 4*M*3584*4
// = 58.7 MB < 77.6 MB GU region, and never overlaps PB.
static constexpr size_t OFF_PART  = OFF_GU;

// async global->LDS, 16B per lane. lds ptr must be wave-uniform; HW writes
// lane l's 16B to ldsbase + l*16. global ptr is per-lane.
#define GLL16(gp, lp)                                                        \
  __builtin_amdgcn_global_load_lds(                                         \
      (const __attribute__((address_space(1))) void*)(gp),                  \
      (__attribute__((address_space(3))) void*)(lp), 16, 0, 0)

#define BAR    asm volatile("s_barrier" ::: "memory")
#define SCHEDB __builtin_amdgcn_sched_barrier(0)

// ---------------- weight transpose + fp32->bf16 ----------------
__global__ __launch_bounds__(256) void transconv_kernel(
    const float* __restrict__ W, __bf16* __restrict__ WT, int K, int N)
{
  __shared__ __bf16 t[64][72];
  const int tid = threadIdx.x;
  const int k0 = blockIdx.y * 64, n0 = blockIdx.x * 64;
#pragma unroll
  for (int it = 0; it < 4; ++it) {
    int idx = it * 256 + tid;
    int r = idx >> 4, c4 = idx & 15;
    float4 v = *(const float4*)(W + (size_t)(k0 + r) * N + n0 + c4 * 4);
    t[r][c4 * 4 + 0] = (__bf16)v.x;
    t[r][c4 * 4 + 1] = (__bf16)v.y;
    t[r][c4 * 4 + 2] = (__bf16)v.z;
    t[r][c4 * 4 + 3] = (__bf16)v.w;
  }
  __syncthreads();
#pragma unroll
  for (int it = 0; it < 2; ++it) {
    int idx = it * 256 + tid;
    int r = idx >> 3, c8 = idx & 7;
    bf16x8 o;
#pragma unroll
    for (int i = 0; i < 8; ++i) o[i] = t[c8 * 8 + i][r];
    *(bf16x8*)(WT + (size_t)(n0 + r) * K + k0 + c8 * 8) = o;
  }
}

// ---------------- bias concat ----------------
__global__ __launch_bounds__(256) void pack_bias_kernel(
    const float* __restrict__ bq, const float* __restrict__ bk,
    const float* __restrict__ bv, float* __restrict__ out)
{
  int i = blockIdx.x * 256 + threadIdx.x;
  if (i < DIM) out[i] = bq[i];
  else if (i < DIM + 512) out[i] = bk[i - DIM];
  else if (i < QKVN) out[i] = bv[i - DIM - 512];
}

// ---------------- RMSNorm (fp32 in, bf16 out) ----------------
__global__ __launch_bounds__(256) void rmsnorm_kernel(
    const float* __restrict__ in, const float* __restrict__ w,
    __bf16* __restrict__ out)
{
  const int row = blockIdx.x;
  const int t = threadIdx.x;
  const float* x = in + (size_t)row * DIM;
  float4 v[4];
  float ss = 0.f;
#pragma unroll
  for (int i = 0; i < 4; ++i) {
    int idx = t + i * 256;
    if (idx < 896) {
      v[i] = ((const float4*)x)[idx];
      ss += v[i].x * v[i].x + v[i].y * v[i].y + v[i].z * v[i].z + v[i].w * v[i].w;
    }
  }
#pragma unroll
  for (int m = 1; m < 64; m <<= 1) ss += __shfl_xor(ss, m);
  __shared__ float red[4];
  if ((t & 63) == 0) red[t >> 6] = ss;
  __syncthreads();
  float tot = red[0] + red[1] + red[2] + red[3];
  float rs = rsqrtf(tot / (float)DIM + 1e-6f);
#pragma unroll
  for (int i = 0; i < 4; ++i) {
    int idx = t + i * 256;
    if (idx < 896) {
      float4 wv = ((const float4*)w)[idx];
      bf16x4 o;
      o[0] = (__bf16)(v[i].x * rs * wv.x);
      o[1] = (__bf16)(v[i].y * rs * wv.y);
      o[2] = (__bf16)(v[i].z * rs * wv.z);
      o[3] = (__bf16)(v[i].w * rs * wv.w);
      *(bf16x4*)(out + (size_t)row * DIM + idx * 4) = o;
    }
  }
}

// ---------------- 128x128 split-K GEMM -> f32 partials ---------------------
// PART[ks][row][col] = A[row][ks*Kc:+Kc] @ BT[col][ks*Kc:+Kc]^T
// m97 structure + LDS XOR swizzle + bijective XCD swizzle. grid = gy*gx*S.
__global__ __launch_bounds__(256, 2) void gemm_splitk_kernel(
    const __bf16* __restrict__ A, const __bf16* __restrict__ BT,
    float* __restrict__ PART, int M, int N, int K, int Kc, int gridY)
{
  __shared__ __bf16 As[128 * 64];
  __shared__ __bf16 Bs[128 * 64];
  const int tid = threadIdx.x;
  const int l = tid & 63, w = tid >> 6;

  const int nwg = gridDim.x;
  const int bq8 = nwg >> 3, br8 = nwg & 7;
  const int xcd = blockIdx.x & 7, bidx = blockIdx.x >> 3;
  const int wg = (xcd < br8 ? xcd * (bq8 + 1) : br8 * (bq8 + 1) + (xcd - br8) * bq8) + bidx;
  const int tm = wg % gridY;           // M fastest: consecutive wg share (tn,ks) B-panel
  const int wg2 = wg / gridY;
  const int gridX = N >> 7;
  const int tn = wg2 % gridX;
  const int ks = wg2 / gridX;
  const int row0 = tm * 128;
  const int col0 = tn * 128;
  const int kbase = ks * Kc;

  const int m0 = (w >> 1) * 64;
  const int n0 = (w & 1) * 64;
  const int lg = l >> 4, lc = l & 15;

  f32x4 acc[4][4] = {};

  size_t aoff[4], boff[4];
  int lbyte[4];
#pragma unroll
  for (int it = 0; it < 4; ++it) {
    const int cbase = (it * 4 + w) * 64;
    const int c = cbase + l;
    const int r = c >> 3, p = c & 7;
    const int b = p ^ (r & 7);           // inverse-swizzled source slot
    aoff[it] = (size_t)(row0 + r) * K + kbase + b * 8;
    boff[it] = (size_t)(col0 + r) * K + kbase + b * 8;
    lbyte[it] = cbase * 16;
  }
  const int sw = lc & 7;

  const int ktc = Kc >> 6;
  for (int kt = 0; kt < ktc; ++kt) {
    const int k0 = kt << 6;
#pragma unroll
    for (int it = 0; it < 4; ++it) {
      GLL16(A + aoff[it] + k0, (char*)As + lbyte[it]);
      GLL16(BT + boff[it] + k0, (char*)Bs + lbyte[it]);
    }
    __syncthreads();
#pragma unroll
    for (int s = 0; s < 2; ++s) {
      bf16x8 af[4], bfv[4];
#pragma unroll
      for (int a = 0; a < 4; ++a)
        af[a] = *(const bf16x8*)(As + (m0 + a * 16 + lc) * 64 + ((s * 4 + lg) ^ sw) * 8);
#pragma unroll
      for (int b = 0; b < 4; ++b)
        bfv[b] = *(const bf16x8*)(Bs + (n0 + b * 16 + lc) * 64 + ((s * 4 + lg) ^ sw) * 8);
#pragma unroll
      for (int a = 0; a < 4; ++a)
#pragma unroll
        for (int b = 0; b < 4; ++b)
          acc[a][b] = __builtin_amdgcn_mfma_f32_16x16x32_bf16(af[a], bfv[b], acc[a][b], 0, 0, 0);
    }
    __syncthreads();
  }

  float* P = PART + (size_t)ks * M * N;
  const int lr = lg * 4;
#pragma unroll
  for (int b = 0; b < 4; ++b) {
    const int col = col0 + n0 + b * 16 + lc;
#pragma unroll
    for (int a = 0; a < 4; ++a)
#pragma unroll
      for (int j = 0; j < 4; ++j)
        P[(size_t)(row0 + m0 + a * 16 + lr + j) * N + col] = acc[a][b][j];
  }
}

// ---------------- split-K reduce epilogues ---------------------------------
// out = sum_s part[s] (+bias | +resid); BF16OUT selects output type.
template<int S, bool BF16OUT, bool BIAS>
__global__ __launch_bounds__(256) void reduce_kernel(
    const float* __restrict__ part, const float* __restrict__ resid,
    const float* __restrict__ bias, void* __restrict__ out, int N, int MN4)
{
  const int i4 = blockIdx.x * 256 + threadIdx.x;
  if (i4 >= MN4) return;
  const size_t base = (size_t)i4 * 4;
  f32x4 s = *(const f32x4*)(part + base);
#pragma unroll
  for (int k = 1; k < S; ++k)
    s += *(const f32x4*)(part + (size_t)k * MN4 * 4 + base);
  if (BIAS) {
    const int col = (int)(base % N);
    s += *(const f32x4*)(bias + col);
  }
  if (resid != nullptr) s += *(const f32x4*)(resid + base);
  if (BF16OUT) {
    bf16x4 o;
#pragma unroll
    for (int j = 0; j < 4; ++j) o[j] = (__bf16)s[j];
    *(bf16x4*)((__bf16*)out + base) = o;
  } else {
    *(f32x4*)((float*)out + base) = s;
  }
}

// ---------------- 256x256 8-phase GEMM (T2+T3+T4+T5), bf16 out ------------
__global__ __launch_bounds__(512, 1) void gemm256_kernel(
    const __bf16* __restrict__ A, const __bf16* __restrict__ BT,
    __bf16* __restrict__ C, int M, int N, int K, int gridY)
{
  __shared__ int4 lds4[8192];            // 128 KB
  char* ldsc = (char*)lds4;
  const int tid = threadIdx.x;
  const int l = tid & 63, w = tid >> 6;
  const int wr = w >> 2, wc = w & 3;
  const int lg = l >> 4, lc = l & 15;

  const int nwg = gridDim.x;
  const int bq8 = nwg >> 3, br8 = nwg & 7;
  const int xcd = blockIdx.x & 7, bidx = blockIdx.x >> 3;
  const int wg = (xcd < br8 ? xcd * (bq8 + 1) : br8 * (bq8 + 1) + (xcd - br8) * bq8) + bidx;
  const int row0 = (wg % gridY) * 256;
  const int col0 = (wg / gridY) * 256;

  size_t aoffj[2], boffj[2];
  int dstj[2];
#pragma unroll
  for (int j = 0; j < 2; ++j) {
    const int c = (j * 8 + w) * 64 + l;
    const int r = c >> 3, p = c & 7;
    const int b = p ^ (r & 7);
    aoffj[j] = (size_t)(row0 + r) * K + b * 8;
    boffj[j] = (size_t)(col0 + r) * K + b * 8;
    dstj[j] = (j * 8 + w) * 1024;
  }

#define STG_A(U, KT, BUFB) do {                                              \
    GLL16(A + aoffj[0] + (size_t)(U) * 128 * K + (size_t)(KT) * 64,          \
          ldsc + (BUFB) + (U) * 16384 + dstj[0]);                            \
    GLL16(A + aoffj[1] + (size_t)(U) * 128 * K + (size_t)(KT) * 64,          \
          ldsc + (BUFB) + (U) * 16384 + dstj[1]); } while (0)
#define STG_B(U, KT, BUFB) do {                                              \
    GLL16(BT + boffj[0] + (size_t)(U) * 128 * K + (size_t)(KT) * 64,         \
          ldsc + (BUFB) + 32768 + (U) * 16384 + dstj[0]);                    \
    GLL16(BT + boffj[1] + (size_t)(U) * 128 * K + (size_t)(KT) * 64,         \
          ldsc + (BUFB) + 32768 + (U) * 16384 + dstj[1]); } while (0)

  const int sw = lc & 7;
  const int rdA = (wr * 128 + lc) * 128;
  const int rdB = 32768 + (wc * 64 + lc) * 128;
  const int sk0 = (lg ^ sw) * 16;
  const int sk1 = ((4 | lg) ^ sw) * 16;

  f32x4 acc[8][4] = {};
  bf16x8 af[4][2], bfr[4][2];

#define RD_A4(MH, BUFB) do { _Pragma("unroll")                               \
    for (int mm = 0; mm < 4; ++mm) {                                         \
      af[mm][0] = *(const bf16x8*)(ldsc + (BUFB) + rdA + ((MH) * 4 + mm) * 2048 + sk0); \
      af[mm][1] = *(const bf16x8*)(ldsc + (BUFB) + rdA + ((MH) * 4 + mm) * 2048 + sk1); } } while (0)
#define RD_B2(NL, BUFB) do { _Pragma("unroll")                               \
    for (int nn = 0; nn < 2; ++nn) {                                         \
      bfr[(NL) + nn][0] = *(const bf16x8*)(ldsc + (BUFB) + rdB + ((NL) + nn) * 2048 + sk0); \
      bfr[(NL) + nn][1] = *(const bf16x8*)(ldsc + (BUFB) + rdB + ((NL) + nn) * 2048 + sk1); } } while (0)

#define MFMA16(MH, NL) do { _Pragma("unroll")                                \
    for (int mm = 0; mm < 4; ++mm) { _Pragma("unroll")                       \
      for (int nn = 0; nn < 2; ++nn) {                                       \
        acc[(MH)*4+mm][(NL)+nn] = __builtin_amdgcn_mfma_f32_16x16x32_bf16(   \
            af[mm][0], bfr[(NL)+nn][0], acc[(MH)*4+mm][(NL)+nn], 0, 0, 0);   \
        acc[(MH)*4+mm][(NL)+nn] = __builtin_amdgcn_mfma_f32_16x16x32_bf16(   \
            af[mm][1], bfr[(NL)+nn][1], acc[(MH)*4+mm][(NL)+nn], 0, 0, 0); } } } while (0)

#define PH_MFMA(MH, NL)                                                      \
    BAR; SCHEDB; __builtin_amdgcn_s_setprio(1);                              \
    MFMA16(MH, NL);                                                          \
    __builtin_amdgcn_s_setprio(0); SCHEDB; BAR

  STG_A(0, 0, 0); STG_A(1, 0, 0); STG_B(0, 0, 0); STG_B(1, 0, 0);
  STG_A(0, 1, 65536); STG_A(1, 1, 65536); STG_B(0, 1, 65536); STG_B(1, 1, 65536);
  asm volatile("s_waitcnt vmcnt(8)" ::: "memory");
  BAR;

  const int T = K >> 6;                  // even
#pragma unroll 1
  for (int i = 0; i < (T >> 1); ++i) {
    const int t0 = 2 * i;
    const int se = (t0 + 2 < T) ? t0 + 2 : 0;
    const int so = (t0 + 3 < T) ? t0 + 3 : 0;
    RD_A4(0, 0); RD_B2(0, 0);
    PH_MFMA(0, 0);
    RD_B2(2, 0);
    PH_MFMA(0, 2);
    RD_A4(1, 0);
    PH_MFMA(1, 2);
    STG_A(0, se, 0); STG_A(1, se, 0);
    asm volatile("s_waitcnt vmcnt(4)" ::: "memory");
    PH_MFMA(1, 0);
    RD_A4(0, 65536); RD_B2(0, 65536);
    STG_B(0, se, 0); STG_B(1, se, 0);
    PH_MFMA(0, 0);
    RD_B2(2, 65536);
    PH_MFMA(0, 2);
    RD_A4(1, 65536);
    PH_MFMA(1, 2);
    STG_A(0, so, 65536); STG_A(1, so, 65536);
    STG_B(0, so, 65536); STG_B(1, so, 65536);
    asm volatile("s_waitcnt vmcnt(8)" ::: "memory");
    PH_MFMA(1, 0);
  }
  asm volatile("s_waitcnt vmcnt(0)" ::: "memory");

#pragma unroll
  for (int m = 0; m < 8; ++m)
#pragma unroll
    for (int n = 0; n < 4; ++n)
#pragma unroll
      for (int j = 0; j < 4; ++j)
        C[(size_t)(row0 + wr * 128 + m * 16 + lg * 4 + j) * N
          + (col0 + wc * 64 + n * 16 + lc)] = (__bf16)acc[m][n][j];
#undef STG_A
#undef STG_B
#undef RD_A4
#undef RD_B2
#undef MFMA16
#undef PH_MFMA
}

// ---------------- mRoPE (in-place on q,k columns of qkv) ----------------
__global__ __launch_bounds__(256) void rope_kernel(
    __bf16* __restrict__ qkv, const float* __restrict__ cosb,
    const float* __restrict__ sinb)
{
  const int n = blockIdx.x;
  for (int p = threadIdx.x; p < 32 * 64; p += 256) {
    const int head = p >> 6;
    const int d = p & 63;
    const int src = (d < 16) ? 0 : (d < 40) ? 1 : 2;
    const float* cb = cosb + (size_t)src * SEQ * HDIM + (size_t)n * HDIM;
    const float* sb = sinb + (size_t)src * SEQ * HDIM + (size_t)n * HDIM;
    const float c0 = cb[d], c1 = cb[d + 64];
    const float s0 = sb[d], s1 = sb[d + 64];
    const int col = (head < NH) ? head * HDIM : DIM + (head - NH) * HDIM;
    __bf16* q = qkv + (size_t)n * QKVN + col;
    const float a = (float)q[d];
    const float b = (float)q[d + 64];
    q[d]      = (__bf16)(a * c0 - b * s0);
    q[d + 64] = (__bf16)(b * c1 + a * s1);
  }
}

// ---------------- V transpose [n][d] -> [d][n], plus column sums -----------
__global__ __launch_bounds__(256) void vtrans_kernel(
    const __bf16* __restrict__ qkv, __bf16* __restrict__ vT,
    float* __restrict__ vsump)
{
  __shared__ __bf16 t[128][132];
  const int nt = blockIdx.x, kvh = blockIdx.y;
  const int n0 = nt * 128;
  const int tid = threadIdx.x;
#pragma unroll
  for (int it = 0; it < 8; ++it) {
    int idx = it * 256 + tid;
    int nl = idx >> 4, c8 = idx & 15;
    bf16x8 v = *(const bf16x8*)(qkv + (size_t)(n0 + nl) * QKVN + 4096 + kvh * HDIM + c8 * 8);
#pragma unroll
    for (int i = 0; i < 8; ++i) t[nl][c8 * 8 + i] = v[i];
  }
  __syncthreads();
#pragma unroll
  for (int it = 0; it < 8; ++it) {
    int idx = it * 256 + tid;
    int d = idx >> 4, c8 = idx & 15;
    bf16x8 o;
#pragma unroll
    for (int i = 0; i < 8; ++i) o[i] = t[c8 * 8 + i][d];
    *(bf16x8*)(vT + (size_t)(kvh * HDIM + d) * SEQ + n0 + c8 * 8) = o;
  }
  if (tid < 128) {
    float s = 0.f;
    for (int nl = 0; nl < 128; ++nl) s += (float)t[nl][tid];
    vsump[(size_t)(kvh * 8 + nt) * 128 + tid] = s;
  }
}

__global__ __launch_bounds__(512) void vsum_reduce_kernel(
    const float* __restrict__ vsump, float* __restrict__ vsum)
{
  const int idx = threadIdx.x;
  const int kvh = idx >> 7, d = idx & 127;
  float s = 0.f;
#pragma unroll
  for (int nt = 0; nt < 8; ++nt) s += vsump[(size_t)(kvh * 8 + nt) * 128 + d];
  vsum[idx] = s;
}

// ---------------- attention -------------------------------------------------
__global__ __launch_bounds__(256) void attn_kernel(
    const __bf16* __restrict__ qkv, const __bf16* __restrict__ vT,
    const float* __restrict__ vsum, const int* __restrict__ prune,
    __bf16* __restrict__ o)
{
  __shared__ __bf16 plds[4 * 16 * 40];
  const int tid = threadIdx.x;
  const int l = tid & 63, w = tid >> 6;
  const int h = blockIdx.y;
  const int kvh = h / 7;
  const int qt = blockIdx.x;
  const int qbase = qt * 64 + w * 16;
  const int lg = l >> 4, lc = l & 15;
  __bf16* pw = plds + w * (16 * 40);

  bf16x8 qf[4];
#pragma unroll
  for (int s = 0; s < 4; ++s)
    qf[s] = *(const bf16x8*)(qkv + (size_t)(qbase + lc) * QKVN + h * HDIM + s * 32 + lg * 8);

  f32x4 oacc[8] = {};
  float mrun[4] = {-3e38f, -3e38f, -3e38f, -3e38f};
  float lrun[4] = {0.f, 0.f, 0.f, 0.f};

  const int kbEnd = ((qbase + 15) >> 5) + 1;
  for (int kb = 0; kb < kbEnd; ++kb) {
    f32x4 sacc[2] = {};
#pragma unroll
    for (int s = 0; s < 4; ++s) {
#pragma unroll
      for (int c = 0; c < 2; ++c) {
        bf16x8 kf = *(const bf16x8*)(qkv + (size_t)(kb * 32 + c * 16 + lc) * QKVN
                                     + DIM + kvh * HDIM + s * 32 + lg * 8);
        sacc[c] = __builtin_amdgcn_mfma_f32_16x16x32_bf16(qf[s], kf, sacc[c], 0, 0, 0);
      }
    }
    float p[2][4];
    int am[2];
#pragma unroll
    for (int c = 0; c < 2; ++c) {
      const int col = kb * 32 + c * 16 + lc;
      am[c] = (prune[col] != 0) ? 1 : 0;
#pragma unroll
      for (int j = 0; j < 4; ++j) {
        const int row = qbase + lg * 4 + j;
        float sv = sacc[c][j] * 0.08838834764831845f;
        p[c][j] = (col <= row) ? sv : -3e38f;
      }
    }
#pragma unroll
    for (int j = 0; j < 4; ++j) {
      float mx = fmaxf(p[0][j], p[1][j]);
      mx = fmaxf(mx, __shfl_xor(mx, 1));
      mx = fmaxf(mx, __shfl_xor(mx, 2));
      mx = fmaxf(mx, __shfl_xor(mx, 4));
      mx = fmaxf(mx, __shfl_xor(mx, 8));
      const float mnew = fmaxf(mrun[j], mx);
      const float scale = __expf(mrun[j] - mnew);
      mrun[j] = mnew;
      const int row = qbase + lg * 4 + j;
      float rs = 0.f;
#pragma unroll
      for (int c = 0; c < 2; ++c) {
        const int col = kb * 32 + c * 16 + lc;
        float e = __expf(p[c][j] - mnew);
        const int keep = (col == row) ? 1 : am[c];
        e = keep ? e : 0.f;
        p[c][j] = e;
        rs += e;
      }
      rs += __shfl_xor(rs, 1);
      rs += __shfl_xor(rs, 2);
      rs += __shfl_xor(rs, 4);
      rs += __shfl_xor(rs, 8);
      lrun[j] = lrun[j] * scale + rs;
#pragma unroll
      for (int df = 0; df < 8; ++df) oacc[df][j] *= scale;
    }
#pragma unroll
    for (int c = 0; c < 2; ++c)
#pragma unroll
      for (int j = 0; j < 4; ++j)
        pw[(lg * 4 + j) * 40 + c * 16 + lc] = (__bf16)p[c][j];
    bf16x8 pa = *(const bf16x8*)(pw + lc * 40 + lg * 8);
#pragma unroll
    for (int df = 0; df < 8; ++df) {
      bf16x8 vf = *(const bf16x8*)(vT + (size_t)(kvh * HDIM + df * 16 + lc) * SEQ + kb * 32 + lg * 8);
      oacc[df] = __builtin_amdgcn_mfma_f32_16x16x32_bf16(pa, vf, oacc[df], 0, 0, 0);
    }
  }
#pragma unroll
  for (int df = 0; df < 8; ++df) {
    const float vs = vsum[kvh * HDIM + df * 16 + lc];
#pragma unroll
    for (int j = 0; j < 4; ++j) {
      const int row = qbase + lg * 4 + j;
      const float denom = lrun[j] + 1e-6f;
      const float val = (oacc[df][j] + 9.765625e-10f * vs) / denom;
      o[(size_t)row * DIM + h * HDIM + df * 16 + lc] = (__bf16)val;
    }
  }
}

// ---------------- SiLU(g) * u ----------------
__global__ __launch_bounds__(256) void silu_mul_kernel(
    const __bf16* __restrict__ gu, __bf16* __restrict__ p)
{
  const int n = blockIdx.y;
  const int i8 = blockIdx.x * 256 + threadIdx.x;
  if (i8 >= IDIM / 8) return;
  bf16x8 g = *(const bf16x8*)(gu + (size_t)n * GUN + i8 * 8);
  bf16x8 u = *(const bf16x8*)(gu + (size_t)n * GUN + IDIM + i8 * 8);
  bf16x8 o;
#pragma unroll
  for (int i = 0; i < 8; ++i) {
    const float gf = (float)g[i];
    const float uf = (float)u[i];
    const float s = gf / (1.f + __expf(-gf));
    o[i] = (__bf16)(s * uf);
  }
  *(bf16x8*)(p + (size_t)n * IDIM + i8 * 8) = o;
}

// ---------------------------------------------------------------------------
extern "C" void kernel_launch(void* const* d_in, const int* in_sizes, int n_in,
                              void* d_out, int out_size, void* d_ws, size_t ws_size,
                              hipStream_t stream) {
  const float* hidden = (const float*)d_in[0];
  const float* cosb   = (const float*)d_in[1];
  const float* sinb   = (const float*)d_in[2];
  const int*   prune  = (const int*)d_in[3];
  const float* Wq     = (const float*)d_in[4];
  const float* bq     = (const float*)d_in[5];
  const float* Wk     = (const float*)d_in[6];
  const float* bk     = (const float*)d_in[7];
  const float* Wv     = (const float*)d_in[8];
  const float* bv     = (const float*)d_in[9];
  const float* Wo     = (const float*)d_in[10];
  const float* ln1    = (const float*)d_in[11];
  const float* ln2    = (const float*)d_in[12];
  const float* Wg     = (const float*)d_in[13];
  const float* Wu     = (const float*)d_in[14];
  const float* Wd     = (const float*)d_in[15];
  float* out = (float*)d_out;
  char* ws = (char*)d_ws;

  __bf16* WQKVT = (__bf16*)(ws + OFF_WQKVT);
  __bf16* WOT   = (__bf16*)(ws + OFF_WOT);
  __bf16* WGUT  = (__bf16*)(ws + OFF_WGUT);
  __bf16* WDT   = (__bf16*)(ws + OFF_WDT);
  __bf16* XB    = (__bf16*)(ws + OFF_XB);
  __bf16* QKV   = (__bf16*)(ws + OFF_QKV);
  __bf16* VT    = (__bf16*)(ws + OFF_VT);
  float*  VSUMP = (float*)(ws + OFF_VSUMP);
  float*  VSUM  = (float*)(ws + OFF_VSUM);
  float*  BQKV  = (float*)(ws + OFF_BQKV);
  __bf16* OB    = (__bf16*)(ws + OFF_OB);
  float*  HB    = (float*)(ws + OFF_HB);
  __bf16* YB    = (__bf16*)(ws + OFF_YB);
  __bf16* GU    = (__bf16*)(ws + OFF_GU);
  __bf16* PB    = (__bf16*)(ws + OFF_PB);
  float*  PART  = (float*)(ws + OFF_PART);

  // weight transpose + convert
  transconv_kernel<<<dim3(DIM / 64, DIM / 64), 256, 0, stream>>>(Wq, WQKVT, DIM, DIM);
  transconv_kernel<<<dim3(512 / 64, DIM / 64), 256, 0, stream>>>(Wk, WQKVT + (size_t)DIM * DIM, DIM, 512);
  transconv_kernel<<<dim3(512 / 64, DIM / 64), 256, 0, stream>>>(Wv, WQKVT + (size_t)4096 * DIM, DIM, 512);
  transconv_kernel<<<dim3(DIM / 64, DIM / 64), 256, 0, stream>>>(Wo, WOT, DIM, DIM);
  transconv_kernel<<<dim3(IDIM / 64, DIM / 64), 256, 0, stream>>>(Wg, WGUT, DIM, IDIM);
  transconv_kernel<<<dim3(IDIM / 64, DIM / 64), 256, 0, stream>>>(Wu, WGUT + (size_t)IDIM * DIM, DIM, IDIM);
  transconv_kernel<<<dim3(DIM / 64, IDIM / 64), 256, 0, stream>>>(Wd, WDT, IDIM, DIM);

  pack_bias_kernel<<<QKVN / 256, 256, 0, stream>>>(bq, bk, bv, BQKV);

  // x = rmsnorm(hidden, ln1)
  rmsnorm_kernel<<<SEQ, 256, 0, stream>>>(hidden, ln1, XB);

  // qkv = x @ Wqkv + b  (split-K 2)
  gemm_splitk_kernel<<<(QKVN / 128) * (SEQ / 128) * 2, 256, 0, stream>>>(
      XB, WQKVT, PART, SEQ, QKVN, DIM, DIM / 2, SEQ / 128);
  reduce_kernel<2, true, true><<<(SEQ * QKVN / 4 + 255) / 256, 256, 0, stream>>>(
      PART, nullptr, BQKV, QKV, QKVN, SEQ * QKVN / 4);

  // mRoPE in-place on q,k
  rope_kernel<<<SEQ, 256, 0, stream>>>(QKV, cosb, sinb);

  // v transpose + column sums
  vtrans_kernel<<<dim3(8, NKVH), 256, 0, stream>>>(QKV, VT, VSUMP);
  vsum_reduce_kernel<<<1, 512, 0, stream>>>(VSUMP, VSUM);

  // attention -> OB
  attn_kernel<<<dim3(SEQ / 64, NH), 256, 0, stream>>>(QKV, VT, VSUM, prune, OB);

  // h = hidden + OB @ Wo  (split-K 2, f32 out)
  gemm_splitk_kernel<<<(DIM / 128) * (SEQ / 128) * 2, 256, 0, stream>>>(
      OB, WOT, PART, SEQ, DIM, DIM, DIM / 2, SEQ / 128);
  reduce_kernel<2, false, false><<<(SEQ * DIM / 4 + 255) / 256, 256, 0, stream>>>(
      PART, hidden, nullptr, HB, DIM, SEQ * DIM / 4);

  // y = rmsnorm(h, ln2)
  rmsnorm_kernel<<<SEQ, 256, 0, stream>>>(HB, ln2, YB);

  // [g|u] = y @ [Wg|Wu]  -- 256x256 8-phase kernel
  gemm256_kernel<<<(GUN / 256) * (SEQ / 256), 512, 0, stream>>>(
      YB, WGUT, GU, SEQ, GUN, DIM, SEQ / 256);

  // p = silu(g) * u
  silu_mul_kernel<<<dim3(10, SEQ), 256, 0, stream>>>(GU, PB);

  // out = h + p @ Wd  (split-K 4, f32 out; PART aliases GU which is now dead)
  gemm_splitk_kernel<<<(DIM / 128) * (SEQ / 128) * 4, 256, 0, stream>>>(
      PB, WDT, PART, SEQ, DIM, IDIM, IDIM / 4, SEQ / 128);
  reduce_kernel<4, false, false><<<(SEQ * DIM / 4 + 255) / 256, 256, 0, stream>>>(
      PART, HB, nullptr, out, DIM, SEQ * DIM / 4);
}

// Round 5
// 986.589 us; speedup vs baseline: 3.9848x; 1.0635x over previous
//
#include <hip/hip_runtime.h>
#include <hip/hip_bf16.h>

// ---------------------------------------------------------------------------
// Qwen2.5-VL decoder layer, MI355X (gfx950)
// B=1, N=1024, D=3584, H=28, KVH=4, HD=128, I=18944
// Round 5: transconv launches moved next to consumers (L3 locality);
// gate/up 8-phase GEMM fuses SiLU via interleaved Wg/Wu layout -> writes PB
// directly; Wo + down GEMMs use the 8-phase 256^2 kernel with split-K S=4
// (224 blocks = exactly one scheduling round).
// ---------------------------------------------------------------------------

#define SEQ   1024
#define DIM   3584
#define NH    28
#define NKVH  4
#define HDIM  128
#define IDIM  18944
#define QKVN  4608    // 3584 q + 512 k + 512 v
#define GUN   37888   // 2*18944

typedef __attribute__((ext_vector_type(8))) __bf16 bf16x8;
typedef __attribute__((ext_vector_type(4))) __bf16 bf16x4;
typedef __attribute__((ext_vector_type(4))) float  f32x4;

// ---------------- workspace layout (bytes) ----------------
static constexpr size_t OFF_WQKVT = 0;                                   // [4608][3584] bf16
static constexpr size_t OFF_WOT   = OFF_WQKVT + (size_t)QKVN*DIM*2;      // [3584][3584] bf16
static constexpr size_t OFF_WGUT  = OFF_WOT   + (size_t)DIM*DIM*2;       // [37888][3584] bf16 (interleaved g/u)
static constexpr size_t OFF_WDT   = OFF_WGUT  + (size_t)GUN*DIM*2;       // [3584][18944] bf16
static constexpr size_t OFF_XB    = OFF_WDT   + (size_t)DIM*IDIM*2;      // [1024][3584] bf16
static constexpr size_t OFF_QKV   = OFF_XB    + (size_t)SEQ*DIM*2;       // [1024][4608] bf16
static constexpr size_t OFF_VT    = OFF_QKV   + (size_t)SEQ*QKVN*2;      // [4][128][1024] bf16
static constexpr size_t OFF_VSUMP = OFF_VT    + (size_t)NKVH*HDIM*SEQ*2; // [4][8][128] f32
static constexpr size_t OFF_VSUM  = OFF_VSUMP + 4*8*128*4;               // [4][128] f32
static constexpr size_t OFF_BQKV  = OFF_VSUM  + 4*128*4;                 // [4608] f32
static constexpr size_t OFF_OB    = OFF_BQKV  + (size_t)QKVN*4;          // [1024][3584] bf16
static constexpr size_t OFF_HB    = OFF_OB    + (size_t)SEQ*DIM*2;       // [1024][3584] f32
static constexpr size_t OFF_YB    = OFF_HB    + (size_t)SEQ*DIM*4;       // [1024][3584] bf16
static constexpr size_t OFF_GU    = OFF_YB    + (size_t)SEQ*DIM*2;       // 77.6 MB scratch region
static constexpr size_t OFF_PB    = OFF_GU    + (size_t)SEQ*GUN*2;       // [1024][18944] bf16
// split-K f32 partials live in the (always dead) GU region: max 4*1024*3584*4
// = 58.7 MB (QKV S=2: 37.7 MB) < 77.6 MB, never overlapping PB.
static constexpr size_t OFF_PART  = OFF_GU;

// async global->LDS, 16B per lane. lds ptr must be wave-uniform; HW writes
// lane l's 16B to ldsbase + l*16. global ptr is per-lane.
#define GLL16(gp, lp)                                                        \
  __builtin_amdgcn_global_load_lds(                                         \
      (const __attribute__((address_space(1))) void*)(gp),                  \
      (__attribute__((address_space(3))) void*)(lp), 16, 0, 0)

#define BAR    asm volatile("s_barrier" ::: "memory")
#define SCHEDB __builtin_amdgcn_sched_barrier(0)

// ---------------- weight transpose + fp32->bf16 ----------------
// mode 0: out row = n.  mode 1/2: interleaved gate/up layout
// (phys row = (n>>4)*32 + (n&15) + (mode==2 ? 16 : 0)).
__global__ __launch_bounds__(256) void transconv_kernel(
    const float* __restrict__ W, __bf16* __restrict__ WT, int K, int N, int mode)
{
  __shared__ __bf16 t[64][72];
  const int tid = threadIdx.x;
  const int k0 = blockIdx.y * 64, n0 = blockIdx.x * 64;
#pragma unroll
  for (int it = 0; it < 4; ++it) {
    int idx = it * 256 + tid;
    int r = idx >> 4, c4 = idx & 15;
    float4 v = *(const float4*)(W + (size_t)(k0 + r) * N + n0 + c4 * 4);
    t[r][c4 * 4 + 0] = (__bf16)v.x;
    t[r][c4 * 4 + 1] = (__bf16)v.y;
    t[r][c4 * 4 + 2] = (__bf16)v.z;
    t[r][c4 * 4 + 3] = (__bf16)v.w;
  }
  __syncthreads();
#pragma unroll
  for (int it = 0; it < 2; ++it) {
    int idx = it * 256 + tid;
    int r = idx >> 3, c8 = idx & 7;
    bf16x8 o;
#pragma unroll
    for (int i = 0; i < 8; ++i) o[i] = t[c8 * 8 + i][r];
    const int nlog = n0 + r;
    const int orow = (mode == 0) ? nlog
                   : ((nlog >> 4) << 5) + ((mode == 2) ? 16 : 0) + (nlog & 15);
    *(bf16x8*)(WT + (size_t)orow * K + k0 + c8 * 8) = o;
  }
}

// ---------------- bias concat ----------------
__global__ __launch_bounds__(256) void pack_bias_kernel(
    const float* __restrict__ bq, const float* __restrict__ bk,
    const float* __restrict__ bv, float* __restrict__ out)
{
  int i = blockIdx.x * 256 + threadIdx.x;
  if (i < DIM) out[i] = bq[i];
  else if (i < DIM + 512) out[i] = bk[i - DIM];
  else if (i < QKVN) out[i] = bv[i - DIM - 512];
}

// ---------------- RMSNorm (fp32 in, bf16 out) ----------------
__global__ __launch_bounds__(256) void rmsnorm_kernel(
    const float* __restrict__ in, const float* __restrict__ w,
    __bf16* __restrict__ out)
{
  const int row = blockIdx.x;
  const int t = threadIdx.x;
  const float* x = in + (size_t)row * DIM;
  float4 v[4];
  float ss = 0.f;
#pragma unroll
  for (int i = 0; i < 4; ++i) {
    int idx = t + i * 256;
    if (idx < 896) {
      v[i] = ((const float4*)x)[idx];
      ss += v[i].x * v[i].x + v[i].y * v[i].y + v[i].z * v[i].z + v[i].w * v[i].w;
    }
  }
#pragma unroll
  for (int m = 1; m < 64; m <<= 1) ss += __shfl_xor(ss, m);
  __shared__ float red[4];
  if ((t & 63) == 0) red[t >> 6] = ss;
  __syncthreads();
  float tot = red[0] + red[1] + red[2] + red[3];
  float rs = rsqrtf(tot / (float)DIM + 1e-6f);
#pragma unroll
  for (int i = 0; i < 4; ++i) {
    int idx = t + i * 256;
    if (idx < 896) {
      float4 wv = ((const float4*)w)[idx];
      bf16x4 o;
      o[0] = (__bf16)(v[i].x * rs * wv.x);
      o[1] = (__bf16)(v[i].y * rs * wv.y);
      o[2] = (__bf16)(v[i].z * rs * wv.z);
      o[3] = (__bf16)(v[i].w * rs * wv.w);
      *(bf16x4*)(out + (size_t)row * DIM + idx * 4) = o;
    }
  }
}

// ---------------- 128x128 split-K GEMM -> f32 partials (QKV) ---------------
__global__ __launch_bounds__(256, 2) void gemm_splitk_kernel(
    const __bf16* __restrict__ A, const __bf16* __restrict__ BT,
    float* __restrict__ PART, int M, int N, int K, int Kc, int gridY)
{
  __shared__ __bf16 As[128 * 64];
  __shared__ __bf16 Bs[128 * 64];
  const int tid = threadIdx.x;
  const int l = tid & 63, w = tid >> 6;

  const int nwg = gridDim.x;
  const int bq8 = nwg >> 3, br8 = nwg & 7;
  const int xcd = blockIdx.x & 7, bidx = blockIdx.x >> 3;
  const int wg = (xcd < br8 ? xcd * (bq8 + 1) : br8 * (bq8 + 1) + (xcd - br8) * bq8) + bidx;
  const int tm = wg % gridY;
  const int wg2 = wg / gridY;
  const int gridX = N >> 7;
  const int tn = wg2 % gridX;
  const int ks = wg2 / gridX;
  const int row0 = tm * 128;
  const int col0 = tn * 128;
  const int kbase = ks * Kc;

  const int m0 = (w >> 1) * 64;
  const int n0 = (w & 1) * 64;
  const int lg = l >> 4, lc = l & 15;

  f32x4 acc[4][4] = {};

  size_t aoff[4], boff[4];
  int lbyte[4];
#pragma unroll
  for (int it = 0; it < 4; ++it) {
    const int cbase = (it * 4 + w) * 64;
    const int c = cbase + l;
    const int r = c >> 3, p = c & 7;
    const int b = p ^ (r & 7);
    aoff[it] = (size_t)(row0 + r) * K + kbase + b * 8;
    boff[it] = (size_t)(col0 + r) * K + kbase + b * 8;
    lbyte[it] = cbase * 16;
  }
  const int sw = lc & 7;

  const int ktc = Kc >> 6;
  for (int kt = 0; kt < ktc; ++kt) {
    const int k0 = kt << 6;
#pragma unroll
    for (int it = 0; it < 4; ++it) {
      GLL16(A + aoff[it] + k0, (char*)As + lbyte[it]);
      GLL16(BT + boff[it] + k0, (char*)Bs + lbyte[it]);
    }
    __syncthreads();
#pragma unroll
    for (int s = 0; s < 2; ++s) {
      bf16x8 af[4], bfv[4];
#pragma unroll
      for (int a = 0; a < 4; ++a)
        af[a] = *(const bf16x8*)(As + (m0 + a * 16 + lc) * 64 + ((s * 4 + lg) ^ sw) * 8);
#pragma unroll
      for (int b = 0; b < 4; ++b)
        bfv[b] = *(const bf16x8*)(Bs + (n0 + b * 16 + lc) * 64 + ((s * 4 + lg) ^ sw) * 8);
#pragma unroll
      for (int a = 0; a < 4; ++a)
#pragma unroll
        for (int b = 0; b < 4; ++b)
          acc[a][b] = __builtin_amdgcn_mfma_f32_16x16x32_bf16(af[a], bfv[b], acc[a][b], 0, 0, 0);
    }
    __syncthreads();
  }

  float* P = PART + (size_t)ks * M * N;
  const int lr = lg * 4;
#pragma unroll
  for (int b = 0; b < 4; ++b) {
    const int col = col0 + n0 + b * 16 + lc;
#pragma unroll
    for (int a = 0; a < 4; ++a)
#pragma unroll
      for (int j = 0; j < 4; ++j)
        P[(size_t)(row0 + m0 + a * 16 + lr + j) * N + col] = acc[a][b][j];
  }
}

// ---------------- split-K reduce epilogues ---------------------------------
template<int S, bool BF16OUT, bool BIAS>
__global__ __launch_bounds__(256) void reduce_kernel(
    const float* __restrict__ part, const float* __restrict__ resid,
    const float* __restrict__ bias, void* __restrict__ out, int N, int MN4)
{
  const int i4 = blockIdx.x * 256 + threadIdx.x;
  if (i4 >= MN4) return;
  const size_t base = (size_t)i4 * 4;
  f32x4 s = *(const f32x4*)(part + base);
#pragma unroll
  for (int k = 1; k < S; ++k)
    s += *(const f32x4*)(part + (size_t)k * MN4 * 4 + base);
  if (BIAS) {
    const int col = (int)(base % N);
    s += *(const f32x4*)(bias + col);
  }
  if (resid != nullptr) s += *(const f32x4*)(resid + base);
  if (BF16OUT) {
    bf16x4 o;
#pragma unroll
    for (int j = 0; j < 4; ++j) o[j] = (__bf16)s[j];
    *(bf16x4*)((__bf16*)out + base) = o;
  } else {
    *(f32x4*)((float*)out + base) = s;
  }
}

// ---------------- 256x256 8-phase GEMM (T2+T3+T4+T5) -----------------------
// EPI 0: gate/up with interleaved B layout -> silu(g)*u -> bf16 [M][N/2] out.
// EPI 1: f32 split-K partial out (OUT + ks*M*N).
// Grid decode: tm = wg % gridY (fastest), tn = (wg/gridY) % (N>>8),
// ks = (wg/gridY) / (N>>8); K-range = [ks*Kc, +Kc).
template<int EPI>
__global__ __launch_bounds__(512, 1) void gemm256_kernel(
    const __bf16* __restrict__ A, const __bf16* __restrict__ BT,
    void* __restrict__ OUT, int M, int N, int K, int Kc, int gridY)
{
  __shared__ int4 lds4[8192];            // 128 KB
  char* ldsc = (char*)lds4;
  const int tid = threadIdx.x;
  const int l = tid & 63, w = tid >> 6;
  const int wr = w >> 2, wc = w & 3;
  const int lg = l >> 4, lc = l & 15;

  const int nwg = gridDim.x;
  const int bq8 = nwg >> 3, br8 = nwg & 7;
  const int xcd = blockIdx.x & 7, bidx = blockIdx.x >> 3;
  const int wg = (xcd < br8 ? xcd * (bq8 + 1) : br8 * (bq8 + 1) + (xcd - br8) * bq8) + bidx;
  const int ntn = N >> 8;
  const int wg2 = wg / gridY;
  const int row0 = (wg % gridY) * 256;
  const int col0 = (wg2 % ntn) * 256;
  const int ks = wg2 / ntn;
  const int kbase = ks * Kc;

  size_t aoffj[2], boffj[2];
  int dstj[2];
#pragma unroll
  for (int j = 0; j < 2; ++j) {
    const int c = (j * 8 + w) * 64 + l;
    const int r = c >> 3, p = c & 7;
    const int b = p ^ (r & 7);
    aoffj[j] = (size_t)(row0 + r) * K + kbase + b * 8;
    boffj[j] = (size_t)(col0 + r) * K + kbase + b * 8;
    dstj[j] = (j * 8 + w) * 1024;
  }

#define STG_A(U, KT, BUFB) do {                                              \
    GLL16(A + aoffj[0] + (size_t)(U) * 128 * K + (size_t)(KT) * 64,          \
          ldsc + (BUFB) + (U) * 16384 + dstj[0]);                            \
    GLL16(A + aoffj[1] + (size_t)(U) * 128 * K + (size_t)(KT) * 64,          \
          ldsc + (BUFB) + (U) * 16384 + dstj[1]); } while (0)
#define STG_B(U, KT, BUFB) do {                                              \
    GLL16(BT + boffj[0] + (size_t)(U) * 128 * K + (size_t)(KT) * 64,         \
          ldsc + (BUFB) + 32768 + (U) * 16384 + dstj[0]);                    \
    GLL16(BT + boffj[1] + (size_t)(U) * 128 * K + (size_t)(KT) * 64,         \
          ldsc + (BUFB) + 32768 + (U) * 16384 + dstj[1]); } while (0)

  const int sw = lc & 7;
  const int rdA = (wr * 128 + lc) * 128;
  const int rdB = 32768 + (wc * 64 + lc) * 128;
  const int sk0 = (lg ^ sw) * 16;
  const int sk1 = ((4 | lg) ^ sw) * 16;

  f32x4 acc[8][4] = {};
  bf16x8 af[4][2], bfr[4][2];

#define RD_A4(MH, BUFB) do { _Pragma("unroll")                               \
    for (int mm = 0; mm < 4; ++mm) {                                         \
      af[mm][0] = *(const bf16x8*)(ldsc + (BUFB) + rdA + ((MH) * 4 + mm) * 2048 + sk0); \
      af[mm][1] = *(const bf16x8*)(ldsc + (BUFB) + rdA + ((MH) * 4 + mm) * 2048 + sk1); } } while (0)
#define RD_B2(NL, BUFB) do { _Pragma("unroll")                               \
    for (int nn = 0; nn < 2; ++nn) {                                         \
      bfr[(NL) + nn][0] = *(const bf16x8*)(ldsc + (BUFB) + rdB + ((NL) + nn) * 2048 + sk0); \
      bfr[(NL) + nn][1] = *(const bf16x8*)(ldsc + (BUFB) + rdB + ((NL) + nn) * 2048 + sk1); } } while (0)

#define MFMA16(MH, NL) do { _Pragma("unroll")                                \
    for (int mm = 0; mm < 4; ++mm) { _Pragma("unroll")                       \
      for (int nn = 0; nn < 2; ++nn) {                                       \
        acc[(MH)*4+mm][(NL)+nn] = __builtin_amdgcn_mfma_f32_16x16x32_bf16(   \
            af[mm][0], bfr[(NL)+nn][0], acc[(MH)*4+mm][(NL)+nn], 0, 0, 0);   \
        acc[(MH)*4+mm][(NL)+nn] = __builtin_amdgcn_mfma_f32_16x16x32_bf16(   \
            af[mm][1], bfr[(NL)+nn][1], acc[(MH)*4+mm][(NL)+nn], 0, 0, 0); } } } while (0)

#define PH_MFMA(MH, NL)                                                      \
    BAR; SCHEDB; __builtin_amdgcn_s_setprio(1);                              \
    MFMA16(MH, NL);                                                          \
    __builtin_amdgcn_s_setprio(0); SCHEDB; BAR

  STG_A(0, 0, 0); STG_A(1, 0, 0); STG_B(0, 0, 0); STG_B(1, 0, 0);
  STG_A(0, 1, 65536); STG_A(1, 1, 65536); STG_B(0, 1, 65536); STG_B(1, 1, 65536);
  asm volatile("s_waitcnt vmcnt(8)" ::: "memory");
  BAR;

  const int T = Kc >> 6;                 // even for all call sites
#pragma unroll 1
  for (int i = 0; i < (T >> 1); ++i) {
    const int t0 = 2 * i;
    const int se = (t0 + 2 < T) ? t0 + 2 : 0;
    const int so = (t0 + 3 < T) ? t0 + 3 : 0;
    RD_A4(0, 0); RD_B2(0, 0);
    PH_MFMA(0, 0);
    RD_B2(2, 0);
    PH_MFMA(0, 2);
    RD_A4(1, 0);
    PH_MFMA(1, 2);
    STG_A(0, se, 0); STG_A(1, se, 0);
    asm volatile("s_waitcnt vmcnt(4)" ::: "memory");
    PH_MFMA(1, 0);
    RD_A4(0, 65536); RD_B2(0, 65536);
    STG_B(0, se, 0); STG_B(1, se, 0);
    PH_MFMA(0, 0);
    RD_B2(2, 65536);
    PH_MFMA(0, 2);
    RD_A4(1, 65536);
    PH_MFMA(1, 2);
    STG_A(0, so, 65536); STG_A(1, so, 65536);
    STG_B(0, so, 65536); STG_B(1, so, 65536);
    asm volatile("s_waitcnt vmcnt(8)" ::: "memory");
    PH_MFMA(1, 0);
  }
  asm volatile("s_waitcnt vmcnt(0)" ::: "memory");

  if (EPI == 0) {
    // interleaved g/u: fragment n even = gate cols, n odd = up cols (same q)
    __bf16* PBo = (__bf16*)OUT;
    const int id = N >> 1;               // 18944
    const int baseq = (col0 + wc * 64) >> 5;
#pragma unroll
    for (int m = 0; m < 8; ++m) {
#pragma unroll
      for (int p = 0; p < 2; ++p) {
        const int gcol = (baseq + p) * 16 + lc;
#pragma unroll
        for (int j = 0; j < 4; ++j) {
          const int row = row0 + wr * 128 + m * 16 + lg * 4 + j;
          const float g = acc[m][2 * p][j];
          const float u = acc[m][2 * p + 1][j];
          const float s = g / (1.f + __expf(-g));
          PBo[(size_t)row * id + gcol] = (__bf16)(s * u);
        }
      }
    }
  } else {
    float* P = (float*)OUT + (size_t)ks * M * N;
#pragma unroll
    for (int m = 0; m < 8; ++m)
#pragma unroll
      for (int n = 0; n < 4; ++n)
#pragma unroll
        for (int j = 0; j < 4; ++j)
          P[(size_t)(row0 + wr * 128 + m * 16 + lg * 4 + j) * N
            + (col0 + wc * 64 + n * 16 + lc)] = acc[m][n][j];
  }
#undef STG_A
#undef STG_B
#undef RD_A4
#undef RD_B2
#undef MFMA16
#undef PH_MFMA
}

// ---------------- mRoPE (in-place on q,k columns of qkv) ----------------
__global__ __launch_bounds__(256) void rope_kernel(
    __bf16* __restrict__ qkv, const float* __restrict__ cosb,
    const float* __restrict__ sinb)
{
  const int n = blockIdx.x;
  for (int p = threadIdx.x; p < 32 * 64; p += 256) {
    const int head = p >> 6;
    const int d = p & 63;
    const int src = (d < 16) ? 0 : (d < 40) ? 1 : 2;
    const float* cb = cosb + (size_t)src * SEQ * HDIM + (size_t)n * HDIM;
    const float* sb = sinb + (size_t)src * SEQ * HDIM + (size_t)n * HDIM;
    const float c0 = cb[d], c1 = cb[d + 64];
    const float s0 = sb[d], s1 = sb[d + 64];
    const int col = (head < NH) ? head * HDIM : DIM + (head - NH) * HDIM;
    __bf16* q = qkv + (size_t)n * QKVN + col;
    const float a = (float)q[d];
    const float b = (float)q[d + 64];
    q[d]      = (__bf16)(a * c0 - b * s0);
    q[d + 64] = (__bf16)(b * c1 + a * s1);
  }
}

// ---------------- V transpose [n][d] -> [d][n], plus column sums -----------
__global__ __launch_bounds__(256) void vtrans_kernel(
    const __bf16* __restrict__ qkv, __bf16* __restrict__ vT,
    float* __restrict__ vsump)
{
  __shared__ __bf16 t[128][132];
  const int nt = blockIdx.x, kvh = blockIdx.y;
  const int n0 = nt * 128;
  const int tid = threadIdx.x;
#pragma unroll
  for (int it = 0; it < 8; ++it) {
    int idx = it * 256 + tid;
    int nl = idx >> 4, c8 = idx & 15;
    bf16x8 v = *(const bf16x8*)(qkv + (size_t)(n0 + nl) * QKVN + 4096 + kvh * HDIM + c8 * 8);
#pragma unroll
    for (int i = 0; i < 8; ++i) t[nl][c8 * 8 + i] = v[i];
  }
  __syncthreads();
#pragma unroll
  for (int it = 0; it < 8; ++it) {
    int idx = it * 256 + tid;
    int d = idx >> 4, c8 = idx & 15;
    bf16x8 o;
#pragma unroll
    for (int i = 0; i < 8; ++i) o[i] = t[c8 * 8 + i][d];
    *(bf16x8*)(vT + (size_t)(kvh * HDIM + d) * SEQ + n0 + c8 * 8) = o;
  }
  if (tid < 128) {
    float s = 0.f;
    for (int nl = 0; nl < 128; ++nl) s += (float)t[nl][tid];
    vsump[(size_t)(kvh * 8 + nt) * 128 + tid] = s;
  }
}

__global__ __launch_bounds__(512) void vsum_reduce_kernel(
    const float* __restrict__ vsump, float* __restrict__ vsum)
{
  const int idx = threadIdx.x;
  const int kvh = idx >> 7, d = idx & 127;
  float s = 0.f;
#pragma unroll
  for (int nt = 0; nt < 8; ++nt) s += vsump[(size_t)(kvh * 8 + nt) * 128 + d];
  vsum[idx] = s;
}

// ---------------- attention -------------------------------------------------
__global__ __launch_bounds__(256) void attn_kernel(
    const __bf16* __restrict__ qkv, const __bf16* __restrict__ vT,
    const float* __restrict__ vsum, const int* __restrict__ prune,
    __bf16* __restrict__ o)
{
  __shared__ __bf16 plds[4 * 16 * 40];
  const int tid = threadIdx.x;
  const int l = tid & 63, w = tid >> 6;
  const int h = blockIdx.y;
  const int kvh = h / 7;
  const int qt = blockIdx.x;
  const int qbase = qt * 64 + w * 16;
  const int lg = l >> 4, lc = l & 15;
  __bf16* pw = plds + w * (16 * 40);

  bf16x8 qf[4];
#pragma unroll
  for (int s = 0; s < 4; ++s)
    qf[s] = *(const bf16x8*)(qkv + (size_t)(qbase + lc) * QKVN + h * HDIM + s * 32 + lg * 8);

  f32x4 oacc[8] = {};
  float mrun[4] = {-3e38f, -3e38f, -3e38f, -3e38f};
  float lrun[4] = {0.f, 0.f, 0.f, 0.f};

  const int kbEnd = ((qbase + 15) >> 5) + 1;
  for (int kb = 0; kb < kbEnd; ++kb) {
    f32x4 sacc[2] = {};
#pragma unroll
    for (int s = 0; s < 4; ++s) {
#pragma unroll
      for (int c = 0; c < 2; ++c) {
        bf16x8 kf = *(const bf16x8*)(qkv + (size_t)(kb * 32 + c * 16 + lc) * QKVN
                                     + DIM + kvh * HDIM + s * 32 + lg * 8);
        sacc[c] = __builtin_amdgcn_mfma_f32_16x16x32_bf16(qf[s], kf, sacc[c], 0, 0, 0);
      }
    }
    float p[2][4];
    int am[2];
#pragma unroll
    for (int c = 0; c < 2; ++c) {
      const int col = kb * 32 + c * 16 + lc;
      am[c] = (prune[col] != 0) ? 1 : 0;
#pragma unroll
      for (int j = 0; j < 4; ++j) {
        const int row = qbase + lg * 4 + j;
        float sv = sacc[c][j] * 0.08838834764831845f;
        p[c][j] = (col <= row) ? sv : -3e38f;
      }
    }
#pragma unroll
    for (int j = 0; j < 4; ++j) {
      float mx = fmaxf(p[0][j], p[1][j]);
      mx = fmaxf(mx, __shfl_xor(mx, 1));
      mx = fmaxf(mx, __shfl_xor(mx, 2));
      mx = fmaxf(mx, __shfl_xor(mx, 4));
      mx = fmaxf(mx, __shfl_xor(mx, 8));
      const float mnew = fmaxf(mrun[j], mx);
      const float scale = __expf(mrun[j] - mnew);
      mrun[j] = mnew;
      const int row = qbase + lg * 4 + j;
      float rs = 0.f;
#pragma unroll
      for (int c = 0; c < 2; ++c) {
        const int col = kb * 32 + c * 16 + lc;
        float e = __expf(p[c][j] - mnew);
        const int keep = (col == row) ? 1 : am[c];
        e = keep ? e : 0.f;
        p[c][j] = e;
        rs += e;
      }
      rs += __shfl_xor(rs, 1);
      rs += __shfl_xor(rs, 2);
      rs += __shfl_xor(rs, 4);
      rs += __shfl_xor(rs, 8);
      lrun[j] = lrun[j] * scale + rs;
#pragma unroll
      for (int df = 0; df < 8; ++df) oacc[df][j] *= scale;
    }
#pragma unroll
    for (int c = 0; c < 2; ++c)
#pragma unroll
      for (int j = 0; j < 4; ++j)
        pw[(lg * 4 + j) * 40 + c * 16 + lc] = (__bf16)p[c][j];
    bf16x8 pa = *(const bf16x8*)(pw + lc * 40 + lg * 8);
#pragma unroll
    for (int df = 0; df < 8; ++df) {
      bf16x8 vf = *(const bf16x8*)(vT + (size_t)(kvh * HDIM + df * 16 + lc) * SEQ + kb * 32 + lg * 8);
      oacc[df] = __builtin_amdgcn_mfma_f32_16x16x32_bf16(pa, vf, oacc[df], 0, 0, 0);
    }
  }
#pragma unroll
  for (int df = 0; df < 8; ++df) {
    const float vs = vsum[kvh * HDIM + df * 16 + lc];
#pragma unroll
    for (int j = 0; j < 4; ++j) {
      const int row = qbase + lg * 4 + j;
      const float denom = lrun[j] + 1e-6f;
      const float val = (oacc[df][j] + 9.765625e-10f * vs) / denom;
      o[(size_t)row * DIM + h * HDIM + df * 16 + lc] = (__bf16)val;
    }
  }
}

// ---------------------------------------------------------------------------
extern "C" void kernel_launch(void* const* d_in, const int* in_sizes, int n_in,
                              void* d_out, int out_size, void* d_ws, size_t ws_size,
                              hipStream_t stream) {
  const float* hidden = (const float*)d_in[0];
  const float* cosb   = (const float*)d_in[1];
  const float* sinb   = (const float*)d_in[2];
  const int*   prune  = (const int*)d_in[3];
  const float* Wq     = (const float*)d_in[4];
  const float* bq     = (const float*)d_in[5];
  const float* Wk     = (const float*)d_in[6];
  const float* bk     = (const float*)d_in[7];
  const float* Wv     = (const float*)d_in[8];
  const float* bv     = (const float*)d_in[9];
  const float* Wo     = (const float*)d_in[10];
  const float* ln1    = (const float*)d_in[11];
  const float* ln2    = (const float*)d_in[12];
  const float* Wg     = (const float*)d_in[13];
  const float* Wu     = (const float*)d_in[14];
  const float* Wd     = (const float*)d_in[15];
  float* out = (float*)d_out;
  char* ws = (char*)d_ws;

  __bf16* WQKVT = (__bf16*)(ws + OFF_WQKVT);
  __bf16* WOT   = (__bf16*)(ws + OFF_WOT);
  __bf16* WGUT  = (__bf16*)(ws + OFF_WGUT);
  __bf16* WDT   = (__bf16*)(ws + OFF_WDT);
  __bf16* XB    = (__bf16*)(ws + OFF_XB);
  __bf16* QKV   = (__bf16*)(ws + OFF_QKV);
  __bf16* VT    = (__bf16*)(ws + OFF_VT);
  float*  VSUMP = (float*)(ws + OFF_VSUMP);
  float*  VSUM  = (float*)(ws + OFF_VSUM);
  float*  BQKV  = (float*)(ws + OFF_BQKV);
  __bf16* OB    = (__bf16*)(ws + OFF_OB);
  float*  HB    = (float*)(ws + OFF_HB);
  __bf16* YB    = (__bf16*)(ws + OFF_YB);
  __bf16* PB    = (__bf16*)(ws + OFF_PB);
  float*  PART  = (float*)(ws + OFF_PART);

  // ---- attention branch: weights converted just before use (L3 locality) --
  transconv_kernel<<<dim3(DIM / 64, DIM / 64), 256, 0, stream>>>(Wq, WQKVT, DIM, DIM, 0);
  transconv_kernel<<<dim3(512 / 64, DIM / 64), 256, 0, stream>>>(Wk, WQKVT + (size_t)DIM * DIM, DIM, 512, 0);
  transconv_kernel<<<dim3(512 / 64, DIM / 64), 256, 0, stream>>>(Wv, WQKVT + (size_t)4096 * DIM, DIM, 512, 0);
  pack_bias_kernel<<<QKVN / 256, 256, 0, stream>>>(bq, bk, bv, BQKV);
  rmsnorm_kernel<<<SEQ, 256, 0, stream>>>(hidden, ln1, XB);

  // qkv = x @ Wqkv + b  (128^2 split-K 2)
  gemm_splitk_kernel<<<(QKVN / 128) * (SEQ / 128) * 2, 256, 0, stream>>>(
      XB, WQKVT, PART, SEQ, QKVN, DIM, DIM / 2, SEQ / 128);
  reduce_kernel<2, true, true><<<(SEQ * QKVN / 4 + 255) / 256, 256, 0, stream>>>(
      PART, nullptr, BQKV, QKV, QKVN, SEQ * QKVN / 4);

  rope_kernel<<<SEQ, 256, 0, stream>>>(QKV, cosb, sinb);
  vtrans_kernel<<<dim3(8, NKVH), 256, 0, stream>>>(QKV, VT, VSUMP);
  vsum_reduce_kernel<<<1, 512, 0, stream>>>(VSUMP, VSUM);
  attn_kernel<<<dim3(SEQ / 64, NH), 256, 0, stream>>>(QKV, VT, VSUM, prune, OB);

  // h = hidden + OB @ Wo  (8-phase 256^2 split-K 4: 224 blocks = 1 round)
  transconv_kernel<<<dim3(DIM / 64, DIM / 64), 256, 0, stream>>>(Wo, WOT, DIM, DIM, 0);
  gemm256_kernel<1><<<(DIM / 256) * (SEQ / 256) * 4, 512, 0, stream>>>(
      OB, WOT, PART, SEQ, DIM, DIM, DIM / 4, SEQ / 256);
  reduce_kernel<4, false, false><<<(SEQ * DIM / 4 + 255) / 256, 256, 0, stream>>>(
      PART, hidden, nullptr, HB, DIM, SEQ * DIM / 4);

  // y = rmsnorm(h, ln2)
  rmsnorm_kernel<<<SEQ, 256, 0, stream>>>(HB, ln2, YB);

  // gate/up: interleaved WGUT written just before use; silu fused -> PB
  transconv_kernel<<<dim3(IDIM / 64, DIM / 64), 256, 0, stream>>>(Wg, WGUT, DIM, IDIM, 1);
  transconv_kernel<<<dim3(IDIM / 64, DIM / 64), 256, 0, stream>>>(Wu, WGUT, DIM, IDIM, 2);
  gemm256_kernel<0><<<(GUN / 256) * (SEQ / 256), 512, 0, stream>>>(
      YB, WGUT, PB, SEQ, GUN, DIM, DIM, SEQ / 256);

  // out = h + p @ Wd  (8-phase 256^2 split-K 4: 224 blocks)
  transconv_kernel<<<dim3(DIM / 64, IDIM / 64), 256, 0, stream>>>(Wd, WDT, IDIM, DIM, 0);
  gemm256_kernel<1><<<(DIM / 256) * (SEQ / 256) * 4, 512, 0, stream>>>(
      PB, WDT, PART, SEQ, DIM, IDIM, IDIM / 4, SEQ / 256);
  reduce_kernel<4, false, false><<<(SEQ * DIM / 4 + 255) / 256, 256, 0, stream>>>(
      PART, HB, nullptr, out, DIM, SEQ * DIM / 4);
}

// Round 6
// 972.804 us; speedup vs baseline: 4.0412x; 1.0142x over previous
//
#include <hip/hip_runtime.h>
#include <hip/hip_bf16.h>

// ---------------------------------------------------------------------------
// Qwen2.5-VL decoder layer, MI355X (gfx950)
// B=1, N=1024, D=3584, H=28, KVH=4, HD=128, I=18944
// Round 6: gemm256 sync collapsed to 2 barriers per K-tile (ds_reads overlap
// MFMA shadow; barriers only at buffer-hazard edges, counted vmcnt(8) gates).
// ---------------------------------------------------------------------------

#define SEQ   1024
#define DIM   3584
#define NH    28
#define NKVH  4
#define HDIM  128
#define IDIM  18944
#define QKVN  4608    // 3584 q + 512 k + 512 v
#define GUN   37888   // 2*18944

typedef __attribute__((ext_vector_type(8))) __bf16 bf16x8;
typedef __attribute__((ext_vector_type(4))) __bf16 bf16x4;
typedef __attribute__((ext_vector_type(4))) float  f32x4;

// ---------------- workspace layout (bytes) ----------------
static constexpr size_t OFF_WQKVT = 0;                                   // [4608][3584] bf16
static constexpr size_t OFF_WOT   = OFF_WQKVT + (size_t)QKVN*DIM*2;      // [3584][3584] bf16
static constexpr size_t OFF_WGUT  = OFF_WOT   + (size_t)DIM*DIM*2;       // [37888][3584] bf16 (interleaved g/u)
static constexpr size_t OFF_WDT   = OFF_WGUT  + (size_t)GUN*DIM*2;       // [3584][18944] bf16
static constexpr size_t OFF_XB    = OFF_WDT   + (size_t)DIM*IDIM*2;      // [1024][3584] bf16
static constexpr size_t OFF_QKV   = OFF_XB    + (size_t)SEQ*DIM*2;       // [1024][4608] bf16
static constexpr size_t OFF_VT    = OFF_QKV   + (size_t)SEQ*QKVN*2;      // [4][128][1024] bf16
static constexpr size_t OFF_VSUMP = OFF_VT    + (size_t)NKVH*HDIM*SEQ*2; // [4][8][128] f32
static constexpr size_t OFF_VSUM  = OFF_VSUMP + 4*8*128*4;               // [4][128] f32
static constexpr size_t OFF_BQKV  = OFF_VSUM  + 4*128*4;                 // [4608] f32
static constexpr size_t OFF_OB    = OFF_BQKV  + (size_t)QKVN*4;          // [1024][3584] bf16
static constexpr size_t OFF_HB    = OFF_OB    + (size_t)SEQ*DIM*2;       // [1024][3584] f32
static constexpr size_t OFF_YB    = OFF_HB    + (size_t)SEQ*DIM*4;       // [1024][3584] bf16
static constexpr size_t OFF_GU    = OFF_YB    + (size_t)SEQ*DIM*2;       // 77.6 MB scratch region
static constexpr size_t OFF_PB    = OFF_GU    + (size_t)SEQ*GUN*2;       // [1024][18944] bf16
// split-K f32 partials live in the (always dead) GU region: max 58.7 MB < 77.6.
static constexpr size_t OFF_PART  = OFF_GU;

// async global->LDS, 16B per lane. lds ptr must be wave-uniform; HW writes
// lane l's 16B to ldsbase + l*16. global ptr is per-lane.
#define GLL16(gp, lp)                                                        \
  __builtin_amdgcn_global_load_lds(                                         \
      (const __attribute__((address_space(1))) void*)(gp),                  \
      (__attribute__((address_space(3))) void*)(lp), 16, 0, 0)

#define BAR    asm volatile("s_barrier" ::: "memory")

// ---------------- weight transpose + fp32->bf16 ----------------
// mode 0: out row = n.  mode 1/2: interleaved gate/up layout
// (phys row = (n>>4)*32 + (n&15) + (mode==2 ? 16 : 0)).
__global__ __launch_bounds__(256) void transconv_kernel(
    const float* __restrict__ W, __bf16* __restrict__ WT, int K, int N, int mode)
{
  __shared__ __bf16 t[64][72];
  const int tid = threadIdx.x;
  const int k0 = blockIdx.y * 64, n0 = blockIdx.x * 64;
#pragma unroll
  for (int it = 0; it < 4; ++it) {
    int idx = it * 256 + tid;
    int r = idx >> 4, c4 = idx & 15;
    float4 v = *(const float4*)(W + (size_t)(k0 + r) * N + n0 + c4 * 4);
    t[r][c4 * 4 + 0] = (__bf16)v.x;
    t[r][c4 * 4 + 1] = (__bf16)v.y;
    t[r][c4 * 4 + 2] = (__bf16)v.z;
    t[r][c4 * 4 + 3] = (__bf16)v.w;
  }
  __syncthreads();
#pragma unroll
  for (int it = 0; it < 2; ++it) {
    int idx = it * 256 + tid;
    int r = idx >> 3, c8 = idx & 7;
    bf16x8 o;
#pragma unroll
    for (int i = 0; i < 8; ++i) o[i] = t[c8 * 8 + i][r];
    const int nlog = n0 + r;
    const int orow = (mode == 0) ? nlog
                   : ((nlog >> 4) << 5) + ((mode == 2) ? 16 : 0) + (nlog & 15);
    *(bf16x8*)(WT + (size_t)orow * K + k0 + c8 * 8) = o;
  }
}

// ---------------- bias concat ----------------
__global__ __launch_bounds__(256) void pack_bias_kernel(
    const float* __restrict__ bq, const float* __restrict__ bk,
    const float* __restrict__ bv, float* __restrict__ out)
{
  int i = blockIdx.x * 256 + threadIdx.x;
  if (i < DIM) out[i] = bq[i];
  else if (i < DIM + 512) out[i] = bk[i - DIM];
  else if (i < QKVN) out[i] = bv[i - DIM - 512];
}

// ---------------- RMSNorm (fp32 in, bf16 out) ----------------
__global__ __launch_bounds__(256) void rmsnorm_kernel(
    const float* __restrict__ in, const float* __restrict__ w,
    __bf16* __restrict__ out)
{
  const int row = blockIdx.x;
  const int t = threadIdx.x;
  const float* x = in + (size_t)row * DIM;
  float4 v[4];
  float ss = 0.f;
#pragma unroll
  for (int i = 0; i < 4; ++i) {
    int idx = t + i * 256;
    if (idx < 896) {
      v[i] = ((const float4*)x)[idx];
      ss += v[i].x * v[i].x + v[i].y * v[i].y + v[i].z * v[i].z + v[i].w * v[i].w;
    }
  }
#pragma unroll
  for (int m = 1; m < 64; m <<= 1) ss += __shfl_xor(ss, m);
  __shared__ float red[4];
  if ((t & 63) == 0) red[t >> 6] = ss;
  __syncthreads();
  float tot = red[0] + red[1] + red[2] + red[3];
  float rs = rsqrtf(tot / (float)DIM + 1e-6f);
#pragma unroll
  for (int i = 0; i < 4; ++i) {
    int idx = t + i * 256;
    if (idx < 896) {
      float4 wv = ((const float4*)w)[idx];
      bf16x4 o;
      o[0] = (__bf16)(v[i].x * rs * wv.x);
      o[1] = (__bf16)(v[i].y * rs * wv.y);
      o[2] = (__bf16)(v[i].z * rs * wv.z);
      o[3] = (__bf16)(v[i].w * rs * wv.w);
      *(bf16x4*)(out + (size_t)row * DIM + idx * 4) = o;
    }
  }
}

// ---------------- 128x128 split-K GEMM -> f32 partials (QKV) ---------------
__global__ __launch_bounds__(256, 2) void gemm_splitk_kernel(
    const __bf16* __restrict__ A, const __bf16* __restrict__ BT,
    float* __restrict__ PART, int M, int N, int K, int Kc, int gridY)
{
  __shared__ __bf16 As[128 * 64];
  __shared__ __bf16 Bs[128 * 64];
  const int tid = threadIdx.x;
  const int l = tid & 63, w = tid >> 6;

  const int nwg = gridDim.x;
  const int bq8 = nwg >> 3, br8 = nwg & 7;
  const int xcd = blockIdx.x & 7, bidx = blockIdx.x >> 3;
  const int wg = (xcd < br8 ? xcd * (bq8 + 1) : br8 * (bq8 + 1) + (xcd - br8) * bq8) + bidx;
  const int tm = wg % gridY;
  const int wg2 = wg / gridY;
  const int gridX = N >> 7;
  const int tn = wg2 % gridX;
  const int ks = wg2 / gridX;
  const int row0 = tm * 128;
  const int col0 = tn * 128;
  const int kbase = ks * Kc;

  const int m0 = (w >> 1) * 64;
  const int n0 = (w & 1) * 64;
  const int lg = l >> 4, lc = l & 15;

  f32x4 acc[4][4] = {};

  size_t aoff[4], boff[4];
  int lbyte[4];
#pragma unroll
  for (int it = 0; it < 4; ++it) {
    const int cbase = (it * 4 + w) * 64;
    const int c = cbase + l;
    const int r = c >> 3, p = c & 7;
    const int b = p ^ (r & 7);
    aoff[it] = (size_t)(row0 + r) * K + kbase + b * 8;
    boff[it] = (size_t)(col0 + r) * K + kbase + b * 8;
    lbyte[it] = cbase * 16;
  }
  const int sw = lc & 7;

  const int ktc = Kc >> 6;
  for (int kt = 0; kt < ktc; ++kt) {
    const int k0 = kt << 6;
#pragma unroll
    for (int it = 0; it < 4; ++it) {
      GLL16(A + aoff[it] + k0, (char*)As + lbyte[it]);
      GLL16(BT + boff[it] + k0, (char*)Bs + lbyte[it]);
    }
    __syncthreads();
#pragma unroll
    for (int s = 0; s < 2; ++s) {
      bf16x8 af[4], bfv[4];
#pragma unroll
      for (int a = 0; a < 4; ++a)
        af[a] = *(const bf16x8*)(As + (m0 + a * 16 + lc) * 64 + ((s * 4 + lg) ^ sw) * 8);
#pragma unroll
      for (int b = 0; b < 4; ++b)
        bfv[b] = *(const bf16x8*)(Bs + (n0 + b * 16 + lc) * 64 + ((s * 4 + lg) ^ sw) * 8);
#pragma unroll
      for (int a = 0; a < 4; ++a)
#pragma unroll
        for (int b = 0; b < 4; ++b)
          acc[a][b] = __builtin_amdgcn_mfma_f32_16x16x32_bf16(af[a], bfv[b], acc[a][b], 0, 0, 0);
    }
    __syncthreads();
  }

  float* P = PART + (size_t)ks * M * N;
  const int lr = lg * 4;
#pragma unroll
  for (int b = 0; b < 4; ++b) {
    const int col = col0 + n0 + b * 16 + lc;
#pragma unroll
    for (int a = 0; a < 4; ++a)
#pragma unroll
      for (int j = 0; j < 4; ++j)
        P[(size_t)(row0 + m0 + a * 16 + lr + j) * N + col] = acc[a][b][j];
  }
}

// ---------------- split-K reduce epilogues ---------------------------------
template<int S, bool BF16OUT, bool BIAS>
__global__ __launch_bounds__(256) void reduce_kernel(
    const float* __restrict__ part, const float* __restrict__ resid,
    const float* __restrict__ bias, void* __restrict__ out, int N, int MN4)
{
  const int i4 = blockIdx.x * 256 + threadIdx.x;
  if (i4 >= MN4) return;
  const size_t base = (size_t)i4 * 4;
  f32x4 s = *(const f32x4*)(part + base);
#pragma unroll
  for (int k = 1; k < S; ++k)
    s += *(const f32x4*)(part + (size_t)k * MN4 * 4 + base);
  if (BIAS) {
    const int col = (int)(base % N);
    s += *(const f32x4*)(bias + col);
  }
  if (resid != nullptr) s += *(const f32x4*)(resid + base);
  if (BF16OUT) {
    bf16x4 o;
#pragma unroll
    for (int j = 0; j < 4; ++j) o[j] = (__bf16)s[j];
    *(bf16x4*)((__bf16*)out + base) = o;
  } else {
    *(f32x4*)((float*)out + base) = s;
  }
}

// ---------------- 256x256 GEMM, 2 barriers per K-tile ----------------------
// EPI 0: gate/up with interleaved B layout -> silu(g)*u -> bf16 [M][N/2] out.
// EPI 1: f32 split-K partial out (OUT + ks*M*N).
// Per K-tile on buffer C: {RD q0..q2 interleaved with MFMA (no barriers,
// DS rides the MFMA shadow) ; lgkmcnt(0) ; BAR ; stage t+2 -> C ; MFMA q3
// (reg-only) ; vmcnt(8) gates the OTHER buffer's tile ; BAR}.
template<int EPI>
__global__ __launch_bounds__(512, 1) void gemm256_kernel(
    const __bf16* __restrict__ A, const __bf16* __restrict__ BT,
    void* __restrict__ OUT, int M, int N, int K, int Kc, int gridY)
{
  __shared__ int4 lds4[8192];            // 128 KB
  char* ldsc = (char*)lds4;
  const int tid = threadIdx.x;
  const int l = tid & 63, w = tid >> 6;
  const int wr = w >> 2, wc = w & 3;
  const int lg = l >> 4, lc = l & 15;

  const int nwg = gridDim.x;
  const int bq8 = nwg >> 3, br8 = nwg & 7;
  const int xcd = blockIdx.x & 7, bidx = blockIdx.x >> 3;
  const int wg = (xcd < br8 ? xcd * (bq8 + 1) : br8 * (bq8 + 1) + (xcd - br8) * bq8) + bidx;
  const int ntn = N >> 8;
  const int wg2 = wg / gridY;
  const int row0 = (wg % gridY) * 256;
  const int col0 = (wg2 % ntn) * 256;
  const int ks = wg2 / ntn;
  const int kbase = ks * Kc;

  size_t aoffj[2], boffj[2];
  int dstj[2];
#pragma unroll
  for (int j = 0; j < 2; ++j) {
    const int c = (j * 8 + w) * 64 + l;
    const int r = c >> 3, p = c & 7;
    const int b = p ^ (r & 7);
    aoffj[j] = (size_t)(row0 + r) * K + kbase + b * 8;
    boffj[j] = (size_t)(col0 + r) * K + kbase + b * 8;
    dstj[j] = (j * 8 + w) * 1024;
  }

#define STG_A(U, KT, BUFB) do {                                              \
    GLL16(A + aoffj[0] + (size_t)(U) * 128 * K + (size_t)(KT) * 64,          \
          ldsc + (BUFB) + (U) * 16384 + dstj[0]);                            \
    GLL16(A + aoffj[1] + (size_t)(U) * 128 * K + (size_t)(KT) * 64,          \
          ldsc + (BUFB) + (U) * 16384 + dstj[1]); } while (0)
#define STG_B(U, KT, BUFB) do {                                              \
    GLL16(BT + boffj[0] + (size_t)(U) * 128 * K + (size_t)(KT) * 64,         \
          ldsc + (BUFB) + 32768 + (U) * 16384 + dstj[0]);                    \
    GLL16(BT + boffj[1] + (size_t)(U) * 128 * K + (size_t)(KT) * 64,         \
          ldsc + (BUFB) + 32768 + (U) * 16384 + dstj[1]); } while (0)

  const int sw = lc & 7;
  const int rdA = (wr * 128 + lc) * 128;
  const int rdB = 32768 + (wc * 64 + lc) * 128;
  const int sk0 = (lg ^ sw) * 16;
  const int sk1 = ((4 | lg) ^ sw) * 16;

  f32x4 acc[8][4] = {};
  bf16x8 af[4][2], bfr[4][2];

#define RD_A4(MH, BUFB) do { _Pragma("unroll")                               \
    for (int mm = 0; mm < 4; ++mm) {                                         \
      af[mm][0] = *(const bf16x8*)(ldsc + (BUFB) + rdA + ((MH) * 4 + mm) * 2048 + sk0); \
      af[mm][1] = *(const bf16x8*)(ldsc + (BUFB) + rdA + ((MH) * 4 + mm) * 2048 + sk1); } } while (0)
#define RD_B2(NL, BUFB) do { _Pragma("unroll")                               \
    for (int nn = 0; nn < 2; ++nn) {                                         \
      bfr[(NL) + nn][0] = *(const bf16x8*)(ldsc + (BUFB) + rdB + ((NL) + nn) * 2048 + sk0); \
      bfr[(NL) + nn][1] = *(const bf16x8*)(ldsc + (BUFB) + rdB + ((NL) + nn) * 2048 + sk1); } } while (0)

#define MFMA16(MH, NL) do { _Pragma("unroll")                                \
    for (int mm = 0; mm < 4; ++mm) { _Pragma("unroll")                       \
      for (int nn = 0; nn < 2; ++nn) {                                       \
        acc[(MH)*4+mm][(NL)+nn] = __builtin_amdgcn_mfma_f32_16x16x32_bf16(   \
            af[mm][0], bfr[(NL)+nn][0], acc[(MH)*4+mm][(NL)+nn], 0, 0, 0);   \
        acc[(MH)*4+mm][(NL)+nn] = __builtin_amdgcn_mfma_f32_16x16x32_bf16(   \
            af[mm][1], bfr[(NL)+nn][1], acc[(MH)*4+mm][(NL)+nn], 0, 0, 0); } } } while (0)

  // one K-tile on buffer BUFB, staging tile TNEXT into the same buffer.
#define KTILE(BUFB, TNEXT)                                                   \
    RD_A4(0, BUFB); RD_B2(0, BUFB);                                          \
    __builtin_amdgcn_s_setprio(1); MFMA16(0, 0);                             \
    __builtin_amdgcn_s_setprio(0);                                           \
    RD_B2(2, BUFB);                                                          \
    __builtin_amdgcn_s_setprio(1); MFMA16(0, 2);                             \
    __builtin_amdgcn_s_setprio(0);                                           \
    RD_A4(1, BUFB);                                                          \
    __builtin_amdgcn_s_setprio(1); MFMA16(1, 2);                             \
    __builtin_amdgcn_s_setprio(0);                                           \
    asm volatile("s_waitcnt lgkmcnt(0)" ::: "memory");                       \
    BAR;                                  /* all waves done reading BUFB */  \
    STG_A(0, TNEXT, BUFB); STG_A(1, TNEXT, BUFB);                            \
    STG_B(0, TNEXT, BUFB); STG_B(1, TNEXT, BUFB);                            \
    __builtin_amdgcn_s_setprio(1); MFMA16(1, 0);                             \
    __builtin_amdgcn_s_setprio(0);                                           \
    asm volatile("s_waitcnt vmcnt(8)" ::: "memory"); /* other buf arrived */ \
    BAR

  // prologue: tile0 -> buf0, tile1 -> buf1; wait tile0.
  STG_A(0, 0, 0); STG_A(1, 0, 0); STG_B(0, 0, 0); STG_B(1, 0, 0);
  STG_A(0, 1, 65536); STG_A(1, 1, 65536); STG_B(0, 1, 65536); STG_B(1, 1, 65536);
  asm volatile("s_waitcnt vmcnt(8)" ::: "memory");
  BAR;

  const int T = Kc >> 6;                 // even for all call sites
#pragma unroll 1
  for (int i = 0; i < (T >> 1); ++i) {
    const int t0 = 2 * i;
    const int se = (t0 + 2 < T) ? t0 + 2 : 0;   // dummy reload at end
    const int so = (t0 + 3 < T) ? t0 + 3 : 0;
    KTILE(0, se);
    KTILE(65536, so);
  }
  asm volatile("s_waitcnt vmcnt(0)" ::: "memory");

  if (EPI == 0) {
    // interleaved g/u: fragment n even = gate cols, n odd = up cols (same q)
    __bf16* PBo = (__bf16*)OUT;
    const int id = N >> 1;               // 18944
    const int baseq = (col0 + wc * 64) >> 5;
#pragma unroll
    for (int m = 0; m < 8; ++m) {
#pragma unroll
      for (int p = 0; p < 2; ++p) {
        const int gcol = (baseq + p) * 16 + lc;
#pragma unroll
        for (int j = 0; j < 4; ++j) {
          const int row = row0 + wr * 128 + m * 16 + lg * 4 + j;
          const float g = acc[m][2 * p][j];
          const float u = acc[m][2 * p + 1][j];
          const float s = g / (1.f + __expf(-g));
          PBo[(size_t)row * id + gcol] = (__bf16)(s * u);
        }
      }
    }
  } else {
    float* P = (float*)OUT + (size_t)ks * M * N;
#pragma unroll
    for (int m = 0; m < 8; ++m)
#pragma unroll
      for (int n = 0; n < 4; ++n)
#pragma unroll
        for (int j = 0; j < 4; ++j)
          P[(size_t)(row0 + wr * 128 + m * 16 + lg * 4 + j) * N
            + (col0 + wc * 64 + n * 16 + lc)] = acc[m][n][j];
  }
#undef STG_A
#undef STG_B
#undef RD_A4
#undef RD_B2
#undef MFMA16
#undef KTILE
}

// ---------------- mRoPE (in-place on q,k columns of qkv) ----------------
__global__ __launch_bounds__(256) void rope_kernel(
    __bf16* __restrict__ qkv, const float* __restrict__ cosb,
    const float* __restrict__ sinb)
{
  const int n = blockIdx.x;
  for (int p = threadIdx.x; p < 32 * 64; p += 256) {
    const int head = p >> 6;
    const int d = p & 63;
    const int src = (d < 16) ? 0 : (d < 40) ? 1 : 2;
    const float* cb = cosb + (size_t)src * SEQ * HDIM + (size_t)n * HDIM;
    const float* sb = sinb + (size_t)src * SEQ * HDIM + (size_t)n * HDIM;
    const float c0 = cb[d], c1 = cb[d + 64];
    const float s0 = sb[d], s1 = sb[d + 64];
    const int col = (head < NH) ? head * HDIM : DIM + (head - NH) * HDIM;
    __bf16* q = qkv + (size_t)n * QKVN + col;
    const float a = (float)q[d];
    const float b = (float)q[d + 64];
    q[d]      = (__bf16)(a * c0 - b * s0);
    q[d + 64] = (__bf16)(b * c1 + a * s1);
  }
}

// ---------------- V transpose [n][d] -> [d][n], plus column sums -----------
__global__ __launch_bounds__(256) void vtrans_kernel(
    const __bf16* __restrict__ qkv, __bf16* __restrict__ vT,
    float* __restrict__ vsump)
{
  __shared__ __bf16 t[128][132];
  const int nt = blockIdx.x, kvh = blockIdx.y;
  const int n0 = nt * 128;
  const int tid = threadIdx.x;
#pragma unroll
  for (int it = 0; it < 8; ++it) {
    int idx = it * 256 + tid;
    int nl = idx >> 4, c8 = idx & 15;
    bf16x8 v = *(const bf16x8*)(qkv + (size_t)(n0 + nl) * QKVN + 4096 + kvh * HDIM + c8 * 8);
#pragma unroll
    for (int i = 0; i < 8; ++i) t[nl][c8 * 8 + i] = v[i];
  }
  __syncthreads();
#pragma unroll
  for (int it = 0; it < 8; ++it) {
    int idx = it * 256 + tid;
    int d = idx >> 4, c8 = idx & 15;
    bf16x8 o;
#pragma unroll
    for (int i = 0; i < 8; ++i) o[i] = t[c8 * 8 + i][d];
    *(bf16x8*)(vT + (size_t)(kvh * HDIM + d) * SEQ + n0 + c8 * 8) = o;
  }
  if (tid < 128) {
    float s = 0.f;
    for (int nl = 0; nl < 128; ++nl) s += (float)t[nl][tid];
    vsump[(size_t)(kvh * 8 + nt) * 128 + tid] = s;
  }
}

__global__ __launch_bounds__(512) void vsum_reduce_kernel(
    const float* __restrict__ vsump, float* __restrict__ vsum)
{
  const int idx = threadIdx.x;
  const int kvh = idx >> 7, d = idx & 127;
  float s = 0.f;
#pragma unroll
  for (int nt = 0; nt < 8; ++nt) s += vsump[(size_t)(kvh * 8 + nt) * 128 + d];
  vsum[idx] = s;
}

// ---------------- attention -------------------------------------------------
__global__ __launch_bounds__(256) void attn_kernel(
    const __bf16* __restrict__ qkv, const __bf16* __restrict__ vT,
    const float* __restrict__ vsum, const int* __restrict__ prune,
    __bf16* __restrict__ o)
{
  __shared__ __bf16 plds[4 * 16 * 40];
  const int tid = threadIdx.x;
  const int l = tid & 63, w = tid >> 6;
  const int h = blockIdx.y;
  const int kvh = h / 7;
  const int qt = blockIdx.x;
  const int qbase = qt * 64 + w * 16;
  const int lg = l >> 4, lc = l & 15;
  __bf16* pw = plds + w * (16 * 40);

  bf16x8 qf[4];
#pragma unroll
  for (int s = 0; s < 4; ++s)
    qf[s] = *(const bf16x8*)(qkv + (size_t)(qbase + lc) * QKVN + h * HDIM + s * 32 + lg * 8);

  f32x4 oacc[8] = {};
  float mrun[4] = {-3e38f, -3e38f, -3e38f, -3e38f};
  float lrun[4] = {0.f, 0.f, 0.f, 0.f};

  const int kbEnd = ((qbase + 15) >> 5) + 1;
  for (int kb = 0; kb < kbEnd; ++kb) {
    f32x4 sacc[2] = {};
#pragma unroll
    for (int s = 0; s < 4; ++s) {
#pragma unroll
      for (int c = 0; c < 2; ++c) {
        bf16x8 kf = *(const bf16x8*)(qkv + (size_t)(kb * 32 + c * 16 + lc) * QKVN
                                     + DIM + kvh * HDIM + s * 32 + lg * 8);
        sacc[c] = __builtin_amdgcn_mfma_f32_16x16x32_bf16(qf[s], kf, sacc[c], 0, 0, 0);
      }
    }
    float p[2][4];
    int am[2];
#pragma unroll
    for (int c = 0; c < 2; ++c) {
      const int col = kb * 32 + c * 16 + lc;
      am[c] = (prune[col] != 0) ? 1 : 0;
#pragma unroll
      for (int j = 0; j < 4; ++j) {
        const int row = qbase + lg * 4 + j;
        float sv = sacc[c][j] * 0.08838834764831845f;
        p[c][j] = (col <= row) ? sv : -3e38f;
      }
    }
#pragma unroll
    for (int j = 0; j < 4; ++j) {
      float mx = fmaxf(p[0][j], p[1][j]);
      mx = fmaxf(mx, __shfl_xor(mx, 1));
      mx = fmaxf(mx, __shfl_xor(mx, 2));
      mx = fmaxf(mx, __shfl_xor(mx, 4));
      mx = fmaxf(mx, __shfl_xor(mx, 8));
      const float mnew = fmaxf(mrun[j], mx);
      const float scale = __expf(mrun[j] - mnew);
      mrun[j] = mnew;
      const int row = qbase + lg * 4 + j;
      float rs = 0.f;
#pragma unroll
      for (int c = 0; c < 2; ++c) {
        const int col = kb * 32 + c * 16 + lc;
        float e = __expf(p[c][j] - mnew);
        const int keep = (col == row) ? 1 : am[c];
        e = keep ? e : 0.f;
        p[c][j] = e;
        rs += e;
      }
      rs += __shfl_xor(rs, 1);
      rs += __shfl_xor(rs, 2);
      rs += __shfl_xor(rs, 4);
      rs += __shfl_xor(rs, 8);
      lrun[j] = lrun[j] * scale + rs;
#pragma unroll
      for (int df = 0; df < 8; ++df) oacc[df][j] *= scale;
    }
#pragma unroll
    for (int c = 0; c < 2; ++c)
#pragma unroll
      for (int j = 0; j < 4; ++j)
        pw[(lg * 4 + j) * 40 + c * 16 + lc] = (__bf16)p[c][j];
    bf16x8 pa = *(const bf16x8*)(pw + lc * 40 + lg * 8);
#pragma unroll
    for (int df = 0; df < 8; ++df) {
      bf16x8 vf = *(const bf16x8*)(vT + (size_t)(kvh * HDIM + df * 16 + lc) * SEQ + kb * 32 + lg * 8);
      oacc[df] = __builtin_amdgcn_mfma_f32_16x16x32_bf16(pa, vf, oacc[df], 0, 0, 0);
    }
  }
#pragma unroll
  for (int df = 0; df < 8; ++df) {
    const float vs = vsum[kvh * HDIM + df * 16 + lc];
#pragma unroll
    for (int j = 0; j < 4; ++j) {
      const int row = qbase + lg * 4 + j;
      const float denom = lrun[j] + 1e-6f;
      const float val = (oacc[df][j] + 9.765625e-10f * vs) / denom;
      o[(size_t)row * DIM + h * HDIM + df * 16 + lc] = (__bf16)val;
    }
  }
}

// ---------------------------------------------------------------------------
extern "C" void kernel_launch(void* const* d_in, const int* in_sizes, int n_in,
                              void* d_out, int out_size, void* d_ws, size_t ws_size,
                              hipStream_t stream) {
  const float* hidden = (const float*)d_in[0];
  const float* cosb   = (const float*)d_in[1];
  const float* sinb   = (const float*)d_in[2];
  const int*   prune  = (const int*)d_in[3];
  const float* Wq     = (const float*)d_in[4];
  const float* bq     = (const float*)d_in[5];
  const float* Wk     = (const float*)d_in[6];
  const float* bk     = (const float*)d_in[7];
  const float* Wv     = (const float*)d_in[8];
  const float* bv     = (const float*)d_in[9];
  const float* Wo     = (const float*)d_in[10];
  const float* ln1    = (const float*)d_in[11];
  const float* ln2    = (const float*)d_in[12];
  const float* Wg     = (const float*)d_in[13];
  const float* Wu     = (const float*)d_in[14];
  const float* Wd     = (const float*)d_in[15];
  float* out = (float*)d_out;
  char* ws = (char*)d_ws;

  __bf16* WQKVT = (__bf16*)(ws + OFF_WQKVT);
  __bf16* WOT   = (__bf16*)(ws + OFF_WOT);
  __bf16* WGUT  = (__bf16*)(ws + OFF_WGUT);
  __bf16* WDT   = (__bf16*)(ws + OFF_WDT);
  __bf16* XB    = (__bf16*)(ws + OFF_XB);
  __bf16* QKV   = (__bf16*)(ws + OFF_QKV);
  __bf16* VT    = (__bf16*)(ws + OFF_VT);
  float*  VSUMP = (float*)(ws + OFF_VSUMP);
  float*  VSUM  = (float*)(ws + OFF_VSUM);
  float*  BQKV  = (float*)(ws + OFF_BQKV);
  __bf16* OB    = (__bf16*)(ws + OFF_OB);
  float*  HB    = (float*)(ws + OFF_HB);
  __bf16* YB    = (__bf16*)(ws + OFF_YB);
  __bf16* PB    = (__bf16*)(ws + OFF_PB);
  float*  PART  = (float*)(ws + OFF_PART);

  // ---- attention branch ----
  transconv_kernel<<<dim3(DIM / 64, DIM / 64), 256, 0, stream>>>(Wq, WQKVT, DIM, DIM, 0);
  transconv_kernel<<<dim3(512 / 64, DIM / 64), 256, 0, stream>>>(Wk, WQKVT + (size_t)DIM * DIM, DIM, 512, 0);
  transconv_kernel<<<dim3(512 / 64, DIM / 64), 256, 0, stream>>>(Wv, WQKVT + (size_t)4096 * DIM, DIM, 512, 0);
  pack_bias_kernel<<<QKVN / 256, 256, 0, stream>>>(bq, bk, bv, BQKV);
  rmsnorm_kernel<<<SEQ, 256, 0, stream>>>(hidden, ln1, XB);

  // qkv = x @ Wqkv + b  (128^2 split-K 2)
  gemm_splitk_kernel<<<(QKVN / 128) * (SEQ / 128) * 2, 256, 0, stream>>>(
      XB, WQKVT, PART, SEQ, QKVN, DIM, DIM / 2, SEQ / 128);
  reduce_kernel<2, true, true><<<(SEQ * QKVN / 4 + 255) / 256, 256, 0, stream>>>(
      PART, nullptr, BQKV, QKV, QKVN, SEQ * QKVN / 4);

  rope_kernel<<<SEQ, 256, 0, stream>>>(QKV, cosb, sinb);
  vtrans_kernel<<<dim3(8, NKVH), 256, 0, stream>>>(QKV, VT, VSUMP);
  vsum_reduce_kernel<<<1, 512, 0, stream>>>(VSUMP, VSUM);
  attn_kernel<<<dim3(SEQ / 64, NH), 256, 0, stream>>>(QKV, VT, VSUM, prune, OB);

  // h = hidden + OB @ Wo  (256^2 split-K 4: 224 blocks = 1 round)
  transconv_kernel<<<dim3(DIM / 64, DIM / 64), 256, 0, stream>>>(Wo, WOT, DIM, DIM, 0);
  gemm256_kernel<1><<<(DIM / 256) * (SEQ / 256) * 4, 512, 0, stream>>>(
      OB, WOT, PART, SEQ, DIM, DIM, DIM / 4, SEQ / 256);
  reduce_kernel<4, false, false><<<(SEQ * DIM / 4 + 255) / 256, 256, 0, stream>>>(
      PART, hidden, nullptr, HB, DIM, SEQ * DIM / 4);

  // y = rmsnorm(h, ln2)
  rmsnorm_kernel<<<SEQ, 256, 0, stream>>>(HB, ln2, YB);

  // gate/up: interleaved WGUT; silu fused -> PB
  transconv_kernel<<<dim3(IDIM / 64, DIM / 64), 256, 0, stream>>>(Wg, WGUT, DIM, IDIM, 1);
  transconv_kernel<<<dim3(IDIM / 64, DIM / 64), 256, 0, stream>>>(Wu, WGUT, DIM, IDIM, 2);
  gemm256_kernel<0><<<(GUN / 256) * (SEQ / 256), 512, 0, stream>>>(
      YB, WGUT, PB, SEQ, GUN, DIM, DIM, SEQ / 256);

  // out = h + p @ Wd  (256^2 split-K 4: 224 blocks)
  transconv_kernel<<<dim3(DIM / 64, IDIM / 64), 256, 0, stream>>>(Wd, WDT, IDIM, DIM, 0);
  gemm256_kernel<1><<<(DIM / 256) * (SEQ / 256) * 4, 512, 0, stream>>>(
      PB, WDT, PART, SEQ, DIM, IDIM, IDIM / 4, SEQ / 256);
  reduce_kernel<4, false, false><<<(SEQ * DIM / 4 + 255) / 256, 256, 0, stream>>>(
      PART, HB, nullptr, out, DIM, SEQ * DIM / 4);
}

// Round 7
// 938.058 us; speedup vs baseline: 4.1909x; 1.0370x over previous
//
#include <hip/hip_runtime.h>
#include <hip/hip_bf16.h>

// ---------------------------------------------------------------------------
// Qwen2.5-VL decoder layer, MI355X (gfx950)
// B=1, N=1024, D=3584, H=28, KVH=4, HD=128, I=18944
// Round 7: gemm256 -> faithful m201 fine-interleave 8-phase schedule
// (1 half-tile staged per phase, vmcnt(4) gates at ph4/ph8, per-phase
// dual barriers). QKV GEMM moved onto gemm256 (split-K 2, 144 blocks).
// ---------------------------------------------------------------------------

#define SEQ   1024
#define DIM   3584
#define NH    28
#define NKVH  4
#define HDIM  128
#define IDIM  18944
#define QKVN  4608    // 3584 q + 512 k + 512 v
#define GUN   37888   // 2*18944

typedef __attribute__((ext_vector_type(8))) __bf16 bf16x8;
typedef __attribute__((ext_vector_type(4))) __bf16 bf16x4;
typedef __attribute__((ext_vector_type(4))) float  f32x4;

// ---------------- workspace layout (bytes) ----------------
static constexpr size_t OFF_WQKVT = 0;                                   // [4608][3584] bf16
static constexpr size_t OFF_WOT   = OFF_WQKVT + (size_t)QKVN*DIM*2;      // [3584][3584] bf16
static constexpr size_t OFF_WGUT  = OFF_WOT   + (size_t)DIM*DIM*2;       // [37888][3584] bf16 (interleaved g/u)
static constexpr size_t OFF_WDT   = OFF_WGUT  + (size_t)GUN*DIM*2;       // [3584][18944] bf16
static constexpr size_t OFF_XB    = OFF_WDT   + (size_t)DIM*IDIM*2;      // [1024][3584] bf16
static constexpr size_t OFF_QKV   = OFF_XB    + (size_t)SEQ*DIM*2;       // [1024][4608] bf16
static constexpr size_t OFF_VT    = OFF_QKV   + (size_t)SEQ*QKVN*2;      // [4][128][1024] bf16
static constexpr size_t OFF_VSUMP = OFF_VT    + (size_t)NKVH*HDIM*SEQ*2; // [4][8][128] f32
static constexpr size_t OFF_VSUM  = OFF_VSUMP + 4*8*128*4;               // [4][128] f32
static constexpr size_t OFF_BQKV  = OFF_VSUM  + 4*128*4;                 // [4608] f32
static constexpr size_t OFF_OB    = OFF_BQKV  + (size_t)QKVN*4;          // [1024][3584] bf16
static constexpr size_t OFF_HB    = OFF_OB    + (size_t)SEQ*DIM*2;       // [1024][3584] f32
static constexpr size_t OFF_YB    = OFF_HB    + (size_t)SEQ*DIM*4;       // [1024][3584] bf16
static constexpr size_t OFF_GU    = OFF_YB    + (size_t)SEQ*DIM*2;       // 77.6 MB scratch region
static constexpr size_t OFF_PB    = OFF_GU    + (size_t)SEQ*GUN*2;       // [1024][18944] bf16
// split-K f32 partials live in the (always dead) GU region: max 58.7 MB < 77.6.
static constexpr size_t OFF_PART  = OFF_GU;

// async global->LDS, 16B per lane. lds ptr must be wave-uniform; HW writes
// lane l's 16B to ldsbase + l*16. global ptr is per-lane.
#define GLL16(gp, lp)                                                        \
  __builtin_amdgcn_global_load_lds(                                         \
      (const __attribute__((address_space(1))) void*)(gp),                  \
      (__attribute__((address_space(3))) void*)(lp), 16, 0, 0)

#define BAR    asm volatile("s_barrier" ::: "memory")
#define LGKM0  asm volatile("s_waitcnt lgkmcnt(0)" ::: "memory")
#define VM4    asm volatile("s_waitcnt vmcnt(4)" ::: "memory")

// ---------------- weight transpose + fp32->bf16 ----------------
// mode 0: out row = n.  mode 1/2: interleaved gate/up layout
// (phys row = (n>>4)*32 + (n&15) + (mode==2 ? 16 : 0)).
__global__ __launch_bounds__(256) void transconv_kernel(
    const float* __restrict__ W, __bf16* __restrict__ WT, int K, int N, int mode)
{
  __shared__ __bf16 t[64][72];
  const int tid = threadIdx.x;
  const int k0 = blockIdx.y * 64, n0 = blockIdx.x * 64;
#pragma unroll
  for (int it = 0; it < 4; ++it) {
    int idx = it * 256 + tid;
    int r = idx >> 4, c4 = idx & 15;
    float4 v = *(const float4*)(W + (size_t)(k0 + r) * N + n0 + c4 * 4);
    t[r][c4 * 4 + 0] = (__bf16)v.x;
    t[r][c4 * 4 + 1] = (__bf16)v.y;
    t[r][c4 * 4 + 2] = (__bf16)v.z;
    t[r][c4 * 4 + 3] = (__bf16)v.w;
  }
  __syncthreads();
#pragma unroll
  for (int it = 0; it < 2; ++it) {
    int idx = it * 256 + tid;
    int r = idx >> 3, c8 = idx & 7;
    bf16x8 o;
#pragma unroll
    for (int i = 0; i < 8; ++i) o[i] = t[c8 * 8 + i][r];
    const int nlog = n0 + r;
    const int orow = (mode == 0) ? nlog
                   : ((nlog >> 4) << 5) + ((mode == 2) ? 16 : 0) + (nlog & 15);
    *(bf16x8*)(WT + (size_t)orow * K + k0 + c8 * 8) = o;
  }
}

// ---------------- bias concat ----------------
__global__ __launch_bounds__(256) void pack_bias_kernel(
    const float* __restrict__ bq, const float* __restrict__ bk,
    const float* __restrict__ bv, float* __restrict__ out)
{
  int i = blockIdx.x * 256 + threadIdx.x;
  if (i < DIM) out[i] = bq[i];
  else if (i < DIM + 512) out[i] = bk[i - DIM];
  else if (i < QKVN) out[i] = bv[i - DIM - 512];
}

// ---------------- RMSNorm (fp32 in, bf16 out) ----------------
__global__ __launch_bounds__(256) void rmsnorm_kernel(
    const float* __restrict__ in, const float* __restrict__ w,
    __bf16* __restrict__ out)
{
  const int row = blockIdx.x;
  const int t = threadIdx.x;
  const float* x = in + (size_t)row * DIM;
  float4 v[4];
  float ss = 0.f;
#pragma unroll
  for (int i = 0; i < 4; ++i) {
    int idx = t + i * 256;
    if (idx < 896) {
      v[i] = ((const float4*)x)[idx];
      ss += v[i].x * v[i].x + v[i].y * v[i].y + v[i].z * v[i].z + v[i].w * v[i].w;
    }
  }
#pragma unroll
  for (int m = 1; m < 64; m <<= 1) ss += __shfl_xor(ss, m);
  __shared__ float red[4];
  if ((t & 63) == 0) red[t >> 6] = ss;
  __syncthreads();
  float tot = red[0] + red[1] + red[2] + red[3];
  float rs = rsqrtf(tot / (float)DIM + 1e-6f);
#pragma unroll
  for (int i = 0; i < 4; ++i) {
    int idx = t + i * 256;
    if (idx < 896) {
      float4 wv = ((const float4*)w)[idx];
      bf16x4 o;
      o[0] = (__bf16)(v[i].x * rs * wv.x);
      o[1] = (__bf16)(v[i].y * rs * wv.y);
      o[2] = (__bf16)(v[i].z * rs * wv.z);
      o[3] = (__bf16)(v[i].w * rs * wv.w);
      *(bf16x4*)(out + (size_t)row * DIM + idx * 4) = o;
    }
  }
}

// ---------------- split-K reduce epilogues ---------------------------------
template<int S, bool BF16OUT, bool BIAS>
__global__ __launch_bounds__(256) void reduce_kernel(
    const float* __restrict__ part, const float* __restrict__ resid,
    const float* __restrict__ bias, void* __restrict__ out, int N, int MN4)
{
  const int i4 = blockIdx.x * 256 + threadIdx.x;
  if (i4 >= MN4) return;
  const size_t base = (size_t)i4 * 4;
  f32x4 s = *(const f32x4*)(part + base);
#pragma unroll
  for (int k = 1; k < S; ++k)
    s += *(const f32x4*)(part + (size_t)k * MN4 * 4 + base);
  if (BIAS) {
    const int col = (int)(base % N);
    s += *(const f32x4*)(bias + col);
  }
  if (resid != nullptr) s += *(const f32x4*)(resid + base);
  if (BF16OUT) {
    bf16x4 o;
#pragma unroll
    for (int j = 0; j < 4; ++j) o[j] = (__bf16)s[j];
    *(bf16x4*)((__bf16*)out + base) = o;
  } else {
    *(f32x4*)((float*)out + base) = s;
  }
}

// ---------------- 256x256 8-phase GEMM (m201 fine interleave) --------------
// EPI 0: gate/up with interleaved B layout -> silu(g)*u -> bf16 [M][N/2] out.
// EPI 1: f32 split-K partial out (OUT + ks*M*N).
// Per phase: {ds_read quadrant ; stage 1 half-tile (2 GLL16) ; BAR ;
// lgkmcnt(0) ; setprio(1) 16 MFMA setprio(0) ; BAR}. Staging schedule:
// ph1 O.A0(t1) ph2 O.A1(t1) ph3 E.B0(se) ph4 E.B1(se)+vmcnt(4)
// ph5 E.A0(se) ph6 E.A1(se) ph7 O.B0(so) ph8 O.B1(so)+vmcnt(4).
// Gates drain exactly the buffer about to be read (12 -> 4 outstanding).
template<int EPI>
__global__ __launch_bounds__(512, 1) void gemm256_kernel(
    const __bf16* __restrict__ A, const __bf16* __restrict__ BT,
    void* __restrict__ OUT, int M, int N, int K, int Kc, int gridY)
{
  __shared__ int4 lds4[8192];            // 128 KB
  char* ldsc = (char*)lds4;
  const int tid = threadIdx.x;
  const int l = tid & 63, w = tid >> 6;
  const int wr = w >> 2, wc = w & 3;
  const int lg = l >> 4, lc = l & 15;

  const int nwg = gridDim.x;
  const int bq8 = nwg >> 3, br8 = nwg & 7;
  const int xcd = blockIdx.x & 7, bidx = blockIdx.x >> 3;
  const int wg = (xcd < br8 ? xcd * (bq8 + 1) : br8 * (bq8 + 1) + (xcd - br8) * bq8) + bidx;
  const int ntn = N >> 8;
  const int wg2 = wg / gridY;
  const int row0 = (wg % gridY) * 256;
  const int col0 = (wg2 % ntn) * 256;
  const int ks = wg2 / ntn;
  const int kbase = ks * Kc;

  size_t aoffj[2], boffj[2];
  int dstj[2];
#pragma unroll
  for (int j = 0; j < 2; ++j) {
    const int c = (j * 8 + w) * 64 + l;
    const int r = c >> 3, p = c & 7;
    const int b = p ^ (r & 7);
    aoffj[j] = (size_t)(row0 + r) * K + kbase + b * 8;
    boffj[j] = (size_t)(col0 + r) * K + kbase + b * 8;
    dstj[j] = (j * 8 + w) * 1024;
  }

// stage A half-tile U (U=0: rows 0-127, U=1: rows 128-255) of K-tile KT
#define STG_A(U, KT, BUFB) do {                                              \
    GLL16(A + aoffj[0] + (size_t)(U) * 128 * K + (size_t)(KT) * 64,          \
          ldsc + (BUFB) + (U) * 16384 + dstj[0]);                            \
    GLL16(A + aoffj[1] + (size_t)(U) * 128 * K + (size_t)(KT) * 64,          \
          ldsc + (BUFB) + (U) * 16384 + dstj[1]); } while (0)
#define STG_B(U, KT, BUFB) do {                                              \
    GLL16(BT + boffj[0] + (size_t)(U) * 128 * K + (size_t)(KT) * 64,         \
          ldsc + (BUFB) + 32768 + (U) * 16384 + dstj[0]);                    \
    GLL16(BT + boffj[1] + (size_t)(U) * 128 * K + (size_t)(KT) * 64,         \
          ldsc + (BUFB) + 32768 + (U) * 16384 + dstj[1]); } while (0)

  const int sw = lc & 7;
  const int rdA = (wr * 128 + lc) * 128;
  const int rdB = 32768 + (wc * 64 + lc) * 128;
  const int sk0 = (lg ^ sw) * 16;
  const int sk1 = ((4 | lg) ^ sw) * 16;

  f32x4 acc[8][4] = {};
  bf16x8 af[4][2], bfr[4][2];

#define RD_A4(MH, BUFB) do { _Pragma("unroll")                               \
    for (int mm = 0; mm < 4; ++mm) {                                         \
      af[mm][0] = *(const bf16x8*)(ldsc + (BUFB) + rdA + ((MH) * 4 + mm) * 2048 + sk0); \
      af[mm][1] = *(const bf16x8*)(ldsc + (BUFB) + rdA + ((MH) * 4 + mm) * 2048 + sk1); } } while (0)
#define RD_B2(NL, BUFB) do { _Pragma("unroll")                               \
    for (int nn = 0; nn < 2; ++nn) {                                         \
      bfr[(NL) + nn][0] = *(const bf16x8*)(ldsc + (BUFB) + rdB + ((NL) + nn) * 2048 + sk0); \
      bfr[(NL) + nn][1] = *(const bf16x8*)(ldsc + (BUFB) + rdB + ((NL) + nn) * 2048 + sk1); } } while (0)

#define MFMA16(MH, NL) do { _Pragma("unroll")                                \
    for (int mm = 0; mm < 4; ++mm) { _Pragma("unroll")                       \
      for (int nn = 0; nn < 2; ++nn) {                                       \
        acc[(MH)*4+mm][(NL)+nn] = __builtin_amdgcn_mfma_f32_16x16x32_bf16(   \
            af[mm][0], bfr[(NL)+nn][0], acc[(MH)*4+mm][(NL)+nn], 0, 0, 0);   \
        acc[(MH)*4+mm][(NL)+nn] = __builtin_amdgcn_mfma_f32_16x16x32_bf16(   \
            af[mm][1], bfr[(NL)+nn][1], acc[(MH)*4+mm][(NL)+nn], 0, 0, 0); } } } while (0)

#define DO_MFMA(MH, NL)                                                      \
    __builtin_amdgcn_s_setprio(1); MFMA16(MH, NL);                           \
    __builtin_amdgcn_s_setprio(0)

  // prologue: E(tile0) all 4 halves, O(tile1) B halves. vmcnt(4) = E done.
  STG_B(0, 0, 0); STG_B(1, 0, 0); STG_A(0, 0, 0); STG_A(1, 0, 0);
  STG_B(0, 1, 65536); STG_B(1, 1, 65536);
  VM4;
  BAR;

  const int T = Kc >> 6;                 // even for all call sites
#pragma unroll 1
  for (int i = 0; i < (T >> 1); ++i) {
    const int t1 = 2 * i + 1;
    const int se = (2 * i + 2 < T) ? 2 * i + 2 : 2 * i;   // E next (dummy=cur)
    const int so = (2 * i + 3 < T) ? 2 * i + 3 : t1;      // O next
    // ph1: E q1 reads; stage O.A0(t1)
    RD_A4(0, 0); RD_B2(0, 0); STG_A(0, t1, 65536);
    BAR; LGKM0; DO_MFMA(0, 0); BAR;
    // ph2: E q2; stage O.A1(t1)
    RD_B2(2, 0); STG_A(1, t1, 65536);
    BAR; LGKM0; DO_MFMA(0, 2); BAR;
    // ph3: E q3; stage E.B0(se)   [E.B free since ph2]
    RD_A4(1, 0); STG_B(0, se, 0);
    BAR; LGKM0; DO_MFMA(1, 2); BAR;
    // ph4: E q4 (reg-only); stage E.B1(se); GATE: O fully arrived
    STG_B(1, se, 0);
    VM4;
    BAR; DO_MFMA(1, 0); BAR;
    // ph5: O q1; stage E.A0(se)   [E.A free since ph3]
    RD_A4(0, 65536); RD_B2(0, 65536); STG_A(0, se, 0);
    BAR; LGKM0; DO_MFMA(0, 0); BAR;
    // ph6: O q2; stage E.A1(se)
    RD_B2(2, 65536); STG_A(1, se, 0);
    BAR; LGKM0; DO_MFMA(0, 2); BAR;
    // ph7: O q3; stage O.B0(so)   [O.B free since ph6]
    RD_A4(1, 65536); STG_B(0, so, 65536);
    BAR; LGKM0; DO_MFMA(1, 2); BAR;
    // ph8: O q4; stage O.B1(so); GATE: E(se) fully arrived
    STG_B(1, so, 65536);
    VM4;
    BAR; DO_MFMA(1, 0); BAR;
  }
  asm volatile("s_waitcnt vmcnt(0)" ::: "memory");

  if (EPI == 0) {
    // interleaved g/u: fragment n even = gate cols, n odd = up cols (same q)
    __bf16* PBo = (__bf16*)OUT;
    const int id = N >> 1;               // 18944
    const int baseq = (col0 + wc * 64) >> 5;
#pragma unroll
    for (int m = 0; m < 8; ++m) {
#pragma unroll
      for (int p = 0; p < 2; ++p) {
        const int gcol = (baseq + p) * 16 + lc;
#pragma unroll
        for (int j = 0; j < 4; ++j) {
          const int row = row0 + wr * 128 + m * 16 + lg * 4 + j;
          const float g = acc[m][2 * p][j];
          const float u = acc[m][2 * p + 1][j];
          const float s = g / (1.f + __expf(-g));
          PBo[(size_t)row * id + gcol] = (__bf16)(s * u);
        }
      }
    }
  } else {
    float* P = (float*)OUT + (size_t)ks * M * N;
#pragma unroll
    for (int m = 0; m < 8; ++m)
#pragma unroll
      for (int n = 0; n < 4; ++n)
#pragma unroll
        for (int j = 0; j < 4; ++j)
          P[(size_t)(row0 + wr * 128 + m * 16 + lg * 4 + j) * N
            + (col0 + wc * 64 + n * 16 + lc)] = acc[m][n][j];
  }
#undef STG_A
#undef STG_B
#undef RD_A4
#undef RD_B2
#undef MFMA16
#undef DO_MFMA
}

// ---------------- mRoPE (in-place on q,k columns of qkv) ----------------
__global__ __launch_bounds__(256) void rope_kernel(
    __bf16* __restrict__ qkv, const float* __restrict__ cosb,
    const float* __restrict__ sinb)
{
  const int n = blockIdx.x;
  for (int p = threadIdx.x; p < 32 * 64; p += 256) {
    const int head = p >> 6;
    const int d = p & 63;
    const int src = (d < 16) ? 0 : (d < 40) ? 1 : 2;
    const float* cb = cosb + (size_t)src * SEQ * HDIM + (size_t)n * HDIM;
    const float* sb = sinb + (size_t)src * SEQ * HDIM + (size_t)n * HDIM;
    const float c0 = cb[d], c1 = cb[d + 64];
    const float s0 = sb[d], s1 = sb[d + 64];
    const int col = (head < NH) ? head * HDIM : DIM + (head - NH) * HDIM;
    __bf16* q = qkv + (size_t)n * QKVN + col;
    const float a = (float)q[d];
    const float b = (float)q[d + 64];
    q[d]      = (__bf16)(a * c0 - b * s0);
    q[d + 64] = (__bf16)(b * c1 + a * s1);
  }
}

// ---------------- V transpose [n][d] -> [d][n], plus column sums -----------
__global__ __launch_bounds__(256) void vtrans_kernel(
    const __bf16* __restrict__ qkv, __bf16* __restrict__ vT,
    float* __restrict__ vsump)
{
  __shared__ __bf16 t[128][132];
  const int nt = blockIdx.x, kvh = blockIdx.y;
  const int n0 = nt * 128;
  const int tid = threadIdx.x;
#pragma unroll
  for (int it = 0; it < 8; ++it) {
    int idx = it * 256 + tid;
    int nl = idx >> 4, c8 = idx & 15;
    bf16x8 v = *(const bf16x8*)(qkv + (size_t)(n0 + nl) * QKVN + 4096 + kvh * HDIM + c8 * 8);
#pragma unroll
    for (int i = 0; i < 8; ++i) t[nl][c8 * 8 + i] = v[i];
  }
  __syncthreads();
#pragma unroll
  for (int it = 0; it < 8; ++it) {
    int idx = it * 256 + tid;
    int d = idx >> 4, c8 = idx & 15;
    bf16x8 o;
#pragma unroll
    for (int i = 0; i < 8; ++i) o[i] = t[c8 * 8 + i][d];
    *(bf16x8*)(vT + (size_t)(kvh * HDIM + d) * SEQ + n0 + c8 * 8) = o;
  }
  if (tid < 128) {
    float s = 0.f;
    for (int nl = 0; nl < 128; ++nl) s += (float)t[nl][tid];
    vsump[(size_t)(kvh * 8 + nt) * 128 + tid] = s;
  }
}

__global__ __launch_bounds__(512) void vsum_reduce_kernel(
    const float* __restrict__ vsump, float* __restrict__ vsum)
{
  const int idx = threadIdx.x;
  const int kvh = idx >> 7, d = idx & 127;
  float s = 0.f;
#pragma unroll
  for (int nt = 0; nt < 8; ++nt) s += vsump[(size_t)(kvh * 8 + nt) * 128 + d];
  vsum[idx] = s;
}

// ---------------- attention -------------------------------------------------
__global__ __launch_bounds__(256) void attn_kernel(
    const __bf16* __restrict__ qkv, const __bf16* __restrict__ vT,
    const float* __restrict__ vsum, const int* __restrict__ prune,
    __bf16* __restrict__ o)
{
  __shared__ __bf16 plds[4 * 16 * 40];
  const int tid = threadIdx.x;
  const int l = tid & 63, w = tid >> 6;
  const int h = blockIdx.y;
  const int kvh = h / 7;
  const int qt = blockIdx.x;
  const int qbase = qt * 64 + w * 16;
  const int lg = l >> 4, lc = l & 15;
  __bf16* pw = plds + w * (16 * 40);

  bf16x8 qf[4];
#pragma unroll
  for (int s = 0; s < 4; ++s)
    qf[s] = *(const bf16x8*)(qkv + (size_t)(qbase + lc) * QKVN + h * HDIM + s * 32 + lg * 8);

  f32x4 oacc[8] = {};
  float mrun[4] = {-3e38f, -3e38f, -3e38f, -3e38f};
  float lrun[4] = {0.f, 0.f, 0.f, 0.f};

  const int kbEnd = ((qbase + 15) >> 5) + 1;
  for (int kb = 0; kb < kbEnd; ++kb) {
    f32x4 sacc[2] = {};
#pragma unroll
    for (int s = 0; s < 4; ++s) {
#pragma unroll
      for (int c = 0; c < 2; ++c) {
        bf16x8 kf = *(const bf16x8*)(qkv + (size_t)(kb * 32 + c * 16 + lc) * QKVN
                                     + DIM + kvh * HDIM + s * 32 + lg * 8);
        sacc[c] = __builtin_amdgcn_mfma_f32_16x16x32_bf16(qf[s], kf, sacc[c], 0, 0, 0);
      }
    }
    float p[2][4];
    int am[2];
#pragma unroll
    for (int c = 0; c < 2; ++c) {
      const int col = kb * 32 + c * 16 + lc;
      am[c] = (prune[col] != 0) ? 1 : 0;
#pragma unroll
      for (int j = 0; j < 4; ++j) {
        const int row = qbase + lg * 4 + j;
        float sv = sacc[c][j] * 0.08838834764831845f;
        p[c][j] = (col <= row) ? sv : -3e38f;
      }
    }
#pragma unroll
    for (int j = 0; j < 4; ++j) {
      float mx = fmaxf(p[0][j], p[1][j]);
      mx = fmaxf(mx, __shfl_xor(mx, 1));
      mx = fmaxf(mx, __shfl_xor(mx, 2));
      mx = fmaxf(mx, __shfl_xor(mx, 4));
      mx = fmaxf(mx, __shfl_xor(mx, 8));
      const float mnew = fmaxf(mrun[j], mx);
      const float scale = __expf(mrun[j] - mnew);
      mrun[j] = mnew;
      const int row = qbase + lg * 4 + j;
      float rs = 0.f;
#pragma unroll
      for (int c = 0; c < 2; ++c) {
        const int col = kb * 32 + c * 16 + lc;
        float e = __expf(p[c][j] - mnew);
        const int keep = (col == row) ? 1 : am[c];
        e = keep ? e : 0.f;
        p[c][j] = e;
        rs += e;
      }
      rs += __shfl_xor(rs, 1);
      rs += __shfl_xor(rs, 2);
      rs += __shfl_xor(rs, 4);
      rs += __shfl_xor(rs, 8);
      lrun[j] = lrun[j] * scale + rs;
#pragma unroll
      for (int df = 0; df < 8; ++df) oacc[df][j] *= scale;
    }
#pragma unroll
    for (int c = 0; c < 2; ++c)
#pragma unroll
      for (int j = 0; j < 4; ++j)
        pw[(lg * 4 + j) * 40 + c * 16 + lc] = (__bf16)p[c][j];
    bf16x8 pa = *(const bf16x8*)(pw + lc * 40 + lg * 8);
#pragma unroll
    for (int df = 0; df < 8; ++df) {
      bf16x8 vf = *(const bf16x8*)(vT + (size_t)(kvh * HDIM + df * 16 + lc) * SEQ + kb * 32 + lg * 8);
      oacc[df] = __builtin_amdgcn_mfma_f32_16x16x32_bf16(pa, vf, oacc[df], 0, 0, 0);
    }
  }
#pragma unroll
  for (int df = 0; df < 8; ++df) {
    const float vs = vsum[kvh * HDIM + df * 16 + lc];
#pragma unroll
    for (int j = 0; j < 4; ++j) {
      const int row = qbase + lg * 4 + j;
      const float denom = lrun[j] + 1e-6f;
      const float val = (oacc[df][j] + 9.765625e-10f * vs) / denom;
      o[(size_t)row * DIM + h * HDIM + df * 16 + lc] = (__bf16)val;
    }
  }
}

// ---------------------------------------------------------------------------
extern "C" void kernel_launch(void* const* d_in, const int* in_sizes, int n_in,
                              void* d_out, int out_size, void* d_ws, size_t ws_size,
                              hipStream_t stream) {
  const float* hidden = (const float*)d_in[0];
  const float* cosb   = (const float*)d_in[1];
  const float* sinb   = (const float*)d_in[2];
  const int*   prune  = (const int*)d_in[3];
  const float* Wq     = (const float*)d_in[4];
  const float* bq     = (const float*)d_in[5];
  const float* Wk     = (const float*)d_in[6];
  const float* bk     = (const float*)d_in[7];
  const float* Wv     = (const float*)d_in[8];
  const float* bv     = (const float*)d_in[9];
  const float* Wo     = (const float*)d_in[10];
  const float* ln1    = (const float*)d_in[11];
  const float* ln2    = (const float*)d_in[12];
  const float* Wg     = (const float*)d_in[13];
  const float* Wu     = (const float*)d_in[14];
  const float* Wd     = (const float*)d_in[15];
  float* out = (float*)d_out;
  char* ws = (char*)d_ws;

  __bf16* WQKVT = (__bf16*)(ws + OFF_WQKVT);
  __bf16* WOT   = (__bf16*)(ws + OFF_WOT);
  __bf16* WGUT  = (__bf16*)(ws + OFF_WGUT);
  __bf16* WDT   = (__bf16*)(ws + OFF_WDT);
  __bf16* XB    = (__bf16*)(ws + OFF_XB);
  __bf16* QKV   = (__bf16*)(ws + OFF_QKV);
  __bf16* VT    = (__bf16*)(ws + OFF_VT);
  float*  VSUMP = (float*)(ws + OFF_VSUMP);
  float*  VSUM  = (float*)(ws + OFF_VSUM);
  float*  BQKV  = (float*)(ws + OFF_BQKV);
  __bf16* OB    = (__bf16*)(ws + OFF_OB);
  float*  HB    = (float*)(ws + OFF_HB);
  __bf16* YB    = (__bf16*)(ws + OFF_YB);
  __bf16* PB    = (__bf16*)(ws + OFF_PB);
  float*  PART  = (float*)(ws + OFF_PART);

  // ---- attention branch ----
  transconv_kernel<<<dim3(DIM / 64, DIM / 64), 256, 0, stream>>>(Wq, WQKVT, DIM, DIM, 0);
  transconv_kernel<<<dim3(512 / 64, DIM / 64), 256, 0, stream>>>(Wk, WQKVT + (size_t)DIM * DIM, DIM, 512, 0);
  transconv_kernel<<<dim3(512 / 64, DIM / 64), 256, 0, stream>>>(Wv, WQKVT + (size_t)4096 * DIM, DIM, 512, 0);
  pack_bias_kernel<<<QKVN / 256, 256, 0, stream>>>(bq, bk, bv, BQKV);
  rmsnorm_kernel<<<SEQ, 256, 0, stream>>>(hidden, ln1, XB);

  // qkv = x @ Wqkv + b  (gemm256 split-K 2: 4x18x2 = 144 blocks)
  gemm256_kernel<1><<<(SEQ / 256) * (QKVN / 256) * 2, 512, 0, stream>>>(
      XB, WQKVT, PART, SEQ, QKVN, DIM, DIM / 2, SEQ / 256);
  reduce_kernel<2, true, true><<<(SEQ * QKVN / 4 + 255) / 256, 256, 0, stream>>>(
      PART, nullptr, BQKV, QKV, QKVN, SEQ * QKVN / 4);

  rope_kernel<<<SEQ, 256, 0, stream>>>(QKV, cosb, sinb);
  vtrans_kernel<<<dim3(8, NKVH), 256, 0, stream>>>(QKV, VT, VSUMP);
  vsum_reduce_kernel<<<1, 512, 0, stream>>>(VSUMP, VSUM);
  attn_kernel<<<dim3(SEQ / 64, NH), 256, 0, stream>>>(QKV, VT, VSUM, prune, OB);

  // h = hidden + OB @ Wo  (gemm256 split-K 4: 224 blocks = 1 round)
  transconv_kernel<<<dim3(DIM / 64, DIM / 64), 256, 0, stream>>>(Wo, WOT, DIM, DIM, 0);
  gemm256_kernel<1><<<(DIM / 256) * (SEQ / 256) * 4, 512, 0, stream>>>(
      OB, WOT, PART, SEQ, DIM, DIM, DIM / 4, SEQ / 256);
  reduce_kernel<4, false, false><<<(SEQ * DIM / 4 + 255) / 256, 256, 0, stream>>>(
      PART, hidden, nullptr, HB, DIM, SEQ * DIM / 4);

  // y = rmsnorm(h, ln2)
  rmsnorm_kernel<<<SEQ, 256, 0, stream>>>(HB, ln2, YB);

  // gate/up: interleaved WGUT; silu fused -> PB
  transconv_kernel<<<dim3(IDIM / 64, DIM / 64), 256, 0, stream>>>(Wg, WGUT, DIM, IDIM, 1);
  transconv_kernel<<<dim3(IDIM / 64, DIM / 64), 256, 0, stream>>>(Wu, WGUT, DIM, IDIM, 2);
  gemm256_kernel<0><<<(GUN / 256) * (SEQ / 256), 512, 0, stream>>>(
      YB, WGUT, PB, SEQ, GUN, DIM, DIM, SEQ / 256);

  // out = h + p @ Wd  (gemm256 split-K 4: 224 blocks)
  transconv_kernel<<<dim3(DIM / 64, IDIM / 64), 256, 0, stream>>>(Wd, WDT, IDIM, DIM, 0);
  gemm256_kernel<1><<<(DIM / 256) * (SEQ / 256) * 4, 512, 0, stream>>>(
      PB, WDT, PART, SEQ, DIM, IDIM, IDIM / 4, SEQ / 256);
  reduce_kernel<4, false, false><<<(SEQ * DIM / 4 + 255) / 256, 256, 0, stream>>>(
      PART, HB, nullptr, out, DIM, SEQ * DIM / 4);
}